// Round 8
// baseline (489.954 us; speedup 1.0000x reference)
//
#include <hip/hip_runtime.h>

#define N_NODES 50000
#define E_EDGES 800000
#define IN_DIM  256
#define HID     128
#define HALF    64
#define OUT_DIM 2
#define NBW     8         // nodes per wave
#define NBB     32        // nodes per block (4 waves)
#define SLOPE   0.01f

#define HS_STRIDE 132               // 128 + 4 pad: broadcast quads hit disjoint bank-quads
#define BUF_FLOATS (NBB * HS_STRIDE)   // 4224 floats = 16.9 KB

// acc[c..c+7] += xv * W[k][c..c+7]
__device__ __forceinline__ void fma8(float* acc, float xv, float4 w0, float4 w1) {
    acc[0] = fmaf(xv, w0.x, acc[0]); acc[1] = fmaf(xv, w0.y, acc[1]);
    acc[2] = fmaf(xv, w0.z, acc[2]); acc[3] = fmaf(xv, w0.w, acc[3]);
    acc[4] = fmaf(xv, w1.x, acc[4]); acc[5] = fmaf(xv, w1.y, acc[5]);
    acc[6] = fmaf(xv, w1.z, acc[6]); acc[7] = fmaf(xv, w1.w, acc[7]);
}

// one k-quad of the weight panel: 8 x float4 (4 k-rows x 8 channels)
__device__ __forceinline__ void load_w8(float4* w, const float* __restrict__ W,
                                        int k, int c0) {
    w[0] = *(const float4*)(W + (size_t)(k + 0) * HID + c0);
    w[1] = *(const float4*)(W + (size_t)(k + 0) * HID + c0 + 4);
    w[2] = *(const float4*)(W + (size_t)(k + 1) * HID + c0);
    w[3] = *(const float4*)(W + (size_t)(k + 1) * HID + c0 + 4);
    w[4] = *(const float4*)(W + (size_t)(k + 2) * HID + c0);
    w[5] = *(const float4*)(W + (size_t)(k + 2) * HID + c0 + 4);
    w[6] = *(const float4*)(W + (size_t)(k + 3) * HID + c0);
    w[7] = *(const float4*)(W + (size_t)(k + 3) * HID + c0 + 4);
}

// acc[r][0..7] over 2 nodes: K-panel GEMM, weights streamed from global
__device__ __forceinline__ void gemm2(float acc[2][8], const float* __restrict__ W,
                                      int K, const float* wbuf, int gq, int c0) {
    for (int k = 0; k < K; k += 4) {
        float4 wq[8];
        load_w8(wq, W, k, c0);
        #pragma unroll
        for (int r = 0; r < 2; r++) {
            float4 xq = *(const float4*)(wbuf + (gq + 4 * r) * HS_STRIDE + k);
            fma8(acc[r], xq.x, wq[0], wq[1]);
            fma8(acc[r], xq.y, wq[2], wq[3]);
            fma8(acc[r], xq.z, wq[4], wq[5]);
            fma8(acc[r], xq.w, wq[6], wq[7]);
        }
    }
}

__device__ __forceinline__ void init8(float acc[2][8], const float* __restrict__ b, int c0) {
    float4 b0 = *(const float4*)(b + c0);
    float4 b1 = *(const float4*)(b + c0 + 4);
    #pragma unroll
    for (int r = 0; r < 2; r++) {
        acc[r][0] = b0.x; acc[r][1] = b0.y; acc[r][2] = b0.z; acc[r][3] = b0.w;
        acc[r][4] = b1.x; acc[r][5] = b1.y; acc[r][6] = b1.z; acc[r][7] = b1.w;
    }
}

// ---------------------------------------------------------------- degree ----
__global__ void zero_int_kernel(int* __restrict__ p, int n) {
    int i = blockIdx.x * blockDim.x + threadIdx.x;
    if (i < n) p[i] = 0;
}

__global__ void deg_ticket_kernel(const int* __restrict__ col,
                                  int* __restrict__ cnt, int* __restrict__ ticket) {
    int e = blockIdx.x * blockDim.x + threadIdx.x;
    if (e < E_EDGES) ticket[e] = atomicAdd(&cnt[col[e]], 1);
}

__global__ __launch_bounds__(1024) void scan_kernel(
    const int* __restrict__ cnt, int* __restrict__ row_start)
{
    __shared__ int sums[1024];
    const int T  = 1024;
    const int t  = threadIdx.x;
    const int CH = (N_NODES + T - 1) / T;   // 49
    const int base = t * CH;

    int s = 0;
    for (int k = 0; k < CH; k++) {
        int i = base + k;
        if (i < N_NODES) s += cnt[i];
    }
    sums[t] = s;
    __syncthreads();
    for (int off = 1; off < T; off <<= 1) {
        int v = (t >= off) ? sums[t - off] : 0;
        __syncthreads();
        sums[t] += v;
        __syncthreads();
    }
    int run = (t == 0) ? 0 : sums[t - 1];
    for (int k = 0; k < CH; k++) {
        int i = base + k;
        if (i < N_NODES) { row_start[i] = run; run += cnt[i]; }
    }
    if (t == T - 1) row_start[N_NODES] = run;
}

__global__ void fill_kernel(const int* __restrict__ ei,
                            const int* __restrict__ row_start,
                            const int* __restrict__ ticket,
                            int* __restrict__ csr_src)
{
    int e = blockIdx.x * blockDim.x + threadIdx.x;
    if (e >= E_EDGES) return;
    int j = ei[e];              // source
    int i = ei[E_EDGES + e];    // target
    csr_src[row_start[i] + ticket[e]] = j;
}

// ------------------------------------------------------------- node phase ---
// 256 threads = 4 waves, each wave owns 8 nodes (wave-private LDS slice, NO
// barriers). lane = (gq = l>>4, m = l&15): channels 8m..8m+7, nodes gq + 4r.
__global__ __launch_bounds__(256, 5) void node_phase_kernel(
    const float* __restrict__ x,
    const float* __restrict__ W_in,    const float* __restrict__ b_in,
    const float* __restrict__ W_nor,   const float* __restrict__ b_nor,
    const float* __restrict__ W_abnor, const float* __restrict__ b_abnor,
    const float* __restrict__ W_att,   const float* __restrict__ b_att,
    const float* __restrict__ v_att,
    const int* __restrict__ cnt,
    float* __restrict__ u)
{
    __shared__ __align__(16) float buf[BUF_FLOATS];   // 16.9 KB, 4 wave slices

    const int tid    = threadIdx.x;
    const int w      = tid >> 6;
    const int l      = tid & 63;
    const int gq     = l >> 4;
    const int m      = l & 15;
    const int c0     = m * 8;
    const int wnode0 = blockIdx.x * NBB + w * NBW;
    if (wnode0 >= N_NODES) return;    // tail waves idle (no barriers used)

    float* wbuf = &buf[w * NBW * HS_STRIDE];
    const float* xrow = x + (size_t)wnode0 * IN_DIM;

    // ---- h = leaky_relu(x @ W_in + b_in), k staged in two 128-halves ----
    float a0[2][8];
    init8(a0, b_in, c0);
    for (int half = 0; half < 2; half++) {
        // stage this wave's 8 rows of the k-half (coalesced float4)
        #pragma unroll
        for (int it = 0; it < 4; it++) {
            int i = it * 64 + l;
            int rr = i >> 5, kq = i & 31;
            float4 v = *(const float4*)(xrow + (size_t)rr * IN_DIM + half * 128 + kq * 4);
            *(float4*)&wbuf[rr * HS_STRIDE + kq * 4] = v;
        }
        gemm2(a0, W_in + (size_t)half * 128 * HID, 128, wbuf, gq, c0);
    }

    // ---- h -> wbuf (leaky relu), wave-private ----
    #pragma unroll
    for (int r = 0; r < 2; r++) {
        int rr = gq + 4 * r;
        float4 h0, h1;
        float v;
        v = a0[r][0]; h0.x = v > 0.f ? v : SLOPE * v;
        v = a0[r][1]; h0.y = v > 0.f ? v : SLOPE * v;
        v = a0[r][2]; h0.z = v > 0.f ? v : SLOPE * v;
        v = a0[r][3]; h0.w = v > 0.f ? v : SLOPE * v;
        v = a0[r][4]; h1.x = v > 0.f ? v : SLOPE * v;
        v = a0[r][5]; h1.y = v > 0.f ? v : SLOPE * v;
        v = a0[r][6]; h1.z = v > 0.f ? v : SLOPE * v;
        v = a0[r][7]; h1.w = v > 0.f ? v : SLOPE * v;
        *(float4*)&wbuf[rr * HS_STRIDE + c0]     = h0;
        *(float4*)&wbuf[rr * HS_STRIDE + c0 + 4] = h1;
    }

    // ---- x_nor / x_abnor from halves of h ----
    float xn[2][8], xa[2][8];
    init8(xn, b_nor, c0);
    gemm2(xn, W_nor, HALF, wbuf, gq, c0);
    init8(xa, b_abnor, c0);
    gemm2(xa, W_abnor, HALF, wbuf + HALF, gq, c0);

    // ---- s = xn + xa -> wbuf (overwrites h, fully consumed) ----
    #pragma unroll
    for (int r = 0; r < 2; r++) {
        int rr = gq + 4 * r;
        float4 s0, s1;
        s0.x = xn[r][0] + xa[r][0]; s0.y = xn[r][1] + xa[r][1];
        s0.z = xn[r][2] + xa[r][2]; s0.w = xn[r][3] + xa[r][3];
        s1.x = xn[r][4] + xa[r][4]; s1.y = xn[r][5] + xa[r][5];
        s1.z = xn[r][6] + xa[r][6]; s1.w = xn[r][7] + xa[r][7];
        *(float4*)&wbuf[rr * HS_STRIDE + c0]     = s0;
        *(float4*)&wbuf[rr * HS_STRIDE + c0 + 4] = s1;
    }

    // ---- t = s @ W_att + b_att ----
    float t[2][8];
    init8(t, b_att, c0);
    gemm2(t, W_att, HID, wbuf, gq, c0);

    // ---- alpha = sigmoid(sum_c tanh(t)*v): reduce over 16 ch-group lanes ----
    float gg[2];
    {
        float4 v0 = *(const float4*)(v_att + c0);
        float4 v1 = *(const float4*)(v_att + c0 + 4);
        #pragma unroll
        for (int r = 0; r < 2; r++) {
            gg[r] = tanhf(t[r][0]) * v0.x + tanhf(t[r][1]) * v0.y
                  + tanhf(t[r][2]) * v0.z + tanhf(t[r][3]) * v0.w
                  + tanhf(t[r][4]) * v1.x + tanhf(t[r][5]) * v1.y
                  + tanhf(t[r][6]) * v1.z + tanhf(t[r][7]) * v1.w;
        }
    }
    #pragma unroll
    for (int msk = 8; msk >= 1; msk >>= 1) {
        #pragma unroll
        for (int r = 0; r < 2; r++) gg[r] += __shfl_xor(gg[r], msk, 64);
    }

    #pragma unroll
    for (int r = 0; r < 2; r++) {
        int n = wnode0 + gq + 4 * r;
        float alpha = 1.f / (1.f + expf(-gg[r]));
        float beta  = 1.f - alpha;
        float dinv  = rsqrtf((float)cnt[n] + 1.0f);  // +1 self loop
        float4 o0, o1;
        o0.x = dinv * (alpha * xn[r][0] + beta * xa[r][0]);
        o0.y = dinv * (alpha * xn[r][1] + beta * xa[r][1]);
        o0.z = dinv * (alpha * xn[r][2] + beta * xa[r][2]);
        o0.w = dinv * (alpha * xn[r][3] + beta * xa[r][3]);
        o1.x = dinv * (alpha * xn[r][4] + beta * xa[r][4]);
        o1.y = dinv * (alpha * xn[r][5] + beta * xa[r][5]);
        o1.z = dinv * (alpha * xn[r][6] + beta * xa[r][6]);
        o1.w = dinv * (alpha * xn[r][7] + beta * xa[r][7]);
        *(float4*)(u + (size_t)n * HID + c0)     = o0;
        *(float4*)(u + (size_t)n * HID + c0 + 4) = o1;
    }
}

// ------------------------------------------------------------- edge phase ---
// One wave per target node: acc[i] = u[i] + sum_{j in in(i)} u[j]
__global__ __launch_bounds__(256) void gather_kernel(
    const int* __restrict__ row_start, const int* __restrict__ csr_src,
    const float* __restrict__ u, float* __restrict__ acc)
{
    int node = blockIdx.x * 4 + (threadIdx.x >> 6);
    int lane = threadIdx.x & 63;
    if (node >= N_NODES) return;

    float2 s = *(const float2*)(u + (size_t)node * HID + lane * 2);
    int b = row_start[node], e = row_start[node + 1];
    int p = b;
    for (; p + 8 <= e; p += 8) {
        int j0 = csr_src[p + 0], j1 = csr_src[p + 1];
        int j2 = csr_src[p + 2], j3 = csr_src[p + 3];
        int j4 = csr_src[p + 4], j5 = csr_src[p + 5];
        int j6 = csr_src[p + 6], j7 = csr_src[p + 7];
        float2 v0 = *(const float2*)(u + (size_t)j0 * HID + lane * 2);
        float2 v1 = *(const float2*)(u + (size_t)j1 * HID + lane * 2);
        float2 v2 = *(const float2*)(u + (size_t)j2 * HID + lane * 2);
        float2 v3 = *(const float2*)(u + (size_t)j3 * HID + lane * 2);
        float2 v4 = *(const float2*)(u + (size_t)j4 * HID + lane * 2);
        float2 v5 = *(const float2*)(u + (size_t)j5 * HID + lane * 2);
        float2 v6 = *(const float2*)(u + (size_t)j6 * HID + lane * 2);
        float2 v7 = *(const float2*)(u + (size_t)j7 * HID + lane * 2);
        s.x += v0.x + v1.x + v2.x + v3.x + v4.x + v5.x + v6.x + v7.x;
        s.y += v0.y + v1.y + v2.y + v3.y + v4.y + v5.y + v6.y + v7.y;
    }
    for (; p < e; p++) {
        int j = csr_src[p];
        float2 v = *(const float2*)(u + (size_t)j * HID + lane * 2);
        s.x += v.x; s.y += v.y;
    }
    *(float2*)(acc + (size_t)node * HID + lane * 2) = s;
}

// ------------------------------------------------------------ final phase ---
// Same 4-wave / 8-nodes-per-wave structure, wave-private LDS, no barriers.
__global__ __launch_bounds__(256, 5) void final_phase_kernel(
    const float* __restrict__ acc, const int* __restrict__ cnt,
    const float* __restrict__ W_upd, const float* __restrict__ b_upd,
    const float* __restrict__ W_cls, const float* __restrict__ b_cls,
    float* __restrict__ out)
{
    __shared__ __align__(16) float buf[BUF_FLOATS];

    const int tid    = threadIdx.x;
    const int w      = tid >> 6;
    const int l      = tid & 63;
    const int gq     = l >> 4;
    const int m      = l & 15;
    const int c0     = m * 8;
    const int wnode0 = blockIdx.x * NBB + w * NBW;
    if (wnode0 >= N_NODES) return;

    float* wbuf = &buf[w * NBW * HS_STRIDE];
    const float* arow = acc + (size_t)wnode0 * HID;

    // stage this wave's 8 acc rows, prescaled by dinv
    #pragma unroll
    for (int it = 0; it < 4; it++) {
        int i = it * 64 + l;
        int rr = i >> 5, kq = i & 31;
        float d = rsqrtf((float)cnt[wnode0 + rr] + 1.0f);
        float4 v = *(const float4*)(arow + (size_t)rr * HID + kq * 4);
        v.x *= d; v.y *= d; v.z *= d; v.w *= d;
        *(float4*)&wbuf[rr * HS_STRIDE + kq * 4] = v;
    }

    float up[2][8];
    init8(up, b_upd, c0);
    gemm2(up, W_upd, HID, wbuf, gq, c0);

    // leaky relu -> wbuf (consumed)
    #pragma unroll
    for (int r = 0; r < 2; r++) {
        int rr = gq + 4 * r;
        float4 u0, u1;
        float v;
        v = up[r][0]; u0.x = v > 0.f ? v : SLOPE * v;
        v = up[r][1]; u0.y = v > 0.f ? v : SLOPE * v;
        v = up[r][2]; u0.z = v > 0.f ? v : SLOPE * v;
        v = up[r][3]; u0.w = v > 0.f ? v : SLOPE * v;
        v = up[r][4]; u1.x = v > 0.f ? v : SLOPE * v;
        v = up[r][5]; u1.y = v > 0.f ? v : SLOPE * v;
        v = up[r][6]; u1.z = v > 0.f ? v : SLOPE * v;
        v = up[r][7]; u1.w = v > 0.f ? v : SLOPE * v;
        *(float4*)&wbuf[rr * HS_STRIDE + c0]     = u0;
        *(float4*)&wbuf[rr * HS_STRIDE + c0 + 4] = u1;
    }

    // classifier: 16 lanes of this wave handle its 8 nodes x 2 outputs
    if (l < NBW * OUT_DIM) {
        int n = l >> 1, o = l & 1;
        float s = b_cls[o];
        for (int k = 0; k < HID; k++)
            s = fmaf(wbuf[n * HS_STRIDE + k], W_cls[k * OUT_DIM + o], s);
        out[(size_t)(wnode0 + n) * OUT_DIM + o] = s;
    }
}

// ------------------------------------------------------------------ launch --
extern "C" void kernel_launch(void* const* d_in, const int* in_sizes, int n_in,
                              void* d_out, int out_size, void* d_ws, size_t ws_size,
                              hipStream_t stream)
{
    const float* x       = (const float*)d_in[0];
    const int*   ei      = (const int*)  d_in[1];   // [2, E] int32
    const float* W_in    = (const float*)d_in[2];
    const float* b_in    = (const float*)d_in[3];
    const float* W_nor   = (const float*)d_in[4];
    const float* b_nor   = (const float*)d_in[5];
    const float* W_abnor = (const float*)d_in[6];
    const float* b_abnor = (const float*)d_in[7];
    const float* W_att   = (const float*)d_in[8];
    const float* b_att   = (const float*)d_in[9];
    const float* v_att   = (const float*)d_in[10];
    const float* W_upd   = (const float*)d_in[11];
    const float* b_upd   = (const float*)d_in[12];
    const float* W_cls   = (const float*)d_in[13];
    const float* b_cls   = (const float*)d_in[14];
    float* out = (float*)d_out;

    // workspace: cnt[N] | row_start[N+1] | csr_src[E] | u[N*HID] | acc[N*HID]
    // ticket[E] aliases acc (acc is only written by gather, after fill).
    int*   cnt       = (int*)d_ws;
    int*   row_start = cnt + N_NODES;
    int*   csr_src   = row_start + (N_NODES + 1);
    float* u         = (float*)(csr_src + E_EDGES);
    float* acc       = u + (size_t)N_NODES * HID;
    int*   ticket    = (int*)acc;

    const int nblk = (N_NODES + NBB - 1) / NBB;   // 1563

    zero_int_kernel<<<(N_NODES + 255) / 256, 256, 0, stream>>>(cnt, N_NODES);
    deg_ticket_kernel<<<(E_EDGES + 255) / 256, 256, 0, stream>>>(ei + E_EDGES, cnt, ticket);
    scan_kernel<<<1, 1024, 0, stream>>>(cnt, row_start);
    fill_kernel<<<(E_EDGES + 255) / 256, 256, 0, stream>>>(ei, row_start, ticket, csr_src);
    node_phase_kernel<<<nblk, 256, 0, stream>>>(
        x, W_in, b_in, W_nor, b_nor, W_abnor, b_abnor,
        W_att, b_att, v_att, cnt, u);
    gather_kernel<<<(N_NODES + 3) / 4, 256, 0, stream>>>(row_start, csr_src, u, acc);
    final_phase_kernel<<<nblk, 256, 0, stream>>>(
        acc, cnt, W_upd, b_upd, W_cls, b_cls, out);
}

// Round 9
// 353.602 us; speedup vs baseline: 1.3856x; 1.3856x over previous
//
#include <hip/hip_runtime.h>

#define N_NODES 50000
#define E_EDGES 800000
#define IN_DIM  256
#define HID     128
#define HALF    64
#define OUT_DIM 2
#define NW      32               // nodes per wave (8 per lane)
#define WPB     2                // waves per block
#define NBB     (NW * WPB)       // 64 nodes per block
#define SLOPE   0.01f

#define ST      132              // 128 + 4 pad: act quads hit 16 disjoint banks
#define WSLICE  (NW * ST)        // 4224 floats = 16.9 KB per wave slice

// acc[c..c+7] += xv * W[k][c..c+7]
__device__ __forceinline__ void fma8(float* acc, float xv, float4 w0, float4 w1) {
    acc[0] = fmaf(xv, w0.x, acc[0]); acc[1] = fmaf(xv, w0.y, acc[1]);
    acc[2] = fmaf(xv, w0.z, acc[2]); acc[3] = fmaf(xv, w0.w, acc[3]);
    acc[4] = fmaf(xv, w1.x, acc[4]); acc[5] = fmaf(xv, w1.y, acc[5]);
    acc[6] = fmaf(xv, w1.z, acc[6]); acc[7] = fmaf(xv, w1.w, acc[7]);
}

// one k-quad of the weight panel: 8 x float4 (4 k-rows x 8 channels)
__device__ __forceinline__ void load_w8(float4* w, const float* __restrict__ W,
                                        int k, int c0) {
    w[0] = *(const float4*)(W + (size_t)(k + 0) * HID + c0);
    w[1] = *(const float4*)(W + (size_t)(k + 0) * HID + c0 + 4);
    w[2] = *(const float4*)(W + (size_t)(k + 1) * HID + c0);
    w[3] = *(const float4*)(W + (size_t)(k + 1) * HID + c0 + 4);
    w[4] = *(const float4*)(W + (size_t)(k + 2) * HID + c0);
    w[5] = *(const float4*)(W + (size_t)(k + 2) * HID + c0 + 4);
    w[6] = *(const float4*)(W + (size_t)(k + 3) * HID + c0);
    w[7] = *(const float4*)(W + (size_t)(k + 3) * HID + c0 + 4);
}

// 8-nodes-per-lane K-panel GEMM: 256 FMAs per 8 weight loads + 8 LDS reads
__device__ __forceinline__ void gemm8(float acc[8][8], const float* __restrict__ W,
                                      int K, const float* B, int gq, int c0) {
    for (int k = 0; k < K; k += 4) {
        float4 wq[8];
        load_w8(wq, W, k, c0);
        #pragma unroll
        for (int r = 0; r < 8; r++) {
            float4 xq = *(const float4*)(B + (gq + 4 * r) * ST + k);
            fma8(acc[r], xq.x, wq[0], wq[1]);
            fma8(acc[r], xq.y, wq[2], wq[3]);
            fma8(acc[r], xq.z, wq[4], wq[5]);
            fma8(acc[r], xq.w, wq[6], wq[7]);
        }
    }
}

__device__ __forceinline__ void init88(float acc[8][8], const float* __restrict__ b, int c0) {
    float4 b0 = *(const float4*)(b + c0);
    float4 b1 = *(const float4*)(b + c0 + 4);
    #pragma unroll
    for (int r = 0; r < 8; r++) {
        acc[r][0] = b0.x; acc[r][1] = b0.y; acc[r][2] = b0.z; acc[r][3] = b0.w;
        acc[r][4] = b1.x; acc[r][5] = b1.y; acc[r][6] = b1.z; acc[r][7] = b1.w;
    }
}

// ---------------------------------------------------------------- degree ----
__global__ void zero_int_kernel(int* __restrict__ p, int n) {
    int i = blockIdx.x * blockDim.x + threadIdx.x;
    if (i < n) p[i] = 0;
}

__global__ void deg_ticket_kernel(const int* __restrict__ col,
                                  int* __restrict__ cnt, int* __restrict__ ticket) {
    int e = blockIdx.x * blockDim.x + threadIdx.x;
    if (e < E_EDGES) ticket[e] = atomicAdd(&cnt[col[e]], 1);
}

__global__ __launch_bounds__(1024) void scan_kernel(
    const int* __restrict__ cnt, int* __restrict__ row_start)
{
    __shared__ int sums[1024];
    const int T  = 1024;
    const int t  = threadIdx.x;
    const int CH = (N_NODES + T - 1) / T;   // 49
    const int base = t * CH;

    int s = 0;
    for (int k = 0; k < CH; k++) {
        int i = base + k;
        if (i < N_NODES) s += cnt[i];
    }
    sums[t] = s;
    __syncthreads();
    for (int off = 1; off < T; off <<= 1) {
        int v = (t >= off) ? sums[t - off] : 0;
        __syncthreads();
        sums[t] += v;
        __syncthreads();
    }
    int run = (t == 0) ? 0 : sums[t - 1];
    for (int k = 0; k < CH; k++) {
        int i = base + k;
        if (i < N_NODES) { row_start[i] = run; run += cnt[i]; }
    }
    if (t == T - 1) row_start[N_NODES] = run;
}

__global__ void fill_kernel(const int* __restrict__ ei,
                            const int* __restrict__ row_start,
                            const int* __restrict__ ticket,
                            int* __restrict__ csr_src)
{
    int e = blockIdx.x * blockDim.x + threadIdx.x;
    if (e >= E_EDGES) return;
    int j = ei[e];              // source
    int i = ei[E_EDGES + e];    // target
    csr_src[row_start[i] + ticket[e]] = j;
}

// ------------------------------------------------------------- node phase ---
// 128 threads = 2 waves; each wave owns 32 nodes (wave-private LDS slice, NO
// barriers). lane = (gq = l>>4, m = l&15): channels 8m..8m+7, nodes gq + 4r
// (r = 0..7). 256 FMAs per weight-quad (32:1) — weight panel amortized over
// 32 nodes (2x r6). Register plan: s -> LDS, keep d = xn - xa in regs;
// u = dinv * (0.5*s + (alpha-0.5)*d).
__global__ __launch_bounds__(128, 2) void node_phase_kernel(
    const float* __restrict__ x,
    const float* __restrict__ W_in,    const float* __restrict__ b_in,
    const float* __restrict__ W_nor,   const float* __restrict__ b_nor,
    const float* __restrict__ W_abnor, const float* __restrict__ b_abnor,
    const float* __restrict__ W_att,   const float* __restrict__ b_att,
    const float* __restrict__ v_att,
    const int* __restrict__ cnt,
    float* __restrict__ u)
{
    __shared__ __align__(16) float buf[WPB * WSLICE];   // 33.8 KB

    const int tid    = threadIdx.x;
    const int w      = tid >> 6;
    const int l      = tid & 63;
    const int gq     = l >> 4;
    const int m      = l & 15;
    const int c0     = m * 8;
    const int wnode0 = blockIdx.x * NBB + w * NW;
    if (wnode0 >= N_NODES) return;    // tail wave idle (no barriers used)

    float* B = buf + w * WSLICE;

    // ---- h = leaky_relu(x @ W_in + b_in), k staged in two 128-halves ----
    float a0[8][8];
    init88(a0, b_in, c0);
    for (int half = 0; half < 2; half++) {
        // stage this wave's 32 rows of the k-half (coalesced float4)
        #pragma unroll
        for (int it = 0; it < 16; it++) {
            int i = it * 64 + l;
            int rr = i >> 5, kq = i & 31;
            int nd = wnode0 + rr; if (nd >= N_NODES) nd = N_NODES - 1;
            float4 v = *(const float4*)(x + (size_t)nd * IN_DIM + half * 128 + kq * 4);
            *(float4*)&B[rr * ST + kq * 4] = v;
        }
        gemm8(a0, W_in + (size_t)half * 128 * HID, 128, B, gq, c0);
    }

    // ---- h -> B (leaky relu), wave-private ----
    #pragma unroll
    for (int r = 0; r < 8; r++) {
        int rr = gq + 4 * r;
        float4 h0, h1;
        float v;
        v = a0[r][0]; h0.x = v > 0.f ? v : SLOPE * v;
        v = a0[r][1]; h0.y = v > 0.f ? v : SLOPE * v;
        v = a0[r][2]; h0.z = v > 0.f ? v : SLOPE * v;
        v = a0[r][3]; h0.w = v > 0.f ? v : SLOPE * v;
        v = a0[r][4]; h1.x = v > 0.f ? v : SLOPE * v;
        v = a0[r][5]; h1.y = v > 0.f ? v : SLOPE * v;
        v = a0[r][6]; h1.z = v > 0.f ? v : SLOPE * v;
        v = a0[r][7]; h1.w = v > 0.f ? v : SLOPE * v;
        *(float4*)&B[rr * ST + c0]     = h0;
        *(float4*)&B[rr * ST + c0 + 4] = h1;
    }

    // ---- x_nor / x_abnor from halves of h (a0 regs recycled by compiler) ----
    float xn[8][8];
    init88(xn, b_nor, c0);
    gemm8(xn, W_nor, HALF, B, gq, c0);
    float xa[8][8];
    init88(xa, b_abnor, c0);
    gemm8(xa, W_abnor, HALF, B + HALF, gq, c0);

    // ---- s = xn + xa -> B; d = xn - xa stays in xn's registers ----
    #pragma unroll
    for (int r = 0; r < 8; r++) {
        int rr = gq + 4 * r;
        float4 s0, s1;
        s0.x = xn[r][0] + xa[r][0]; s0.y = xn[r][1] + xa[r][1];
        s0.z = xn[r][2] + xa[r][2]; s0.w = xn[r][3] + xa[r][3];
        s1.x = xn[r][4] + xa[r][4]; s1.y = xn[r][5] + xa[r][5];
        s1.z = xn[r][6] + xa[r][6]; s1.w = xn[r][7] + xa[r][7];
        *(float4*)&B[rr * ST + c0]     = s0;
        *(float4*)&B[rr * ST + c0 + 4] = s1;
        #pragma unroll
        for (int i = 0; i < 8; i++) xn[r][i] -= xa[r][i];   // d
    }

    // ---- t = s @ W_att + b_att ----
    float t[8][8];
    init88(t, b_att, c0);
    gemm8(t, W_att, HID, B, gq, c0);

    // ---- alpha = sigmoid(sum_c tanh(t)*v): reduce over 16 ch-group lanes ----
    float gg[8];
    {
        float4 v0 = *(const float4*)(v_att + c0);
        float4 v1 = *(const float4*)(v_att + c0 + 4);
        #pragma unroll
        for (int r = 0; r < 8; r++) {
            gg[r] = tanhf(t[r][0]) * v0.x + tanhf(t[r][1]) * v0.y
                  + tanhf(t[r][2]) * v0.z + tanhf(t[r][3]) * v0.w
                  + tanhf(t[r][4]) * v1.x + tanhf(t[r][5]) * v1.y
                  + tanhf(t[r][6]) * v1.z + tanhf(t[r][7]) * v1.w;
        }
    }
    #pragma unroll
    for (int msk = 8; msk >= 1; msk >>= 1) {
        #pragma unroll
        for (int r = 0; r < 8; r++) gg[r] += __shfl_xor(gg[r], msk, 64);
    }

    // ---- u = dinv * (0.5*s + (alpha-0.5)*d) ----
    #pragma unroll
    for (int r = 0; r < 8; r++) {
        int rr = gq + 4 * r;
        int n  = wnode0 + rr;
        if (n >= N_NODES) continue;
        float alpha = 1.f / (1.f + expf(-gg[r]));
        float am    = alpha - 0.5f;
        float dinv  = rsqrtf((float)cnt[n] + 1.0f);  // +1 self loop
        float4 s0 = *(const float4*)&B[rr * ST + c0];
        float4 s1 = *(const float4*)&B[rr * ST + c0 + 4];
        float4 o0, o1;
        o0.x = dinv * (0.5f * s0.x + am * xn[r][0]);
        o0.y = dinv * (0.5f * s0.y + am * xn[r][1]);
        o0.z = dinv * (0.5f * s0.z + am * xn[r][2]);
        o0.w = dinv * (0.5f * s0.w + am * xn[r][3]);
        o1.x = dinv * (0.5f * s1.x + am * xn[r][4]);
        o1.y = dinv * (0.5f * s1.y + am * xn[r][5]);
        o1.z = dinv * (0.5f * s1.z + am * xn[r][6]);
        o1.w = dinv * (0.5f * s1.w + am * xn[r][7]);
        *(float4*)(u + (size_t)n * HID + c0)     = o0;
        *(float4*)(u + (size_t)n * HID + c0 + 4) = o1;
    }
}

// ------------------------------------------------------------- edge phase ---
// One wave per target node: acc[i] = u[i] + sum_{j in in(i)} u[j]
__global__ __launch_bounds__(256) void gather_kernel(
    const int* __restrict__ row_start, const int* __restrict__ csr_src,
    const float* __restrict__ u, float* __restrict__ acc)
{
    int node = blockIdx.x * 4 + (threadIdx.x >> 6);
    int lane = threadIdx.x & 63;
    if (node >= N_NODES) return;

    float2 s = *(const float2*)(u + (size_t)node * HID + lane * 2);
    int b = row_start[node], e = row_start[node + 1];
    int p = b;
    for (; p + 8 <= e; p += 8) {
        int j0 = csr_src[p + 0], j1 = csr_src[p + 1];
        int j2 = csr_src[p + 2], j3 = csr_src[p + 3];
        int j4 = csr_src[p + 4], j5 = csr_src[p + 5];
        int j6 = csr_src[p + 6], j7 = csr_src[p + 7];
        float2 v0 = *(const float2*)(u + (size_t)j0 * HID + lane * 2);
        float2 v1 = *(const float2*)(u + (size_t)j1 * HID + lane * 2);
        float2 v2 = *(const float2*)(u + (size_t)j2 * HID + lane * 2);
        float2 v3 = *(const float2*)(u + (size_t)j3 * HID + lane * 2);
        float2 v4 = *(const float2*)(u + (size_t)j4 * HID + lane * 2);
        float2 v5 = *(const float2*)(u + (size_t)j5 * HID + lane * 2);
        float2 v6 = *(const float2*)(u + (size_t)j6 * HID + lane * 2);
        float2 v7 = *(const float2*)(u + (size_t)j7 * HID + lane * 2);
        s.x += v0.x + v1.x + v2.x + v3.x + v4.x + v5.x + v6.x + v7.x;
        s.y += v0.y + v1.y + v2.y + v3.y + v4.y + v5.y + v6.y + v7.y;
    }
    for (; p < e; p++) {
        int j = csr_src[p];
        float2 v = *(const float2*)(u + (size_t)j * HID + lane * 2);
        s.x += v.x; s.y += v.y;
    }
    *(float2*)(acc + (size_t)node * HID + lane * 2) = s;
}

// ------------------------------------------------------------ final phase ---
// Same 8-nodes-per-lane structure; acc staged prescaled by dinv.
__global__ __launch_bounds__(128, 2) void final_phase_kernel(
    const float* __restrict__ acc, const int* __restrict__ cnt,
    const float* __restrict__ W_upd, const float* __restrict__ b_upd,
    const float* __restrict__ W_cls, const float* __restrict__ b_cls,
    float* __restrict__ out)
{
    __shared__ __align__(16) float buf[WPB * WSLICE];

    const int tid    = threadIdx.x;
    const int w      = tid >> 6;
    const int l      = tid & 63;
    const int gq     = l >> 4;
    const int m      = l & 15;
    const int c0     = m * 8;
    const int wnode0 = blockIdx.x * NBB + w * NW;
    if (wnode0 >= N_NODES) return;

    float* B = buf + w * WSLICE;

    // stage this wave's 32 acc rows, prescaled by dinv
    #pragma unroll
    for (int it = 0; it < 16; it++) {
        int i = it * 64 + l;
        int rr = i >> 5, kq = i & 31;
        int nd = wnode0 + rr; if (nd >= N_NODES) nd = N_NODES - 1;
        float d = rsqrtf((float)cnt[nd] + 1.0f);
        float4 v = *(const float4*)(acc + (size_t)nd * HID + kq * 4);
        v.x *= d; v.y *= d; v.z *= d; v.w *= d;
        *(float4*)&B[rr * ST + kq * 4] = v;
    }

    float up[8][8];
    init88(up, b_upd, c0);
    gemm8(up, W_upd, HID, B, gq, c0);

    // leaky relu -> B (consumed)
    #pragma unroll
    for (int r = 0; r < 8; r++) {
        int rr = gq + 4 * r;
        float4 u0, u1;
        float v;
        v = up[r][0]; u0.x = v > 0.f ? v : SLOPE * v;
        v = up[r][1]; u0.y = v > 0.f ? v : SLOPE * v;
        v = up[r][2]; u0.z = v > 0.f ? v : SLOPE * v;
        v = up[r][3]; u0.w = v > 0.f ? v : SLOPE * v;
        v = up[r][4]; u1.x = v > 0.f ? v : SLOPE * v;
        v = up[r][5]; u1.y = v > 0.f ? v : SLOPE * v;
        v = up[r][6]; u1.z = v > 0.f ? v : SLOPE * v;
        v = up[r][7]; u1.w = v > 0.f ? v : SLOPE * v;
        *(float4*)&B[rr * ST + c0]     = u0;
        *(float4*)&B[rr * ST + c0 + 4] = u1;
    }

    // classifier: 64 lanes handle this wave's 32 nodes x 2 outputs
    {
        int n = l >> 1, o = l & 1;
        if (wnode0 + n < N_NODES) {
            float s = b_cls[o];
            for (int k = 0; k < HID; k++)
                s = fmaf(B[n * ST + k], W_cls[k * OUT_DIM + o], s);
            out[(size_t)(wnode0 + n) * OUT_DIM + o] = s;
        }
    }
}

// ------------------------------------------------------------------ launch --
extern "C" void kernel_launch(void* const* d_in, const int* in_sizes, int n_in,
                              void* d_out, int out_size, void* d_ws, size_t ws_size,
                              hipStream_t stream)
{
    const float* x       = (const float*)d_in[0];
    const int*   ei      = (const int*)  d_in[1];   // [2, E] int32
    const float* W_in    = (const float*)d_in[2];
    const float* b_in    = (const float*)d_in[3];
    const float* W_nor   = (const float*)d_in[4];
    const float* b_nor   = (const float*)d_in[5];
    const float* W_abnor = (const float*)d_in[6];
    const float* b_abnor = (const float*)d_in[7];
    const float* W_att   = (const float*)d_in[8];
    const float* b_att   = (const float*)d_in[9];
    const float* v_att   = (const float*)d_in[10];
    const float* W_upd   = (const float*)d_in[11];
    const float* b_upd   = (const float*)d_in[12];
    const float* W_cls   = (const float*)d_in[13];
    const float* b_cls   = (const float*)d_in[14];
    float* out = (float*)d_out;

    // workspace: cnt[N] | row_start[N+1] | csr_src[E] | u[N*HID] | acc[N*HID]
    // ticket[E] aliases acc (acc is only written by gather, after fill).
    int*   cnt       = (int*)d_ws;
    int*   row_start = cnt + N_NODES;
    int*   csr_src   = row_start + (N_NODES + 1);
    float* u         = (float*)(csr_src + E_EDGES);
    float* acc       = u + (size_t)N_NODES * HID;
    int*   ticket    = (int*)acc;

    const int nblk = (N_NODES + NBB - 1) / NBB;   // 782

    zero_int_kernel<<<(N_NODES + 255) / 256, 256, 0, stream>>>(cnt, N_NODES);
    deg_ticket_kernel<<<(E_EDGES + 255) / 256, 256, 0, stream>>>(ei + E_EDGES, cnt, ticket);
    scan_kernel<<<1, 1024, 0, stream>>>(cnt, row_start);
    fill_kernel<<<(E_EDGES + 255) / 256, 256, 0, stream>>>(ei, row_start, ticket, csr_src);
    node_phase_kernel<<<nblk, 128, 0, stream>>>(
        x, W_in, b_in, W_nor, b_nor, W_abnor, b_abnor,
        W_att, b_att, v_att, cnt, u);
    gather_kernel<<<(N_NODES + 3) / 4, 256, 0, stream>>>(row_start, csr_src, u, acc);
    final_phase_kernel<<<nblk, 128, 0, stream>>>(
        acc, cnt, W_upd, b_upd, W_cls, b_cls, out);
}

// Round 10
// 332.587 us; speedup vs baseline: 1.4732x; 1.0632x over previous
//
#include <hip/hip_runtime.h>

#define N_NODES 50000
#define E_EDGES 800000
#define IN_DIM  256
#define HID     128
#define HALF    64
#define OUT_DIM 2
#define NW      32               // nodes per wave (8 per lane)
#define SLOPE   0.01f

#define ST      132              // 128 + 4 pad: act quads broadcast conflict-free
#define WSLICE  (NW * ST)        // 4224 floats = 16.9 KB per (1-wave) block

typedef unsigned int uint32;

// acc[c..c+7] += xv * W[k][c..c+7]
__device__ __forceinline__ void fma8(float* acc, float xv, float4 w0, float4 w1) {
    acc[0] = fmaf(xv, w0.x, acc[0]); acc[1] = fmaf(xv, w0.y, acc[1]);
    acc[2] = fmaf(xv, w0.z, acc[2]); acc[3] = fmaf(xv, w0.w, acc[3]);
    acc[4] = fmaf(xv, w1.x, acc[4]); acc[5] = fmaf(xv, w1.y, acc[5]);
    acc[6] = fmaf(xv, w1.z, acc[6]); acc[7] = fmaf(xv, w1.w, acc[7]);
}

// one k-quad of the weight panel: 8 x float4 (4 k-rows x 8 channels)
__device__ __forceinline__ void load_w8(float4* w, const float* __restrict__ W,
                                        int k, int c0) {
    w[0] = *(const float4*)(W + (size_t)(k + 0) * HID + c0);
    w[1] = *(const float4*)(W + (size_t)(k + 0) * HID + c0 + 4);
    w[2] = *(const float4*)(W + (size_t)(k + 1) * HID + c0);
    w[3] = *(const float4*)(W + (size_t)(k + 1) * HID + c0 + 4);
    w[4] = *(const float4*)(W + (size_t)(k + 2) * HID + c0);
    w[5] = *(const float4*)(W + (size_t)(k + 2) * HID + c0 + 4);
    w[6] = *(const float4*)(W + (size_t)(k + 3) * HID + c0);
    w[7] = *(const float4*)(W + (size_t)(k + 3) * HID + c0 + 4);
}

// 256 FMAs against one staged weight quad
__device__ __forceinline__ void fmaq(float acc[8][8], const float4* w,
                                     const float* B, int k, int gq) {
    #pragma unroll
    for (int r = 0; r < 8; r++) {
        float4 xq = *(const float4*)(B + (gq + 4 * r) * ST + k);
        fma8(acc[r], xq.x, w[0], w[1]);
        fma8(acc[r], xq.y, w[2], w[3]);
        fma8(acc[r], xq.z, w[4], w[5]);
        fma8(acc[r], xq.w, w[6], w[7]);
    }
}

// K-panel GEMM, weights register-double-buffered (K % 8 == 0)
__device__ __forceinline__ void gemm8(float acc[8][8], const float* __restrict__ W,
                                      int K, const float* B, int gq, int c0) {
    float4 wA[8], wB[8];
    load_w8(wA, W, 0, c0);
    for (int k = 0; k < K; k += 8) {
        load_w8(wB, W, k + 4, c0);
        fmaq(acc, wA, B, k, gq);
        if (k + 8 < K) load_w8(wA, W, k + 8, c0);
        fmaq(acc, wB, B, k + 4, gq);
    }
}

__device__ __forceinline__ void init88(float acc[8][8], const float* __restrict__ b, int c0) {
    float4 b0 = *(const float4*)(b + c0);
    float4 b1 = *(const float4*)(b + c0 + 4);
    #pragma unroll
    for (int r = 0; r < 8; r++) {
        acc[r][0] = b0.x; acc[r][1] = b0.y; acc[r][2] = b0.z; acc[r][3] = b0.w;
        acc[r][4] = b1.x; acc[r][5] = b1.y; acc[r][6] = b1.z; acc[r][7] = b1.w;
    }
}

// RNE-pack two fp32 into one uint of 2 bf16 (lo -> bits 0..15)
__device__ __forceinline__ uint32 pack_bf2(float x, float y) {
    uint32 a = __float_as_uint(x); a = (a + 0x7fffu + ((a >> 16) & 1u)) >> 16;
    uint32 b = __float_as_uint(y); b = (b + 0x7fffu + ((b >> 16) & 1u)) >> 16;
    return a | (b << 16);
}

// ---------------------------------------------------------------- degree ----
__global__ void zero_int_kernel(int* __restrict__ p, int n) {
    int i = blockIdx.x * blockDim.x + threadIdx.x;
    if (i < n) p[i] = 0;
}

__global__ void deg_ticket_kernel(const int* __restrict__ col,
                                  int* __restrict__ cnt, int* __restrict__ ticket) {
    int e = blockIdx.x * blockDim.x + threadIdx.x;
    if (e < E_EDGES) ticket[e] = atomicAdd(&cnt[col[e]], 1);
}

__global__ __launch_bounds__(1024) void scan_kernel(
    const int* __restrict__ cnt, int* __restrict__ row_start)
{
    __shared__ int sums[1024];
    const int T  = 1024;
    const int t  = threadIdx.x;
    const int CH = (N_NODES + T - 1) / T;   // 49
    const int base = t * CH;

    int s = 0;
    for (int k = 0; k < CH; k++) {
        int i = base + k;
        if (i < N_NODES) s += cnt[i];
    }
    sums[t] = s;
    __syncthreads();
    for (int off = 1; off < T; off <<= 1) {
        int v = (t >= off) ? sums[t - off] : 0;
        __syncthreads();
        sums[t] += v;
        __syncthreads();
    }
    int run = (t == 0) ? 0 : sums[t - 1];
    for (int k = 0; k < CH; k++) {
        int i = base + k;
        if (i < N_NODES) { row_start[i] = run; run += cnt[i]; }
    }
    if (t == T - 1) row_start[N_NODES] = run;
}

__global__ void fill_kernel(const int* __restrict__ ei,
                            const int* __restrict__ row_start,
                            const int* __restrict__ ticket,
                            int* __restrict__ csr_src)
{
    int e = blockIdx.x * blockDim.x + threadIdx.x;
    if (e >= E_EDGES) return;
    int j = ei[e];              // source
    int i = ei[E_EDGES + e];    // target
    csr_src[row_start[i] + ticket[e]] = j;
}

// ------------------------------------------------------------- node phase ---
// ONE 64-lane wave per block, 32 nodes/wave (8 per lane): grid 1563 blocks,
// 16.9 KB LDS -> ~6 resident waves/CU. Weights reg-double-buffered.
// u is written as bf16 (2-per-uint) for the gather phase.
__global__ __launch_bounds__(64, 2) void node_phase_kernel(
    const float* __restrict__ x,
    const float* __restrict__ W_in,    const float* __restrict__ b_in,
    const float* __restrict__ W_nor,   const float* __restrict__ b_nor,
    const float* __restrict__ W_abnor, const float* __restrict__ b_abnor,
    const float* __restrict__ W_att,   const float* __restrict__ b_att,
    const float* __restrict__ v_att,
    const int* __restrict__ cnt,
    uint32* __restrict__ u)            // [N][HID/2] packed bf16 pairs
{
    __shared__ __align__(16) float B[WSLICE];   // 16.9 KB, one wave

    const int l      = threadIdx.x;
    const int gq     = l >> 4;
    const int m      = l & 15;
    const int c0     = m * 8;
    const int wnode0 = blockIdx.x * NW;

    // ---- h = leaky_relu(x @ W_in + b_in), k staged in two 128-halves ----
    float a0[8][8];
    init88(a0, b_in, c0);
    for (int half = 0; half < 2; half++) {
        #pragma unroll
        for (int it = 0; it < 16; it++) {
            int i = it * 64 + l;
            int rr = i >> 5, kq = i & 31;
            int nd = wnode0 + rr; if (nd >= N_NODES) nd = N_NODES - 1;
            float4 v = *(const float4*)(x + (size_t)nd * IN_DIM + half * 128 + kq * 4);
            *(float4*)&B[rr * ST + kq * 4] = v;
        }
        gemm8(a0, W_in + (size_t)half * 128 * HID, 128, B, gq, c0);
    }

    // ---- h -> B (leaky relu), wave-private ----
    #pragma unroll
    for (int r = 0; r < 8; r++) {
        int rr = gq + 4 * r;
        float4 h0, h1;
        float v;
        v = a0[r][0]; h0.x = v > 0.f ? v : SLOPE * v;
        v = a0[r][1]; h0.y = v > 0.f ? v : SLOPE * v;
        v = a0[r][2]; h0.z = v > 0.f ? v : SLOPE * v;
        v = a0[r][3]; h0.w = v > 0.f ? v : SLOPE * v;
        v = a0[r][4]; h1.x = v > 0.f ? v : SLOPE * v;
        v = a0[r][5]; h1.y = v > 0.f ? v : SLOPE * v;
        v = a0[r][6]; h1.z = v > 0.f ? v : SLOPE * v;
        v = a0[r][7]; h1.w = v > 0.f ? v : SLOPE * v;
        *(float4*)&B[rr * ST + c0]     = h0;
        *(float4*)&B[rr * ST + c0 + 4] = h1;
    }

    // ---- x_nor / x_abnor from halves of h ----
    float xn[8][8];
    init88(xn, b_nor, c0);
    gemm8(xn, W_nor, HALF, B, gq, c0);
    float xa[8][8];
    init88(xa, b_abnor, c0);
    gemm8(xa, W_abnor, HALF, B + HALF, gq, c0);

    // ---- s = xn + xa -> B; d = xn - xa stays in xn's registers ----
    #pragma unroll
    for (int r = 0; r < 8; r++) {
        int rr = gq + 4 * r;
        float4 s0, s1;
        s0.x = xn[r][0] + xa[r][0]; s0.y = xn[r][1] + xa[r][1];
        s0.z = xn[r][2] + xa[r][2]; s0.w = xn[r][3] + xa[r][3];
        s1.x = xn[r][4] + xa[r][4]; s1.y = xn[r][5] + xa[r][5];
        s1.z = xn[r][6] + xa[r][6]; s1.w = xn[r][7] + xa[r][7];
        *(float4*)&B[rr * ST + c0]     = s0;
        *(float4*)&B[rr * ST + c0 + 4] = s1;
        #pragma unroll
        for (int i = 0; i < 8; i++) xn[r][i] -= xa[r][i];   // d
    }

    // ---- t = s @ W_att + b_att ----
    float t[8][8];
    init88(t, b_att, c0);
    gemm8(t, W_att, HID, B, gq, c0);

    // ---- alpha = sigmoid(sum_c tanh(t)*v): reduce over 16 ch-group lanes ----
    float gg[8];
    {
        float4 v0 = *(const float4*)(v_att + c0);
        float4 v1 = *(const float4*)(v_att + c0 + 4);
        #pragma unroll
        for (int r = 0; r < 8; r++) {
            gg[r] = tanhf(t[r][0]) * v0.x + tanhf(t[r][1]) * v0.y
                  + tanhf(t[r][2]) * v0.z + tanhf(t[r][3]) * v0.w
                  + tanhf(t[r][4]) * v1.x + tanhf(t[r][5]) * v1.y
                  + tanhf(t[r][6]) * v1.z + tanhf(t[r][7]) * v1.w;
        }
    }
    #pragma unroll
    for (int msk = 8; msk >= 1; msk >>= 1) {
        #pragma unroll
        for (int r = 0; r < 8; r++) gg[r] += __shfl_xor(gg[r], msk, 64);
    }

    // ---- u = dinv * (0.5*s + (alpha-0.5)*d), packed bf16 ----
    #pragma unroll
    for (int r = 0; r < 8; r++) {
        int rr = gq + 4 * r;
        int n  = wnode0 + rr;
        if (n >= N_NODES) continue;
        float alpha = 1.f / (1.f + expf(-gg[r]));
        float am    = alpha - 0.5f;
        float dinv  = rsqrtf((float)cnt[n] + 1.0f);  // +1 self loop
        float4 s0 = *(const float4*)&B[rr * ST + c0];
        float4 s1 = *(const float4*)&B[rr * ST + c0 + 4];
        float o0 = dinv * (0.5f * s0.x + am * xn[r][0]);
        float o1 = dinv * (0.5f * s0.y + am * xn[r][1]);
        float o2 = dinv * (0.5f * s0.z + am * xn[r][2]);
        float o3 = dinv * (0.5f * s0.w + am * xn[r][3]);
        float o4 = dinv * (0.5f * s1.x + am * xn[r][4]);
        float o5 = dinv * (0.5f * s1.y + am * xn[r][5]);
        float o6 = dinv * (0.5f * s1.z + am * xn[r][6]);
        float o7 = dinv * (0.5f * s1.w + am * xn[r][7]);
        uint4 q;
        q.x = pack_bf2(o0, o1); q.y = pack_bf2(o2, o3);
        q.z = pack_bf2(o4, o5); q.w = pack_bf2(o6, o7);
        *(uint4*)(u + (size_t)n * (HID / 2) + c0 / 2) = q;
    }
}

// ------------------------------------------------------------- edge phase ---
// One wave per target node; u rows are 64 uints (2 bf16 each) = 256 B/edge.
__global__ __launch_bounds__(256) void gather_kernel(
    const int* __restrict__ row_start, const int* __restrict__ csr_src,
    const uint32* __restrict__ u, float* __restrict__ acc)
{
    int node = blockIdx.x * 4 + (threadIdx.x >> 6);
    int lane = threadIdx.x & 63;
    if (node >= N_NODES) return;

    const size_t RW = HID / 2;   // 64 uints per row
    uint32 v = u[(size_t)node * RW + lane];
    float sx = __uint_as_float(v << 16);
    float sy = __uint_as_float(v & 0xffff0000u);

    int b = row_start[node], e = row_start[node + 1];
    int p = b;
    for (; p + 8 <= e; p += 8) {
        int j0 = csr_src[p + 0], j1 = csr_src[p + 1];
        int j2 = csr_src[p + 2], j3 = csr_src[p + 3];
        int j4 = csr_src[p + 4], j5 = csr_src[p + 5];
        int j6 = csr_src[p + 6], j7 = csr_src[p + 7];
        uint32 v0 = u[(size_t)j0 * RW + lane];
        uint32 v1 = u[(size_t)j1 * RW + lane];
        uint32 v2 = u[(size_t)j2 * RW + lane];
        uint32 v3 = u[(size_t)j3 * RW + lane];
        uint32 v4 = u[(size_t)j4 * RW + lane];
        uint32 v5 = u[(size_t)j5 * RW + lane];
        uint32 v6 = u[(size_t)j6 * RW + lane];
        uint32 v7 = u[(size_t)j7 * RW + lane];
        sx += __uint_as_float(v0 << 16) + __uint_as_float(v1 << 16)
            + __uint_as_float(v2 << 16) + __uint_as_float(v3 << 16)
            + __uint_as_float(v4 << 16) + __uint_as_float(v5 << 16)
            + __uint_as_float(v6 << 16) + __uint_as_float(v7 << 16);
        sy += __uint_as_float(v0 & 0xffff0000u) + __uint_as_float(v1 & 0xffff0000u)
            + __uint_as_float(v2 & 0xffff0000u) + __uint_as_float(v3 & 0xffff0000u)
            + __uint_as_float(v4 & 0xffff0000u) + __uint_as_float(v5 & 0xffff0000u)
            + __uint_as_float(v6 & 0xffff0000u) + __uint_as_float(v7 & 0xffff0000u);
    }
    for (; p < e; p++) {
        int j = csr_src[p];
        uint32 w = u[(size_t)j * RW + lane];
        sx += __uint_as_float(w << 16);
        sy += __uint_as_float(w & 0xffff0000u);
    }
    float2 s = make_float2(sx, sy);
    *(float2*)(acc + (size_t)node * HID + lane * 2) = s;
}

// ------------------------------------------------------------ final phase ---
// One wave per 32 nodes; acc staged prescaled by dinv; gemm8 prefetches.
__global__ __launch_bounds__(64, 2) void final_phase_kernel(
    const float* __restrict__ acc, const int* __restrict__ cnt,
    const float* __restrict__ W_upd, const float* __restrict__ b_upd,
    const float* __restrict__ W_cls, const float* __restrict__ b_cls,
    float* __restrict__ out)
{
    __shared__ __align__(16) float B[WSLICE];

    const int l      = threadIdx.x;
    const int gq     = l >> 4;
    const int m      = l & 15;
    const int c0     = m * 8;
    const int wnode0 = blockIdx.x * NW;

    // stage this wave's 32 acc rows, prescaled by dinv
    #pragma unroll
    for (int it = 0; it < 16; it++) {
        int i = it * 64 + l;
        int rr = i >> 5, kq = i & 31;
        int nd = wnode0 + rr; if (nd >= N_NODES) nd = N_NODES - 1;
        float d = rsqrtf((float)cnt[nd] + 1.0f);
        float4 v = *(const float4*)(acc + (size_t)nd * HID + kq * 4);
        v.x *= d; v.y *= d; v.z *= d; v.w *= d;
        *(float4*)&B[rr * ST + kq * 4] = v;
    }

    float up[8][8];
    init88(up, b_upd, c0);
    gemm8(up, W_upd, HID, B, gq, c0);

    // leaky relu -> B (consumed)
    #pragma unroll
    for (int r = 0; r < 8; r++) {
        int rr = gq + 4 * r;
        float4 u0, u1;
        float v;
        v = up[r][0]; u0.x = v > 0.f ? v : SLOPE * v;
        v = up[r][1]; u0.y = v > 0.f ? v : SLOPE * v;
        v = up[r][2]; u0.z = v > 0.f ? v : SLOPE * v;
        v = up[r][3]; u0.w = v > 0.f ? v : SLOPE * v;
        v = up[r][4]; u1.x = v > 0.f ? v : SLOPE * v;
        v = up[r][5]; u1.y = v > 0.f ? v : SLOPE * v;
        v = up[r][6]; u1.z = v > 0.f ? v : SLOPE * v;
        v = up[r][7]; u1.w = v > 0.f ? v : SLOPE * v;
        *(float4*)&B[rr * ST + c0]     = u0;
        *(float4*)&B[rr * ST + c0 + 4] = u1;
    }

    // classifier: 64 lanes handle this wave's 32 nodes x 2 outputs
    {
        int n = l >> 1, o = l & 1;
        if (wnode0 + n < N_NODES) {
            float s = b_cls[o];
            for (int k = 0; k < HID; k++)
                s = fmaf(B[n * ST + k], W_cls[k * OUT_DIM + o], s);
            out[(size_t)(wnode0 + n) * OUT_DIM + o] = s;
        }
    }
}

// ------------------------------------------------------------------ launch --
extern "C" void kernel_launch(void* const* d_in, const int* in_sizes, int n_in,
                              void* d_out, int out_size, void* d_ws, size_t ws_size,
                              hipStream_t stream)
{
    const float* x       = (const float*)d_in[0];
    const int*   ei      = (const int*)  d_in[1];   // [2, E] int32
    const float* W_in    = (const float*)d_in[2];
    const float* b_in    = (const float*)d_in[3];
    const float* W_nor   = (const float*)d_in[4];
    const float* b_nor   = (const float*)d_in[5];
    const float* W_abnor = (const float*)d_in[6];
    const float* b_abnor = (const float*)d_in[7];
    const float* W_att   = (const float*)d_in[8];
    const float* b_att   = (const float*)d_in[9];
    const float* v_att   = (const float*)d_in[10];
    const float* W_upd   = (const float*)d_in[11];
    const float* b_upd   = (const float*)d_in[12];
    const float* W_cls   = (const float*)d_in[13];
    const float* b_cls   = (const float*)d_in[14];
    float* out = (float*)d_out;

    // workspace: cnt[N] | row_start[N+1] | csr_src[E] | u_bf16[N*HID/2 uints]
    //            | acc[N*HID] fp32.   ticket[E] aliases acc.
    char* base = (char*)d_ws;
    int*  cnt       = (int*)base;
    int*  row_start = cnt + N_NODES;
    int*  csr_src   = row_start + (N_NODES + 1);
    size_t off_u    = (((size_t)(2 * N_NODES + 1 + E_EDGES)) * 4 + 63) & ~(size_t)63;
    uint32* u       = (uint32*)(base + off_u);
    size_t off_acc  = (off_u + (size_t)N_NODES * (HID / 2) * 4 + 63) & ~(size_t)63;
    float* acc      = (float*)(base + off_acc);
    int*   ticket   = (int*)acc;

    const int nblk = (N_NODES + NW - 1) / NW;   // 1563

    zero_int_kernel<<<(N_NODES + 255) / 256, 256, 0, stream>>>(cnt, N_NODES);
    deg_ticket_kernel<<<(E_EDGES + 255) / 256, 256, 0, stream>>>(ei + E_EDGES, cnt, ticket);
    scan_kernel<<<1, 1024, 0, stream>>>(cnt, row_start);
    fill_kernel<<<(E_EDGES + 255) / 256, 256, 0, stream>>>(ei, row_start, ticket, csr_src);
    node_phase_kernel<<<nblk, 64, 0, stream>>>(
        x, W_in, b_in, W_nor, b_nor, W_abnor, b_abnor,
        W_att, b_att, v_att, cnt, u);
    gather_kernel<<<(N_NODES + 3) / 4, 256, 0, stream>>>(row_start, csr_src, u, acc);
    final_phase_kernel<<<nblk, 64, 0, stream>>>(
        acc, cnt, W_upd, b_upd, W_cls, b_cls, out);
}

// Round 11
// 277.450 us; speedup vs baseline: 1.7659x; 1.1987x over previous
//
#include <hip/hip_runtime.h>

#define N_NODES 50000
#define E_EDGES 800000
#define IN_DIM  256
#define HID     128
#define HALF    64
#define OUT_DIM 2
#define NW      32               // nodes per wave
#define SLOPE   0.01f

#define ST      132              // LDS row stride (floats)
#define WSLICE  (NW * ST)        // 4224 floats = 16.9 KB

typedef unsigned int uint32;
typedef __attribute__((ext_vector_type(8)))  __bf16 bf16x8v;
typedef __attribute__((ext_vector_type(16))) float  f32x16;

union BF8 { bf16x8v v; unsigned short s[8]; uint4 q; };

// weight-fragment table offsets (in frag units; each frag = 2 uint4: hi, lo)
#define FI_F 0        // W_in : S=16 steps, 16*4*64 = 4096 frags
#define FN_F 4096     // W_nor: S=4,  1024
#define FA_F 5120     // W_abnor: S=4, 1024
#define FT_F 6144     // W_att: S=8, 2048
#define F_TOTAL 8192  // frags -> 16384 uint4 = 256 KB

__device__ __forceinline__ uint32 rne16u(uint32 u) {
    return (u + 0x7fffu + ((u >> 16) & 1u)) >> 16;
}

// split 8 fp32 -> hi/lo bf16x8
__device__ __forceinline__ void split8(const float* f, BF8& hi, BF8& lo) {
    #pragma unroll
    for (int j = 0; j < 8; j++) {
        uint32 uu = __float_as_uint(f[j]);
        uint32 h  = rne16u(uu);
        float  fh = __uint_as_float(h << 16);
        float  r  = f[j] - fh;
        hi.s[j] = (unsigned short)h;
        lo.s[j] = (unsigned short)rne16u(__float_as_uint(r));
    }
}

__device__ __forceinline__ void mfma3(f32x16& acc, bf16x8v ah, bf16x8v al,
                                      bf16x8v bh, bf16x8v bl) {
    acc = __builtin_amdgcn_mfma_f32_32x32x16_bf16(ah, bh, acc, 0, 0, 0);
    acc = __builtin_amdgcn_mfma_f32_32x32x16_bf16(ah, bl, acc, 0, 0, 0);
    acc = __builtin_amdgcn_mfma_f32_32x32x16_bf16(al, bh, acc, 0, 0, 0);
}

// C[32 x 128] += A(LDS rows, cols aoff..aoff+16S) @ W(frags at fbase)
__device__ __forceinline__ void mfma_gemm(f32x16* acc, const float* B, int aoff,
                                          int S, int sg0, const uint4* __restrict__ F,
                                          int fbase, int l) {
    const int row = l & 31;
    const int khi = 8 * (l >> 5);
    for (int s = 0; s < S; s++) {
        int k0 = aoff + 16 * s + khi;
        float a8[8];
        *(float4*)&a8[0] = *(const float4*)&B[row * ST + k0];
        *(float4*)&a8[4] = *(const float4*)&B[row * ST + k0 + 4];
        BF8 ah, al; split8(a8, ah, al);
        #pragma unroll
        for (int t = 0; t < 4; t++) {
            int f = fbase + ((sg0 + s) * 4 + t) * 64 + l;
            BF8 bh, bl; bh.q = F[2 * f]; bl.q = F[2 * f + 1];
            mfma3(acc[t], ah.v, al.v, bh.v, bl.v);
        }
    }
}

__device__ __forceinline__ void initacc(f32x16* acc, const float* __restrict__ b, int col) {
    #pragma unroll
    for (int t = 0; t < 4; t++) {
        float bv = b[32 * t + col];
        #pragma unroll
        for (int r2 = 0; r2 < 16; r2++) acc[t][r2] = bv;
    }
}

// RNE-pack two fp32 into one uint of 2 bf16 (lo -> bits 0..15)
__device__ __forceinline__ uint32 pack_bf2(float x, float y) {
    return rne16u(__float_as_uint(x)) | (rne16u(__float_as_uint(y)) << 16);
}

// ---- legacy fp32 helpers (final_phase) ----
__device__ __forceinline__ void fma8(float* acc, float xv, float4 w0, float4 w1) {
    acc[0] = fmaf(xv, w0.x, acc[0]); acc[1] = fmaf(xv, w0.y, acc[1]);
    acc[2] = fmaf(xv, w0.z, acc[2]); acc[3] = fmaf(xv, w0.w, acc[3]);
    acc[4] = fmaf(xv, w1.x, acc[4]); acc[5] = fmaf(xv, w1.y, acc[5]);
    acc[6] = fmaf(xv, w1.z, acc[6]); acc[7] = fmaf(xv, w1.w, acc[7]);
}
__device__ __forceinline__ void load_w8(float4* w, const float* __restrict__ W, int k, int c0) {
    w[0] = *(const float4*)(W + (size_t)(k + 0) * HID + c0);
    w[1] = *(const float4*)(W + (size_t)(k + 0) * HID + c0 + 4);
    w[2] = *(const float4*)(W + (size_t)(k + 1) * HID + c0);
    w[3] = *(const float4*)(W + (size_t)(k + 1) * HID + c0 + 4);
    w[4] = *(const float4*)(W + (size_t)(k + 2) * HID + c0);
    w[5] = *(const float4*)(W + (size_t)(k + 2) * HID + c0 + 4);
    w[6] = *(const float4*)(W + (size_t)(k + 3) * HID + c0);
    w[7] = *(const float4*)(W + (size_t)(k + 3) * HID + c0 + 4);
}
__device__ __forceinline__ void fmaq(float acc[8][8], const float4* w,
                                     const float* B, int k, int gq) {
    #pragma unroll
    for (int r = 0; r < 8; r++) {
        float4 xq = *(const float4*)(B + (gq + 4 * r) * ST + k);
        fma8(acc[r], xq.x, w[0], w[1]);
        fma8(acc[r], xq.y, w[2], w[3]);
        fma8(acc[r], xq.z, w[4], w[5]);
        fma8(acc[r], xq.w, w[6], w[7]);
    }
}
__device__ __forceinline__ void gemm8(float acc[8][8], const float* __restrict__ W,
                                      int K, const float* B, int gq, int c0) {
    float4 wA[8], wB[8];
    load_w8(wA, W, 0, c0);
    for (int k = 0; k < K; k += 8) {
        load_w8(wB, W, k + 4, c0);
        fmaq(acc, wA, B, k, gq);
        if (k + 8 < K) load_w8(wA, W, k + 8, c0);
        fmaq(acc, wB, B, k + 4, gq);
    }
}
__device__ __forceinline__ void init88(float acc[8][8], const float* __restrict__ b, int c0) {
    float4 b0 = *(const float4*)(b + c0);
    float4 b1 = *(const float4*)(b + c0 + 4);
    #pragma unroll
    for (int r = 0; r < 8; r++) {
        acc[r][0] = b0.x; acc[r][1] = b0.y; acc[r][2] = b0.z; acc[r][3] = b0.w;
        acc[r][4] = b1.x; acc[r][5] = b1.y; acc[r][6] = b1.z; acc[r][7] = b1.w;
    }
}

// ---------------------------------------------------------------- degree ----
__global__ void zero_int_kernel(int* __restrict__ p, int n) {
    int i = blockIdx.x * blockDim.x + threadIdx.x;
    if (i < n) p[i] = 0;
}

__global__ void deg_ticket_kernel(const int* __restrict__ col,
                                  int* __restrict__ cnt, int* __restrict__ ticket) {
    int e = blockIdx.x * blockDim.x + threadIdx.x;
    if (e < E_EDGES) ticket[e] = atomicAdd(&cnt[col[e]], 1);
}

__global__ __launch_bounds__(1024) void scan_kernel(
    const int* __restrict__ cnt, int* __restrict__ row_start)
{
    __shared__ int sums[1024];
    const int T  = 1024;
    const int t  = threadIdx.x;
    const int CH = (N_NODES + T - 1) / T;
    const int base = t * CH;

    int s = 0;
    for (int k = 0; k < CH; k++) {
        int i = base + k;
        if (i < N_NODES) s += cnt[i];
    }
    sums[t] = s;
    __syncthreads();
    for (int off = 1; off < T; off <<= 1) {
        int v = (t >= off) ? sums[t - off] : 0;
        __syncthreads();
        sums[t] += v;
        __syncthreads();
    }
    int run = (t == 0) ? 0 : sums[t - 1];
    for (int k = 0; k < CH; k++) {
        int i = base + k;
        if (i < N_NODES) { row_start[i] = run; run += cnt[i]; }
    }
    if (t == T - 1) row_start[N_NODES] = run;
}

__global__ void fill_kernel(const int* __restrict__ ei,
                            const int* __restrict__ row_start,
                            const int* __restrict__ ticket,
                            int* __restrict__ csr_src)
{
    int e = blockIdx.x * blockDim.x + threadIdx.x;
    if (e >= E_EDGES) return;
    int j = ei[e];
    int i = ei[E_EDGES + e];
    csr_src[row_start[i] + ticket[e]] = j;
}

// ---------------------------------------------------- weight prep (split) ---
// One thread per fragment: builds hi/lo bf16 B-fragments for the MFMA GEMMs.
// B-frag layout (32x32x16): col = lane&31, k = 8*(lane>>5)+j, j=0..7.
__global__ __launch_bounds__(256) void prep_w_kernel(
    const float* __restrict__ W_in, const float* __restrict__ W_nor,
    const float* __restrict__ W_ab, const float* __restrict__ W_att,
    uint4* __restrict__ F)
{
    int idx = blockIdx.x * 256 + threadIdx.x;
    const float* W; int fbase, fi;
    if (idx < 4096)      { W = W_in;  fbase = FI_F; fi = idx; }
    else if (idx < 5120) { W = W_nor; fbase = FN_F; fi = idx - 4096; }
    else if (idx < 6144) { W = W_ab;  fbase = FA_F; fi = idx - 5120; }
    else if (idx < 8192) { W = W_att; fbase = FT_F; fi = idx - 6144; }
    else return;
    int l = fi & 63, st = fi >> 6, t = st & 3, s = st >> 2;
    int k0 = 16 * s + 8 * (l >> 5);
    int c  = 32 * t + (l & 31);
    uint32 hi[8], lo[8];
    #pragma unroll
    for (int j = 0; j < 8; j++) {
        float v = W[(size_t)(k0 + j) * HID + c];
        uint32 uu = __float_as_uint(v);
        uint32 h  = rne16u(uu);
        float  fh = __uint_as_float(h << 16);
        float  r  = v - fh;
        hi[j] = h;
        lo[j] = rne16u(__float_as_uint(r));
    }
    uint4 H, L;
    H.x = hi[0] | (hi[1] << 16); H.y = hi[2] | (hi[3] << 16);
    H.z = hi[4] | (hi[5] << 16); H.w = hi[6] | (hi[7] << 16);
    L.x = lo[0] | (lo[1] << 16); L.y = lo[2] | (lo[3] << 16);
    L.z = lo[4] | (lo[5] << 16); L.w = lo[6] | (lo[7] << 16);
    int f = fbase + fi;
    F[2 * f]     = H;
    F[2 * f + 1] = L;
}

// ------------------------------------------------------------- node phase ---
// One wave per 32 nodes; all four GEMMs via split-bf16 MFMA 32x32x16.
// D layout: col = l&31, row = (reg&3) + 8*(reg>>2) + 4*(l>>5).
__global__ __launch_bounds__(64, 2) void node_phase_kernel(
    const float* __restrict__ x,
    const float* __restrict__ b_in,  const float* __restrict__ b_nor,
    const float* __restrict__ b_abnor, const float* __restrict__ b_att,
    const float* __restrict__ v_att,
    const int* __restrict__ cnt,
    const uint4* __restrict__ F,
    uint32* __restrict__ u)            // [N][HID/2] packed bf16 pairs
{
    __shared__ __align__(16) float B[WSLICE];
    __shared__ float dinvs[NW];

    const int l      = threadIdx.x;
    const int col    = l & 31;
    const int wnode0 = blockIdx.x * NW;

    if (l < NW) {
        int nd = wnode0 + l;
        float c = (nd < N_NODES) ? (float)cnt[nd] : 0.f;
        dinvs[l] = rsqrtf(c + 1.0f);
    }

    // ---- h = leaky_relu(x @ W_in + b_in), K=256 staged in two 128-halves ----
    f32x16 hacc[4];
    initacc(hacc, b_in, col);
    for (int half = 0; half < 2; half++) {
        #pragma unroll
        for (int it = 0; it < 16; it++) {
            int i = it * 64 + l;
            int rr = i >> 5, kq = i & 31;
            int nd = wnode0 + rr; if (nd >= N_NODES) nd = N_NODES - 1;
            float4 v = *(const float4*)(x + (size_t)nd * IN_DIM + half * 128 + kq * 4);
            *(float4*)&B[rr * ST + kq * 4] = v;
        }
        mfma_gemm(hacc, B, 0, 8, half * 8, F, FI_F, l);
    }

    // ---- lrelu(h) -> B [row][col 0..127] ----
    #pragma unroll
    for (int t = 0; t < 4; t++) {
        #pragma unroll
        for (int rg = 0; rg < 16; rg++) {
            int rrow = (rg & 3) + 8 * (rg >> 2) + 4 * (l >> 5);
            float v = hacc[t][rg];
            B[rrow * ST + 32 * t + col] = v > 0.f ? v : SLOPE * v;
        }
    }

    // ---- xn = h[:, :64] @ W_nor ; xa = h[:, 64:] @ W_abnor ----
    f32x16 xn[4]; initacc(xn, b_nor, col);
    mfma_gemm(xn, B, 0, 4, 0, F, FN_F, l);
    f32x16 xa[4]; initacc(xa, b_abnor, col);
    mfma_gemm(xa, B, HALF, 4, 0, F, FA_F, l);

    // ---- s = xn+xa -> B (overwrites h); d = xn-xa in regs ----
    f32x16 d[4];
    #pragma unroll
    for (int t = 0; t < 4; t++) {
        #pragma unroll
        for (int rg = 0; rg < 16; rg++) {
            int rrow = (rg & 3) + 8 * (rg >> 2) + 4 * (l >> 5);
            float sv = xn[t][rg] + xa[t][rg];
            d[t][rg] = xn[t][rg] - xa[t][rg];
            B[rrow * ST + 32 * t + col] = sv;
        }
    }

    // ---- t = s @ W_att + b_att ----
    f32x16 tac[4]; initacc(tac, b_att, col);
    mfma_gemm(tac, B, 0, 8, 0, F, FT_F, l);

    // ---- alpha per row: g = sum_c tanh(t)*v ; reduce over 32-lane half ----
    float g[16];
    #pragma unroll
    for (int rg = 0; rg < 16; rg++) g[rg] = 0.f;
    #pragma unroll
    for (int t = 0; t < 4; t++) {
        float vv = v_att[32 * t + col];
        #pragma unroll
        for (int rg = 0; rg < 16; rg++) g[rg] += tanhf(tac[t][rg]) * vv;
    }
    #pragma unroll
    for (int msk = 16; msk >= 1; msk >>= 1) {
        #pragma unroll
        for (int rg = 0; rg < 16; rg++) g[rg] += __shfl_xor(g[rg], msk, 64);
    }
    float am[16];
    #pragma unroll
    for (int rg = 0; rg < 16; rg++)
        am[rg] = 1.f / (1.f + expf(-g[rg])) - 0.5f;

    // ---- u = dinv * (0.5*s + (alpha-0.5)*d), packed bf16 pairs ----
    #pragma unroll
    for (int t = 0; t < 4; t++) {
        #pragma unroll
        for (int rg = 0; rg < 16; rg++) {
            int rrow = (rg & 3) + 8 * (rg >> 2) + 4 * (l >> 5);
            int n    = wnode0 + rrow;
            float sv = B[rrow * ST + 32 * t + col];
            float uv = dinvs[rrow] * (0.5f * sv + am[rg] * d[t][rg]);
            float pv = __shfl_xor(uv, 1, 64);
            if (((l & 1) == 0) && n < N_NODES) {
                u[(size_t)n * (HID / 2) + 16 * t + (col >> 1)] = pack_bf2(uv, pv);
            }
        }
    }
}

// ------------------------------------------------------------- edge phase ---
__global__ __launch_bounds__(256) void gather_kernel(
    const int* __restrict__ row_start, const int* __restrict__ csr_src,
    const uint32* __restrict__ u, float* __restrict__ acc)
{
    int node = blockIdx.x * 4 + (threadIdx.x >> 6);
    int lane = threadIdx.x & 63;
    if (node >= N_NODES) return;

    const size_t RW = HID / 2;
    uint32 v = u[(size_t)node * RW + lane];
    float sx = __uint_as_float(v << 16);
    float sy = __uint_as_float(v & 0xffff0000u);

    int b = row_start[node], e = row_start[node + 1];
    int p = b;
    for (; p + 8 <= e; p += 8) {
        int j0 = csr_src[p + 0], j1 = csr_src[p + 1];
        int j2 = csr_src[p + 2], j3 = csr_src[p + 3];
        int j4 = csr_src[p + 4], j5 = csr_src[p + 5];
        int j6 = csr_src[p + 6], j7 = csr_src[p + 7];
        uint32 v0 = u[(size_t)j0 * RW + lane];
        uint32 v1 = u[(size_t)j1 * RW + lane];
        uint32 v2 = u[(size_t)j2 * RW + lane];
        uint32 v3 = u[(size_t)j3 * RW + lane];
        uint32 v4 = u[(size_t)j4 * RW + lane];
        uint32 v5 = u[(size_t)j5 * RW + lane];
        uint32 v6 = u[(size_t)j6 * RW + lane];
        uint32 v7 = u[(size_t)j7 * RW + lane];
        sx += __uint_as_float(v0 << 16) + __uint_as_float(v1 << 16)
            + __uint_as_float(v2 << 16) + __uint_as_float(v3 << 16)
            + __uint_as_float(v4 << 16) + __uint_as_float(v5 << 16)
            + __uint_as_float(v6 << 16) + __uint_as_float(v7 << 16);
        sy += __uint_as_float(v0 & 0xffff0000u) + __uint_as_float(v1 & 0xffff0000u)
            + __uint_as_float(v2 & 0xffff0000u) + __uint_as_float(v3 & 0xffff0000u)
            + __uint_as_float(v4 & 0xffff0000u) + __uint_as_float(v5 & 0xffff0000u)
            + __uint_as_float(v6 & 0xffff0000u) + __uint_as_float(v7 & 0xffff0000u);
    }
    for (; p < e; p++) {
        int j = csr_src[p];
        uint32 w = u[(size_t)j * RW + lane];
        sx += __uint_as_float(w << 16);
        sy += __uint_as_float(w & 0xffff0000u);
    }
    float2 s = make_float2(sx, sy);
    *(float2*)(acc + (size_t)node * HID + lane * 2) = s;
}

// ------------------------------------------------------------ final phase ---
__global__ __launch_bounds__(64, 2) void final_phase_kernel(
    const float* __restrict__ acc, const int* __restrict__ cnt,
    const float* __restrict__ W_upd, const float* __restrict__ b_upd,
    const float* __restrict__ W_cls, const float* __restrict__ b_cls,
    float* __restrict__ out)
{
    __shared__ __align__(16) float B[WSLICE];

    const int l      = threadIdx.x;
    const int gq     = l >> 4;
    const int m      = l & 15;
    const int c0     = m * 8;
    const int wnode0 = blockIdx.x * NW;

    #pragma unroll
    for (int it = 0; it < 16; it++) {
        int i = it * 64 + l;
        int rr = i >> 5, kq = i & 31;
        int nd = wnode0 + rr; if (nd >= N_NODES) nd = N_NODES - 1;
        float d = rsqrtf((float)cnt[nd] + 1.0f);
        float4 v = *(const float4*)(acc + (size_t)nd * HID + kq * 4);
        v.x *= d; v.y *= d; v.z *= d; v.w *= d;
        *(float4*)&B[rr * ST + kq * 4] = v;
    }

    float up[8][8];
    init88(up, b_upd, c0);
    gemm8(up, W_upd, HID, B, gq, c0);

    #pragma unroll
    for (int r = 0; r < 8; r++) {
        int rr = gq + 4 * r;
        float4 u0, u1;
        float v;
        v = up[r][0]; u0.x = v > 0.f ? v : SLOPE * v;
        v = up[r][1]; u0.y = v > 0.f ? v : SLOPE * v;
        v = up[r][2]; u0.z = v > 0.f ? v : SLOPE * v;
        v = up[r][3]; u0.w = v > 0.f ? v : SLOPE * v;
        v = up[r][4]; u1.x = v > 0.f ? v : SLOPE * v;
        v = up[r][5]; u1.y = v > 0.f ? v : SLOPE * v;
        v = up[r][6]; u1.z = v > 0.f ? v : SLOPE * v;
        v = up[r][7]; u1.w = v > 0.f ? v : SLOPE * v;
        *(float4*)&B[rr * ST + c0]     = u0;
        *(float4*)&B[rr * ST + c0 + 4] = u1;
    }

    {
        int n = l >> 1, o = l & 1;
        if (wnode0 + n < N_NODES) {
            float s = b_cls[o];
            for (int k = 0; k < HID; k++)
                s = fmaf(B[n * ST + k], W_cls[k * OUT_DIM + o], s);
            out[(size_t)(wnode0 + n) * OUT_DIM + o] = s;
        }
    }
}

// ------------------------------------------------------------------ launch --
extern "C" void kernel_launch(void* const* d_in, const int* in_sizes, int n_in,
                              void* d_out, int out_size, void* d_ws, size_t ws_size,
                              hipStream_t stream)
{
    const float* x       = (const float*)d_in[0];
    const int*   ei      = (const int*)  d_in[1];   // [2, E] int32
    const float* W_in    = (const float*)d_in[2];
    const float* b_in    = (const float*)d_in[3];
    const float* W_nor   = (const float*)d_in[4];
    const float* b_nor   = (const float*)d_in[5];
    const float* W_abnor = (const float*)d_in[6];
    const float* b_abnor = (const float*)d_in[7];
    const float* W_att   = (const float*)d_in[8];
    const float* b_att   = (const float*)d_in[9];
    const float* v_att   = (const float*)d_in[10];
    const float* W_upd   = (const float*)d_in[11];
    const float* b_upd   = (const float*)d_in[12];
    const float* W_cls   = (const float*)d_in[13];
    const float* b_cls   = (const float*)d_in[14];
    float* out = (float*)d_out;

    // ws: cnt[N] | row_start[N+1] | csr_src[E] | u_bf16[N*64 uints] | acc[N*HID] f32 | F[16384 uint4]
    // ticket[E] aliases acc.
    char* base = (char*)d_ws;
    int*  cnt       = (int*)base;
    int*  row_start = cnt + N_NODES;
    int*  csr_src   = row_start + (N_NODES + 1);
    size_t off_u    = (((size_t)(2 * N_NODES + 1 + E_EDGES)) * 4 + 63) & ~(size_t)63;
    uint32* u       = (uint32*)(base + off_u);
    size_t off_acc  = (off_u + (size_t)N_NODES * (HID / 2) * 4 + 63) & ~(size_t)63;
    float* acc      = (float*)(base + off_acc);
    int*   ticket   = (int*)acc;
    size_t off_f    = (off_acc + (size_t)N_NODES * HID * 4 + 63) & ~(size_t)63;
    uint4* F        = (uint4*)(base + off_f);

    const int nblk = (N_NODES + NW - 1) / NW;   // 1563

    zero_int_kernel<<<(N_NODES + 255) / 256, 256, 0, stream>>>(cnt, N_NODES);
    deg_ticket_kernel<<<(E_EDGES + 255) / 256, 256, 0, stream>>>(ei + E_EDGES, cnt, ticket);
    scan_kernel<<<1, 1024, 0, stream>>>(cnt, row_start);
    fill_kernel<<<(E_EDGES + 255) / 256, 256, 0, stream>>>(ei, row_start, ticket, csr_src);
    prep_w_kernel<<<F_TOTAL / 256, 256, 0, stream>>>(W_in, W_nor, W_abnor, W_att, F);
    node_phase_kernel<<<nblk, 64, 0, stream>>>(
        x, b_in, b_nor, b_abnor, b_att, v_att, cnt, F, u);
    gather_kernel<<<(N_NODES + 3) / 4, 256, 0, stream>>>(row_start, csr_src, u, acc);
    final_phase_kernel<<<nblk, 64, 0, stream>>>(
        acc, cnt, W_upd, b_upd, W_cls, b_cls, out);
}

// Round 12
// 191.010 us; speedup vs baseline: 2.5651x; 1.4525x over previous
//
#include <hip/hip_runtime.h>

#define N_NODES 50000
#define E_EDGES 800000
#define IN_DIM  256
#define HID     128
#define HALF    64
#define OUT_DIM 2
#define NW      32               // nodes per wave
#define SLOPE   0.01f

#define ST      132              // LDS row stride (floats)
#define WSLICE  (NW * ST)        // 4224 floats = 16.9 KB

#define SCAN_B  512
#define SCAN_NB ((N_NODES + SCAN_B - 1) / SCAN_B)   // 98

typedef unsigned int uint32;
typedef __attribute__((ext_vector_type(8)))  __bf16 bf16x8v;
typedef __attribute__((ext_vector_type(16))) float  f32x16;

union BF8 { bf16x8v v; unsigned short s[8]; uint4 q; };

// weight-fragment table offsets (in frag units; each frag = 2 uint4: hi, lo)
#define FI_F 0        // W_in : S=16 steps, 16*4*64 = 4096 frags
#define FN_F 4096     // W_nor: S=4,  1024
#define FA_F 5120     // W_abnor: S=4, 1024
#define FT_F 6144     // W_att: S=8, 2048
#define F_TOTAL 8192  // frags -> 16384 uint4 = 256 KB

__device__ __forceinline__ uint32 rne16u(uint32 u) {
    return (u + 0x7fffu + ((u >> 16) & 1u)) >> 16;
}

// split 8 fp32 -> hi/lo bf16x8
__device__ __forceinline__ void split8(const float* f, BF8& hi, BF8& lo) {
    #pragma unroll
    for (int j = 0; j < 8; j++) {
        uint32 uu = __float_as_uint(f[j]);
        uint32 h  = rne16u(uu);
        float  fh = __uint_as_float(h << 16);
        float  r  = f[j] - fh;
        hi.s[j] = (unsigned short)h;
        lo.s[j] = (unsigned short)rne16u(__float_as_uint(r));
    }
}

__device__ __forceinline__ void mfma3(f32x16& acc, bf16x8v ah, bf16x8v al,
                                      bf16x8v bh, bf16x8v bl) {
    acc = __builtin_amdgcn_mfma_f32_32x32x16_bf16(ah, bh, acc, 0, 0, 0);
    acc = __builtin_amdgcn_mfma_f32_32x32x16_bf16(ah, bl, acc, 0, 0, 0);
    acc = __builtin_amdgcn_mfma_f32_32x32x16_bf16(al, bh, acc, 0, 0, 0);
}

// C[32 x 128] += A(LDS rows, cols aoff..aoff+16S) @ W(frags at fbase)
__device__ __forceinline__ void mfma_gemm(f32x16* acc, const float* B, int aoff,
                                          int S, int sg0, const uint4* __restrict__ F,
                                          int fbase, int l) {
    const int row = l & 31;
    const int khi = 8 * (l >> 5);
    for (int s = 0; s < S; s++) {
        int k0 = aoff + 16 * s + khi;
        float a8[8];
        *(float4*)&a8[0] = *(const float4*)&B[row * ST + k0];
        *(float4*)&a8[4] = *(const float4*)&B[row * ST + k0 + 4];
        BF8 ah, al; split8(a8, ah, al);
        #pragma unroll
        for (int t = 0; t < 4; t++) {
            int f = fbase + ((sg0 + s) * 4 + t) * 64 + l;
            BF8 bh, bl; bh.q = F[2 * f]; bl.q = F[2 * f + 1];
            mfma3(acc[t], ah.v, al.v, bh.v, bl.v);
        }
    }
}

__device__ __forceinline__ void initacc(f32x16* acc, const float* __restrict__ b, int col) {
    #pragma unroll
    for (int t = 0; t < 4; t++) {
        float bv = b[32 * t + col];
        #pragma unroll
        for (int r2 = 0; r2 < 16; r2++) acc[t][r2] = bv;
    }
}

// RNE-pack two fp32 into one uint of 2 bf16 (lo -> bits 0..15)
__device__ __forceinline__ uint32 pack_bf2(float x, float y) {
    return rne16u(__float_as_uint(x)) | (rne16u(__float_as_uint(y)) << 16);
}

// ---- legacy fp32 helpers (final_phase) ----
__device__ __forceinline__ void fma8(float* acc, float xv, float4 w0, float4 w1) {
    acc[0] = fmaf(xv, w0.x, acc[0]); acc[1] = fmaf(xv, w0.y, acc[1]);
    acc[2] = fmaf(xv, w0.z, acc[2]); acc[3] = fmaf(xv, w0.w, acc[3]);
    acc[4] = fmaf(xv, w1.x, acc[4]); acc[5] = fmaf(xv, w1.y, acc[5]);
    acc[6] = fmaf(xv, w1.z, acc[6]); acc[7] = fmaf(xv, w1.w, acc[7]);
}
__device__ __forceinline__ void load_w8(float4* w, const float* __restrict__ W, int k, int c0) {
    w[0] = *(const float4*)(W + (size_t)(k + 0) * HID + c0);
    w[1] = *(const float4*)(W + (size_t)(k + 0) * HID + c0 + 4);
    w[2] = *(const float4*)(W + (size_t)(k + 1) * HID + c0);
    w[3] = *(const float4*)(W + (size_t)(k + 1) * HID + c0 + 4);
    w[4] = *(const float4*)(W + (size_t)(k + 2) * HID + c0);
    w[5] = *(const float4*)(W + (size_t)(k + 2) * HID + c0 + 4);
    w[6] = *(const float4*)(W + (size_t)(k + 3) * HID + c0);
    w[7] = *(const float4*)(W + (size_t)(k + 3) * HID + c0 + 4);
}
__device__ __forceinline__ void fmaq(float acc[8][8], const float4* w,
                                     const float* B, int k, int gq) {
    #pragma unroll
    for (int r = 0; r < 8; r++) {
        float4 xq = *(const float4*)(B + (gq + 4 * r) * ST + k);
        fma8(acc[r], xq.x, w[0], w[1]);
        fma8(acc[r], xq.y, w[2], w[3]);
        fma8(acc[r], xq.z, w[4], w[5]);
        fma8(acc[r], xq.w, w[6], w[7]);
    }
}
__device__ __forceinline__ void gemm8(float acc[8][8], const float* __restrict__ W,
                                      int K, const float* B, int gq, int c0) {
    float4 wA[8], wB[8];
    load_w8(wA, W, 0, c0);
    for (int k = 0; k < K; k += 8) {
        load_w8(wB, W, k + 4, c0);
        fmaq(acc, wA, B, k, gq);
        if (k + 8 < K) load_w8(wA, W, k + 8, c0);
        fmaq(acc, wB, B, k + 4, gq);
    }
}
__device__ __forceinline__ void init88(float acc[8][8], const float* __restrict__ b, int c0) {
    float4 b0 = *(const float4*)(b + c0);
    float4 b1 = *(const float4*)(b + c0 + 4);
    #pragma unroll
    for (int r = 0; r < 8; r++) {
        acc[r][0] = b0.x; acc[r][1] = b0.y; acc[r][2] = b0.z; acc[r][3] = b0.w;
        acc[r][4] = b1.x; acc[r][5] = b1.y; acc[r][6] = b1.z; acc[r][7] = b1.w;
    }
}

// ---------------------------------------------------------------- degree ----
__global__ void zero_int_kernel(int* __restrict__ p, int n) {
    int i = blockIdx.x * blockDim.x + threadIdx.x;
    if (i < n) p[i] = 0;
}

__global__ void deg_ticket_kernel(const int* __restrict__ col,
                                  int* __restrict__ cnt, int* __restrict__ ticket) {
    int e = blockIdx.x * blockDim.x + threadIdx.x;
    if (e < E_EDGES) ticket[e] = atomicAdd(&cnt[col[e]], 1);
}

// ------------------------------------------------------- 3-pass fast scan ---
__device__ __forceinline__ int wave_iscan(int v, int l) {
    #pragma unroll
    for (int off = 1; off < 64; off <<= 1) {
        int t = __shfl_up(v, off, 64);
        if (l >= off) v += t;
    }
    return v;
}

// per-block exclusive scan of 512 elements + block sum
__global__ __launch_bounds__(SCAN_B) void scan1_kernel(
    const int* __restrict__ cnt, int* __restrict__ row_start, int* __restrict__ bsum)
{
    __shared__ int wsum[SCAN_B / 64];
    int i = blockIdx.x * SCAN_B + threadIdx.x;
    int v = (i < N_NODES) ? cnt[i] : 0;
    int l = threadIdx.x & 63, w = threadIdx.x >> 6;
    int isc = wave_iscan(v, l);
    if (l == 63) wsum[w] = isc;
    __syncthreads();
    int wo = 0;
    #pragma unroll
    for (int k = 0; k < SCAN_B / 64; k++) wo += (k < w) ? wsum[k] : 0;
    if (i < N_NODES) row_start[i] = wo + isc - v;
    if (threadIdx.x == SCAN_B - 1) bsum[blockIdx.x] = wo + isc;
}

// scan the 98 block sums in place (-> exclusive offsets); write grand total
__global__ __launch_bounds__(128) void scan2_kernel(
    int* __restrict__ bsum, int* __restrict__ row_start)
{
    __shared__ int wsum[2];
    int i = threadIdx.x;
    int v = (i < SCAN_NB) ? bsum[i] : 0;
    int l = i & 63, w = i >> 6;
    int isc = wave_iscan(v, l);
    if (l == 63) wsum[w] = isc;
    __syncthreads();
    int wo = (w == 1) ? wsum[0] : 0;
    if (i < SCAN_NB) bsum[i] = wo + isc - v;
    if (i == SCAN_NB - 1) row_start[N_NODES] = wo + isc;
}

__global__ __launch_bounds__(SCAN_B) void scan3_kernel(
    const int* __restrict__ bsum, int* __restrict__ row_start)
{
    int i = blockIdx.x * SCAN_B + threadIdx.x;
    if (i < N_NODES) row_start[i] += bsum[blockIdx.x];
}

__global__ void fill_kernel(const int* __restrict__ ei,
                            const int* __restrict__ row_start,
                            const int* __restrict__ ticket,
                            int* __restrict__ csr_src)
{
    int e = blockIdx.x * blockDim.x + threadIdx.x;
    if (e >= E_EDGES) return;
    int j = ei[e];
    int i = ei[E_EDGES + e];
    csr_src[row_start[i] + ticket[e]] = j;
}

// ---------------------------------------------------- weight prep (split) ---
// B-frag layout (32x32x16): col = lane&31, k = 8*(lane>>5)+j, j=0..7.
__global__ __launch_bounds__(256) void prep_w_kernel(
    const float* __restrict__ W_in, const float* __restrict__ W_nor,
    const float* __restrict__ W_ab, const float* __restrict__ W_att,
    uint4* __restrict__ F)
{
    int idx = blockIdx.x * 256 + threadIdx.x;
    const float* W; int fbase, fi;
    if (idx < 4096)      { W = W_in;  fbase = FI_F; fi = idx; }
    else if (idx < 5120) { W = W_nor; fbase = FN_F; fi = idx - 4096; }
    else if (idx < 6144) { W = W_ab;  fbase = FA_F; fi = idx - 5120; }
    else if (idx < 8192) { W = W_att; fbase = FT_F; fi = idx - 6144; }
    else return;
    int l = fi & 63, st = fi >> 6, t = st & 3, s = st >> 2;
    int k0 = 16 * s + 8 * (l >> 5);
    int c  = 32 * t + (l & 31);
    uint32 hi[8], lo[8];
    #pragma unroll
    for (int j = 0; j < 8; j++) {
        float v = W[(size_t)(k0 + j) * HID + c];
        uint32 uu = __float_as_uint(v);
        uint32 h  = rne16u(uu);
        float  fh = __uint_as_float(h << 16);
        float  r  = v - fh;
        hi[j] = h;
        lo[j] = rne16u(__float_as_uint(r));
    }
    uint4 H, L;
    H.x = hi[0] | (hi[1] << 16); H.y = hi[2] | (hi[3] << 16);
    H.z = hi[4] | (hi[5] << 16); H.w = hi[6] | (hi[7] << 16);
    L.x = lo[0] | (lo[1] << 16); L.y = lo[2] | (lo[3] << 16);
    L.z = lo[4] | (lo[5] << 16); L.w = lo[6] | (lo[7] << 16);
    int f = fbase + fi;
    F[2 * f]     = H;
    F[2 * f + 1] = L;
}

// ------------------------------------------------------------- node phase ---
// One wave per 32 nodes; all four GEMMs via split-bf16 MFMA 32x32x16.
// D layout: col = l&31, row = (reg&3) + 8*(reg>>2) + 4*(l>>5).
__global__ __launch_bounds__(64, 2) void node_phase_kernel(
    const float* __restrict__ x,
    const float* __restrict__ b_in,  const float* __restrict__ b_nor,
    const float* __restrict__ b_abnor, const float* __restrict__ b_att,
    const float* __restrict__ v_att,
    const int* __restrict__ cnt,
    const uint4* __restrict__ F,
    uint32* __restrict__ u)            // [N][HID/2] packed bf16 pairs
{
    __shared__ __align__(16) float B[WSLICE];
    __shared__ float dinvs[NW];

    const int l      = threadIdx.x;
    const int col    = l & 31;
    const int wnode0 = blockIdx.x * NW;

    if (l < NW) {
        int nd = wnode0 + l;
        float c = (nd < N_NODES) ? (float)cnt[nd] : 0.f;
        dinvs[l] = rsqrtf(c + 1.0f);
    }

    // ---- h = leaky_relu(x @ W_in + b_in), K=256 staged in two 128-halves ----
    f32x16 hacc[4];
    initacc(hacc, b_in, col);
    for (int half = 0; half < 2; half++) {
        #pragma unroll
        for (int it = 0; it < 16; it++) {
            int i = it * 64 + l;
            int rr = i >> 5, kq = i & 31;
            int nd = wnode0 + rr; if (nd >= N_NODES) nd = N_NODES - 1;
            float4 v = *(const float4*)(x + (size_t)nd * IN_DIM + half * 128 + kq * 4);
            *(float4*)&B[rr * ST + kq * 4] = v;
        }
        mfma_gemm(hacc, B, 0, 8, half * 8, F, FI_F, l);
    }

    // ---- lrelu(h) -> B [row][col 0..127] ----
    #pragma unroll
    for (int t = 0; t < 4; t++) {
        #pragma unroll
        for (int rg = 0; rg < 16; rg++) {
            int rrow = (rg & 3) + 8 * (rg >> 2) + 4 * (l >> 5);
            float v = hacc[t][rg];
            B[rrow * ST + 32 * t + col] = v > 0.f ? v : SLOPE * v;
        }
    }

    // ---- xn = h[:, :64] @ W_nor ; xa = h[:, 64:] @ W_abnor ----
    f32x16 xn[4]; initacc(xn, b_nor, col);
    mfma_gemm(xn, B, 0, 4, 0, F, FN_F, l);
    f32x16 xa[4]; initacc(xa, b_abnor, col);
    mfma_gemm(xa, B, HALF, 4, 0, F, FA_F, l);

    // ---- s = xn+xa -> B (overwrites h); d = xn-xa in regs ----
    f32x16 d[4];
    #pragma unroll
    for (int t = 0; t < 4; t++) {
        #pragma unroll
        for (int rg = 0; rg < 16; rg++) {
            int rrow = (rg & 3) + 8 * (rg >> 2) + 4 * (l >> 5);
            float sv = xn[t][rg] + xa[t][rg];
            d[t][rg] = xn[t][rg] - xa[t][rg];
            B[rrow * ST + 32 * t + col] = sv;
        }
    }

    // ---- t = s @ W_att + b_att ----
    f32x16 tac[4]; initacc(tac, b_att, col);
    mfma_gemm(tac, B, 0, 8, 0, F, FT_F, l);

    // ---- alpha per row: g = sum_c tanh(t)*v ; reduce over 32-lane half ----
    float g[16];
    #pragma unroll
    for (int rg = 0; rg < 16; rg++) g[rg] = 0.f;
    #pragma unroll
    for (int t = 0; t < 4; t++) {
        float vv = v_att[32 * t + col];
        #pragma unroll
        for (int rg = 0; rg < 16; rg++) g[rg] += tanhf(tac[t][rg]) * vv;
    }
    #pragma unroll
    for (int msk = 16; msk >= 1; msk >>= 1) {
        #pragma unroll
        for (int rg = 0; rg < 16; rg++) g[rg] += __shfl_xor(g[rg], msk, 64);
    }
    float am[16];
    #pragma unroll
    for (int rg = 0; rg < 16; rg++)
        am[rg] = 1.f / (1.f + expf(-g[rg])) - 0.5f;

    // ---- u = dinv * (0.5*s + (alpha-0.5)*d), packed bf16 pairs ----
    #pragma unroll
    for (int t = 0; t < 4; t++) {
        #pragma unroll
        for (int rg = 0; rg < 16; rg++) {
            int rrow = (rg & 3) + 8 * (rg >> 2) + 4 * (l >> 5);
            int n    = wnode0 + rrow;
            float sv = B[rrow * ST + 32 * t + col];
            float uv = dinvs[rrow] * (0.5f * sv + am[rg] * d[t][rg]);
            float pv = __shfl_xor(uv, 1, 64);
            if (((l & 1) == 0) && n < N_NODES) {
                u[(size_t)n * (HID / 2) + 16 * t + (col >> 1)] = pack_bf2(uv, pv);
            }
        }
    }
}

// ------------------------------------------------------------- edge phase ---
__global__ __launch_bounds__(256) void gather_kernel(
    const int* __restrict__ row_start, const int* __restrict__ csr_src,
    const uint32* __restrict__ u, float* __restrict__ acc)
{
    int node = blockIdx.x * 4 + (threadIdx.x >> 6);
    int lane = threadIdx.x & 63;
    if (node >= N_NODES) return;

    const size_t RW = HID / 2;
    uint32 v = u[(size_t)node * RW + lane];
    float sx = __uint_as_float(v << 16);
    float sy = __uint_as_float(v & 0xffff0000u);

    int b = row_start[node], e = row_start[node + 1];
    int p = b;
    for (; p + 8 <= e; p += 8) {
        int j0 = csr_src[p + 0], j1 = csr_src[p + 1];
        int j2 = csr_src[p + 2], j3 = csr_src[p + 3];
        int j4 = csr_src[p + 4], j5 = csr_src[p + 5];
        int j6 = csr_src[p + 6], j7 = csr_src[p + 7];
        uint32 v0 = u[(size_t)j0 * RW + lane];
        uint32 v1 = u[(size_t)j1 * RW + lane];
        uint32 v2 = u[(size_t)j2 * RW + lane];
        uint32 v3 = u[(size_t)j3 * RW + lane];
        uint32 v4 = u[(size_t)j4 * RW + lane];
        uint32 v5 = u[(size_t)j5 * RW + lane];
        uint32 v6 = u[(size_t)j6 * RW + lane];
        uint32 v7 = u[(size_t)j7 * RW + lane];
        sx += __uint_as_float(v0 << 16) + __uint_as_float(v1 << 16)
            + __uint_as_float(v2 << 16) + __uint_as_float(v3 << 16)
            + __uint_as_float(v4 << 16) + __uint_as_float(v5 << 16)
            + __uint_as_float(v6 << 16) + __uint_as_float(v7 << 16);
        sy += __uint_as_float(v0 & 0xffff0000u) + __uint_as_float(v1 & 0xffff0000u)
            + __uint_as_float(v2 & 0xffff0000u) + __uint_as_float(v3 & 0xffff0000u)
            + __uint_as_float(v4 & 0xffff0000u) + __uint_as_float(v5 & 0xffff0000u)
            + __uint_as_float(v6 & 0xffff0000u) + __uint_as_float(v7 & 0xffff0000u);
    }
    for (; p < e; p++) {
        int j = csr_src[p];
        uint32 w = u[(size_t)j * RW + lane];
        sx += __uint_as_float(w << 16);
        sy += __uint_as_float(w & 0xffff0000u);
    }
    float2 s = make_float2(sx, sy);
    *(float2*)(acc + (size_t)node * HID + lane * 2) = s;
}

// ------------------------------------------------------------ final phase ---
__global__ __launch_bounds__(64, 2) void final_phase_kernel(
    const float* __restrict__ acc, const int* __restrict__ cnt,
    const float* __restrict__ W_upd, const float* __restrict__ b_upd,
    const float* __restrict__ W_cls, const float* __restrict__ b_cls,
    float* __restrict__ out)
{
    __shared__ __align__(16) float B[WSLICE];

    const int l      = threadIdx.x;
    const int gq     = l >> 4;
    const int m      = l & 15;
    const int c0     = m * 8;
    const int wnode0 = blockIdx.x * NW;

    #pragma unroll
    for (int it = 0; it < 16; it++) {
        int i = it * 64 + l;
        int rr = i >> 5, kq = i & 31;
        int nd = wnode0 + rr; if (nd >= N_NODES) nd = N_NODES - 1;
        float d = rsqrtf((float)cnt[nd] + 1.0f);
        float4 v = *(const float4*)(acc + (size_t)nd * HID + kq * 4);
        v.x *= d; v.y *= d; v.z *= d; v.w *= d;
        *(float4*)&B[rr * ST + kq * 4] = v;
    }

    float up[8][8];
    init88(up, b_upd, c0);
    gemm8(up, W_upd, HID, B, gq, c0);

    #pragma unroll
    for (int r = 0; r < 8; r++) {
        int rr = gq + 4 * r;
        float4 u0, u1;
        float v;
        v = up[r][0]; u0.x = v > 0.f ? v : SLOPE * v;
        v = up[r][1]; u0.y = v > 0.f ? v : SLOPE * v;
        v = up[r][2]; u0.z = v > 0.f ? v : SLOPE * v;
        v = up[r][3]; u0.w = v > 0.f ? v : SLOPE * v;
        v = up[r][4]; u1.x = v > 0.f ? v : SLOPE * v;
        v = up[r][5]; u1.y = v > 0.f ? v : SLOPE * v;
        v = up[r][6]; u1.z = v > 0.f ? v : SLOPE * v;
        v = up[r][7]; u1.w = v > 0.f ? v : SLOPE * v;
        *(float4*)&B[rr * ST + c0]     = u0;
        *(float4*)&B[rr * ST + c0 + 4] = u1;
    }

    {
        int n = l >> 1, o = l & 1;
        if (wnode0 + n < N_NODES) {
            float s = b_cls[o];
            for (int k = 0; k < HID; k++)
                s = fmaf(B[n * ST + k], W_cls[k * OUT_DIM + o], s);
            out[(size_t)(wnode0 + n) * OUT_DIM + o] = s;
        }
    }
}

// ------------------------------------------------------------------ launch --
extern "C" void kernel_launch(void* const* d_in, const int* in_sizes, int n_in,
                              void* d_out, int out_size, void* d_ws, size_t ws_size,
                              hipStream_t stream)
{
    const float* x       = (const float*)d_in[0];
    const int*   ei      = (const int*)  d_in[1];   // [2, E] int32
    const float* W_in    = (const float*)d_in[2];
    const float* b_in    = (const float*)d_in[3];
    const float* W_nor   = (const float*)d_in[4];
    const float* b_nor   = (const float*)d_in[5];
    const float* W_abnor = (const float*)d_in[6];
    const float* b_abnor = (const float*)d_in[7];
    const float* W_att   = (const float*)d_in[8];
    const float* b_att   = (const float*)d_in[9];
    const float* v_att   = (const float*)d_in[10];
    const float* W_upd   = (const float*)d_in[11];
    const float* b_upd   = (const float*)d_in[12];
    const float* W_cls   = (const float*)d_in[13];
    const float* b_cls   = (const float*)d_in[14];
    float* out = (float*)d_out;

    // ws: cnt[N] | row_start[N+1] | bsum[128] | csr_src[E] | u_bf16[N*64 uints]
    //     | acc[N*HID] f32 | F[16384 uint4].   ticket[E] aliases acc.
    char* base = (char*)d_ws;
    int*  cnt       = (int*)base;
    int*  row_start = cnt + N_NODES;
    int*  bsum      = row_start + (N_NODES + 1);
    int*  csr_src   = bsum + 128;
    size_t off_u    = (((size_t)(2 * N_NODES + 129 + E_EDGES)) * 4 + 63) & ~(size_t)63;
    uint32* u       = (uint32*)(base + off_u);
    size_t off_acc  = (off_u + (size_t)N_NODES * (HID / 2) * 4 + 63) & ~(size_t)63;
    float* acc      = (float*)(base + off_acc);
    int*   ticket   = (int*)acc;
    size_t off_f    = (off_acc + (size_t)N_NODES * HID * 4 + 63) & ~(size_t)63;
    uint4* F        = (uint4*)(base + off_f);

    const int nblk = (N_NODES + NW - 1) / NW;   // 1563

    zero_int_kernel<<<(N_NODES + 255) / 256, 256, 0, stream>>>(cnt, N_NODES);
    deg_ticket_kernel<<<(E_EDGES + 255) / 256, 256, 0, stream>>>(ei + E_EDGES, cnt, ticket);
    scan1_kernel<<<SCAN_NB, SCAN_B, 0, stream>>>(cnt, row_start, bsum);
    scan2_kernel<<<1, 128, 0, stream>>>(bsum, row_start);
    scan3_kernel<<<SCAN_NB, SCAN_B, 0, stream>>>(bsum, row_start);
    fill_kernel<<<(E_EDGES + 255) / 256, 256, 0, stream>>>(ei, row_start, ticket, csr_src);
    prep_w_kernel<<<F_TOTAL / 256, 256, 0, stream>>>(W_in, W_nor, W_abnor, W_att, F);
    node_phase_kernel<<<nblk, 64, 0, stream>>>(
        x, b_in, b_nor, b_abnor, b_att, v_att, cnt, F, u);
    gather_kernel<<<(N_NODES + 3) / 4, 256, 0, stream>>>(row_start, csr_src, u, acc);
    final_phase_kernel<<<nblk, 64, 0, stream>>>(
        acc, cnt, W_upd, b_upd, W_cls, b_cls, out);
}

// Round 13
// 174.242 us; speedup vs baseline: 2.8119x; 1.0962x over previous
//
#include <hip/hip_runtime.h>

#define N_NODES 50000
#define E_EDGES 800000
#define IN_DIM  256
#define HID     128
#define HALF    64
#define OUT_DIM 2
#define NW      32               // nodes per block tile
#define SLOPE   0.01f

#define ST      132              // LDS row stride (floats)
#define WSLICE  (NW * ST)        // 4224 floats = 16.9 KB

#define SCAN_B  512
#define SCAN_NB ((N_NODES + SCAN_B - 1) / SCAN_B)   // 98

typedef unsigned int uint32;
typedef __attribute__((ext_vector_type(8)))  __bf16 bf16x8v;
typedef __attribute__((ext_vector_type(16))) float  f32x16;

union BF8 { bf16x8v v; unsigned short s[8]; uint4 q; };

// weight-fragment table offsets (frag = 2 uint4: hi, lo)
#define FI_F 0        // W_in : S=16 -> 4096 frags
#define FN_F 4096     // W_nor: S=4  -> 1024
#define FA_F 5120     // W_abnor: S=4 -> 1024
#define FT_F 6144     // W_att: S=8 -> 2048
#define FU_F 8192     // W_upd: S=8 -> 2048
#define F_TOTAL 10240 // 20480 uint4 = 320 KB

__device__ __forceinline__ uint32 rne16u(uint32 u) {
    return (u + 0x7fffu + ((u >> 16) & 1u)) >> 16;
}

__device__ __forceinline__ void split8(const float* f, BF8& hi, BF8& lo) {
    #pragma unroll
    for (int j = 0; j < 8; j++) {
        uint32 uu = __float_as_uint(f[j]);
        uint32 h  = rne16u(uu);
        float  fh = __uint_as_float(h << 16);
        float  r  = f[j] - fh;
        hi.s[j] = (unsigned short)h;
        lo.s[j] = (unsigned short)rne16u(__float_as_uint(r));
    }
}

__device__ __forceinline__ void mfma3(f32x16& acc, bf16x8v ah, bf16x8v al,
                                      bf16x8v bh, bf16x8v bl) {
    acc = __builtin_amdgcn_mfma_f32_32x32x16_bf16(ah, bh, acc, 0, 0, 0);
    acc = __builtin_amdgcn_mfma_f32_32x32x16_bf16(ah, bl, acc, 0, 0, 0);
    acc = __builtin_amdgcn_mfma_f32_32x32x16_bf16(al, bh, acc, 0, 0, 0);
}

// 4-tile (full 128-col) GEMM: one wave does all t=0..3
__device__ __forceinline__ void mfma_gemm(f32x16* acc, const float* B, int aoff,
                                          int S, int sg0, const uint4* __restrict__ F,
                                          int fbase, int l) {
    const int row = l & 31;
    const int khi = 8 * (l >> 5);
    for (int s = 0; s < S; s++) {
        int k0 = aoff + 16 * s + khi;
        float a8[8];
        *(float4*)&a8[0] = *(const float4*)&B[row * ST + k0];
        *(float4*)&a8[4] = *(const float4*)&B[row * ST + k0 + 4];
        BF8 ah, al; split8(a8, ah, al);
        #pragma unroll
        for (int t = 0; t < 4; t++) {
            int f = fbase + ((sg0 + s) * 4 + t) * 64 + l;
            BF8 bh, bl; bh.q = F[2 * f]; bl.q = F[2 * f + 1];
            mfma3(acc[t], ah.v, al.v, bh.v, bl.v);
        }
    }
}

// 2-tile GEMM: wave handles t = t0, t0+1 (64 output cols)
__device__ __forceinline__ void mfma_gemm2(f32x16* acc, const float* B, int aoff,
                                           int S, int sg0, const uint4* __restrict__ F,
                                           int fbase, int l, int t0) {
    const int row = l & 31;
    const int khi = 8 * (l >> 5);
    for (int s = 0; s < S; s++) {
        int k0 = aoff + 16 * s + khi;
        float a8[8];
        *(float4*)&a8[0] = *(const float4*)&B[row * ST + k0];
        *(float4*)&a8[4] = *(const float4*)&B[row * ST + k0 + 4];
        BF8 ah, al; split8(a8, ah, al);
        #pragma unroll
        for (int tt = 0; tt < 2; tt++) {
            int f = fbase + ((sg0 + s) * 4 + t0 + tt) * 64 + l;
            BF8 bh, bl; bh.q = F[2 * f]; bl.q = F[2 * f + 1];
            mfma3(acc[tt], ah.v, al.v, bh.v, bl.v);
        }
    }
}

__device__ __forceinline__ void initacc(f32x16* acc, const float* __restrict__ b, int col) {
    #pragma unroll
    for (int t = 0; t < 4; t++) {
        float bv = b[32 * t + col];
        #pragma unroll
        for (int r2 = 0; r2 < 16; r2++) acc[t][r2] = bv;
    }
}

__device__ __forceinline__ void initacc2(f32x16* acc, const float* __restrict__ b,
                                         int col, int t0) {
    #pragma unroll
    for (int tt = 0; tt < 2; tt++) {
        float bv = b[32 * (t0 + tt) + col];
        #pragma unroll
        for (int r2 = 0; r2 < 16; r2++) acc[tt][r2] = bv;
    }
}

__device__ __forceinline__ uint32 pack_bf2(float x, float y) {
    return rne16u(__float_as_uint(x)) | (rne16u(__float_as_uint(y)) << 16);
}

// ---------------------------------------------------------------- degree ----
__global__ void zero_int_kernel(int* __restrict__ p, int n) {
    int i = blockIdx.x * blockDim.x + threadIdx.x;
    if (i < n) p[i] = 0;
}

__global__ void deg_ticket_kernel(const int* __restrict__ col,
                                  int* __restrict__ cnt, int* __restrict__ ticket) {
    int e = blockIdx.x * blockDim.x + threadIdx.x;
    if (e < E_EDGES) ticket[e] = atomicAdd(&cnt[col[e]], 1);
}

// ------------------------------------------------------- 3-pass fast scan ---
__device__ __forceinline__ int wave_iscan(int v, int l) {
    #pragma unroll
    for (int off = 1; off < 64; off <<= 1) {
        int t = __shfl_up(v, off, 64);
        if (l >= off) v += t;
    }
    return v;
}

__global__ __launch_bounds__(SCAN_B) void scan1_kernel(
    const int* __restrict__ cnt, int* __restrict__ row_start, int* __restrict__ bsum)
{
    __shared__ int wsum[SCAN_B / 64];
    int i = blockIdx.x * SCAN_B + threadIdx.x;
    int v = (i < N_NODES) ? cnt[i] : 0;
    int l = threadIdx.x & 63, w = threadIdx.x >> 6;
    int isc = wave_iscan(v, l);
    if (l == 63) wsum[w] = isc;
    __syncthreads();
    int wo = 0;
    #pragma unroll
    for (int k = 0; k < SCAN_B / 64; k++) wo += (k < w) ? wsum[k] : 0;
    if (i < N_NODES) row_start[i] = wo + isc - v;
    if (threadIdx.x == SCAN_B - 1) bsum[blockIdx.x] = wo + isc;
}

__global__ __launch_bounds__(128) void scan2_kernel(
    int* __restrict__ bsum, int* __restrict__ row_start)
{
    __shared__ int wsum[2];
    int i = threadIdx.x;
    int v = (i < SCAN_NB) ? bsum[i] : 0;
    int l = i & 63, w = i >> 6;
    int isc = wave_iscan(v, l);
    if (l == 63) wsum[w] = isc;
    __syncthreads();
    int wo = (w == 1) ? wsum[0] : 0;
    if (i < SCAN_NB) bsum[i] = wo + isc - v;
    if (i == SCAN_NB - 1) row_start[N_NODES] = wo + isc;
}

__global__ __launch_bounds__(SCAN_B) void scan3_kernel(
    const int* __restrict__ bsum, int* __restrict__ row_start)
{
    int i = blockIdx.x * SCAN_B + threadIdx.x;
    if (i < N_NODES) row_start[i] += bsum[blockIdx.x];
}

__global__ void fill_kernel(const int* __restrict__ ei,
                            const int* __restrict__ row_start,
                            const int* __restrict__ ticket,
                            int* __restrict__ csr_src)
{
    int e = blockIdx.x * blockDim.x + threadIdx.x;
    if (e >= E_EDGES) return;
    int j = ei[e];
    int i = ei[E_EDGES + e];
    csr_src[row_start[i] + ticket[e]] = j;
}

// ---------------------------------------------------- weight prep (split) ---
// B-frag layout (32x32x16): col = lane&31, k = 8*(lane>>5)+j.
__global__ __launch_bounds__(256) void prep_w_kernel(
    const float* __restrict__ W_in, const float* __restrict__ W_nor,
    const float* __restrict__ W_ab, const float* __restrict__ W_att,
    const float* __restrict__ W_upd,
    uint4* __restrict__ F)
{
    int idx = blockIdx.x * 256 + threadIdx.x;
    const float* W; int fbase, fi;
    if (idx < 4096)       { W = W_in;  fbase = FI_F; fi = idx; }
    else if (idx < 5120)  { W = W_nor; fbase = FN_F; fi = idx - 4096; }
    else if (idx < 6144)  { W = W_ab;  fbase = FA_F; fi = idx - 5120; }
    else if (idx < 8192)  { W = W_att; fbase = FT_F; fi = idx - 6144; }
    else if (idx < 10240) { W = W_upd; fbase = FU_F; fi = idx - 8192; }
    else return;
    int l = fi & 63, st = fi >> 6, t = st & 3, s = st >> 2;
    int k0 = 16 * s + 8 * (l >> 5);
    int c  = 32 * t + (l & 31);
    uint32 hi[8], lo[8];
    #pragma unroll
    for (int j = 0; j < 8; j++) {
        float v = W[(size_t)(k0 + j) * HID + c];
        uint32 uu = __float_as_uint(v);
        uint32 h  = rne16u(uu);
        float  fh = __uint_as_float(h << 16);
        float  r  = v - fh;
        hi[j] = h;
        lo[j] = rne16u(__float_as_uint(r));
    }
    uint4 H, L;
    H.x = hi[0] | (hi[1] << 16); H.y = hi[2] | (hi[3] << 16);
    H.z = hi[4] | (hi[5] << 16); H.w = hi[6] | (hi[7] << 16);
    L.x = lo[0] | (lo[1] << 16); L.y = lo[2] | (lo[3] << 16);
    L.z = lo[4] | (lo[5] << 16); L.w = lo[6] | (lo[7] << 16);
    int f = fbase + fi;
    F[2 * f]     = H;
    F[2 * f + 1] = L;
}

// ------------------------------------------------------------- node phase ---
// 128 threads = 2 waves per 32-node tile. Wave w owns output cols 64w..64w+63
// (t = 2w, 2w+1). Shared B tile with barriers; per-wave MFMA and F-traffic
// halved vs 1-wave. D layout: col=l&31, row=(rg&3)+8*(rg>>2)+4*(l>>5).
__global__ __launch_bounds__(128, 2) void node_phase_kernel(
    const float* __restrict__ x,
    const float* __restrict__ b_in,  const float* __restrict__ b_nor,
    const float* __restrict__ b_abnor, const float* __restrict__ b_att,
    const float* __restrict__ v_att,
    const int* __restrict__ cnt,
    const uint4* __restrict__ F,
    uint32* __restrict__ u)            // [N][HID/2] packed bf16 pairs
{
    __shared__ __align__(16) float B[WSLICE];
    __shared__ float dinvs[NW];
    __shared__ float gpart[2][NW];

    const int tid    = threadIdx.x;
    const int w      = tid >> 6;
    const int l      = tid & 63;
    const int col    = l & 31;
    const int hi     = l >> 5;
    const int t0     = 2 * w;
    const int wnode0 = blockIdx.x * NW;

    if (tid < NW) {
        int nd = wnode0 + tid;
        float c = (nd < N_NODES) ? (float)cnt[nd] : 0.f;
        dinvs[tid] = rsqrtf(c + 1.0f);
    }

    // ---- h = leaky_relu(x @ W_in + b_in), K=256 in two 128-halves ----
    f32x16 hacc[2];
    initacc2(hacc, b_in, col, t0);
    for (int half = 0; half < 2; half++) {
        __syncthreads();
        #pragma unroll
        for (int it = 0; it < 8; it++) {
            int i = it * 128 + tid;          // 1024 float4 of the tile
            int rr = i >> 5, kq = i & 31;
            int nd = wnode0 + rr; if (nd >= N_NODES) nd = N_NODES - 1;
            float4 v = *(const float4*)(x + (size_t)nd * IN_DIM + half * 128 + kq * 4);
            *(float4*)&B[rr * ST + kq * 4] = v;
        }
        __syncthreads();
        mfma_gemm2(hacc, B, 0, 8, half * 8, F, FI_F, l, t0);
    }
    __syncthreads();   // both waves done reading x tile

    // ---- lrelu(h) -> B cols [64w, 64w+64) ----
    #pragma unroll
    for (int tt = 0; tt < 2; tt++) {
        #pragma unroll
        for (int rg = 0; rg < 16; rg++) {
            int rrow = (rg & 3) + 8 * (rg >> 2) + 4 * hi;
            float v = hacc[tt][rg];
            B[rrow * ST + 32 * (t0 + tt) + col] = v > 0.f ? v : SLOPE * v;
        }
    }
    __syncthreads();

    // ---- xn = h[:, :64] @ W_nor ; xa = h[:, 64:] @ W_abnor ----
    f32x16 xn[2]; initacc2(xn, b_nor, col, t0);
    mfma_gemm2(xn, B, 0, 4, 0, F, FN_F, l, t0);
    f32x16 xa[2]; initacc2(xa, b_abnor, col, t0);
    mfma_gemm2(xa, B, HALF, 4, 0, F, FA_F, l, t0);
    __syncthreads();   // done reading h

    // ---- s = xn+xa -> B; d = xn-xa in regs ----
    f32x16 d[2];
    #pragma unroll
    for (int tt = 0; tt < 2; tt++) {
        #pragma unroll
        for (int rg = 0; rg < 16; rg++) {
            int rrow = (rg & 3) + 8 * (rg >> 2) + 4 * hi;
            float sv = xn[tt][rg] + xa[tt][rg];
            d[tt][rg] = xn[tt][rg] - xa[tt][rg];
            B[rrow * ST + 32 * (t0 + tt) + col] = sv;
        }
    }
    __syncthreads();

    // ---- t = s @ W_att + b_att ----
    f32x16 tac[2]; initacc2(tac, b_att, col, t0);
    mfma_gemm2(tac, B, 0, 8, 0, F, FT_F, l, t0);

    // ---- alpha: per-wave partial over its 64 cols, cross-wave via LDS ----
    float g[16];
    #pragma unroll
    for (int rg = 0; rg < 16; rg++) g[rg] = 0.f;
    #pragma unroll
    for (int tt = 0; tt < 2; tt++) {
        float vv = v_att[32 * (t0 + tt) + col];
        #pragma unroll
        for (int rg = 0; rg < 16; rg++) g[rg] += tanhf(tac[tt][rg]) * vv;
    }
    #pragma unroll
    for (int msk = 16; msk >= 1; msk >>= 1) {
        #pragma unroll
        for (int rg = 0; rg < 16; rg++) g[rg] += __shfl_xor(g[rg], msk, 64);
    }
    if (col == 0) {
        #pragma unroll
        for (int rg = 0; rg < 16; rg++) {
            int rrow = (rg & 3) + 8 * (rg >> 2) + 4 * hi;
            gpart[w][rrow] = g[rg];
        }
    }
    __syncthreads();

    float am[16];
    #pragma unroll
    for (int rg = 0; rg < 16; rg++) {
        int rrow = (rg & 3) + 8 * (rg >> 2) + 4 * hi;
        float gt = gpart[0][rrow] + gpart[1][rrow];
        am[rg] = 1.f / (1.f + expf(-gt)) - 0.5f;
    }

    // ---- u = dinv * (0.5*s + (alpha-0.5)*d), packed bf16 pairs ----
    #pragma unroll
    for (int tt = 0; tt < 2; tt++) {
        #pragma unroll
        for (int rg = 0; rg < 16; rg++) {
            int rrow = (rg & 3) + 8 * (rg >> 2) + 4 * hi;
            int n    = wnode0 + rrow;
            float sv = B[rrow * ST + 32 * (t0 + tt) + col];
            float uv = dinvs[rrow] * (0.5f * sv + am[rg] * d[tt][rg]);
            float pv = __shfl_xor(uv, 1, 64);
            if (((l & 1) == 0) && n < N_NODES) {
                u[(size_t)n * (HID / 2) + 16 * (t0 + tt) + (col >> 1)] = pack_bf2(uv, pv);
            }
        }
    }
}

// ------------------------------------------------------------- edge phase ---
__global__ __launch_bounds__(256) void gather_kernel(
    const int* __restrict__ row_start, const int* __restrict__ csr_src,
    const uint32* __restrict__ u, float* __restrict__ acc)
{
    int node = blockIdx.x * 4 + (threadIdx.x >> 6);
    int lane = threadIdx.x & 63;
    if (node >= N_NODES) return;

    const size_t RW = HID / 2;
    uint32 v = u[(size_t)node * RW + lane];
    float sx = __uint_as_float(v << 16);
    float sy = __uint_as_float(v & 0xffff0000u);

    int b = row_start[node], e = row_start[node + 1];
    int p = b;
    for (; p + 8 <= e; p += 8) {
        int j0 = csr_src[p + 0], j1 = csr_src[p + 1];
        int j2 = csr_src[p + 2], j3 = csr_src[p + 3];
        int j4 = csr_src[p + 4], j5 = csr_src[p + 5];
        int j6 = csr_src[p + 6], j7 = csr_src[p + 7];
        uint32 v0 = u[(size_t)j0 * RW + lane];
        uint32 v1 = u[(size_t)j1 * RW + lane];
        uint32 v2 = u[(size_t)j2 * RW + lane];
        uint32 v3 = u[(size_t)j3 * RW + lane];
        uint32 v4 = u[(size_t)j4 * RW + lane];
        uint32 v5 = u[(size_t)j5 * RW + lane];
        uint32 v6 = u[(size_t)j6 * RW + lane];
        uint32 v7 = u[(size_t)j7 * RW + lane];
        sx += __uint_as_float(v0 << 16) + __uint_as_float(v1 << 16)
            + __uint_as_float(v2 << 16) + __uint_as_float(v3 << 16)
            + __uint_as_float(v4 << 16) + __uint_as_float(v5 << 16)
            + __uint_as_float(v6 << 16) + __uint_as_float(v7 << 16);
        sy += __uint_as_float(v0 & 0xffff0000u) + __uint_as_float(v1 & 0xffff0000u)
            + __uint_as_float(v2 & 0xffff0000u) + __uint_as_float(v3 & 0xffff0000u)
            + __uint_as_float(v4 & 0xffff0000u) + __uint_as_float(v5 & 0xffff0000u)
            + __uint_as_float(v6 & 0xffff0000u) + __uint_as_float(v7 & 0xffff0000u);
    }
    for (; p < e; p++) {
        int j = csr_src[p];
        uint32 w = u[(size_t)j * RW + lane];
        sx += __uint_as_float(w << 16);
        sy += __uint_as_float(w & 0xffff0000u);
    }
    float2 s = make_float2(sx, sy);
    *(float2*)(acc + (size_t)node * HID + lane * 2) = s;
}

// ------------------------------------------------------------ final phase ---
// One wave per 32 nodes; upd GEMM via split-bf16 MFMA (FU frags).
__global__ __launch_bounds__(64, 2) void final_phase_kernel(
    const float* __restrict__ acc, const int* __restrict__ cnt,
    const float* __restrict__ b_upd,
    const float* __restrict__ W_cls, const float* __restrict__ b_cls,
    const uint4* __restrict__ F,
    float* __restrict__ out)
{
    __shared__ __align__(16) float B[WSLICE];

    const int l      = threadIdx.x;
    const int col    = l & 31;
    const int wnode0 = blockIdx.x * NW;

    // stage this wave's 32 acc rows, prescaled by dinv
    #pragma unroll
    for (int it = 0; it < 16; it++) {
        int i = it * 64 + l;
        int rr = i >> 5, kq = i & 31;
        int nd = wnode0 + rr; if (nd >= N_NODES) nd = N_NODES - 1;
        float d = rsqrtf((float)cnt[nd] + 1.0f);
        float4 v = *(const float4*)(acc + (size_t)nd * HID + kq * 4);
        v.x *= d; v.y *= d; v.z *= d; v.w *= d;
        *(float4*)&B[rr * ST + kq * 4] = v;
    }

    f32x16 up[4];
    initacc(up, b_upd, col);
    mfma_gemm(up, B, 0, 8, 0, F, FU_F, l);

    // lrelu -> B via D layout
    #pragma unroll
    for (int t = 0; t < 4; t++) {
        #pragma unroll
        for (int rg = 0; rg < 16; rg++) {
            int rrow = (rg & 3) + 8 * (rg >> 2) + 4 * (l >> 5);
            float v = up[t][rg];
            B[rrow * ST + 32 * t + col] = v > 0.f ? v : SLOPE * v;
        }
    }

    // classifier: 64 lanes handle 32 nodes x 2 outputs
    {
        int n = l >> 1, o = l & 1;
        if (wnode0 + n < N_NODES) {
            float s = b_cls[o];
            for (int k = 0; k < HID; k++)
                s = fmaf(B[n * ST + k], W_cls[k * OUT_DIM + o], s);
            out[(size_t)(wnode0 + n) * OUT_DIM + o] = s;
        }
    }
}

// ------------------------------------------------------------------ launch --
extern "C" void kernel_launch(void* const* d_in, const int* in_sizes, int n_in,
                              void* d_out, int out_size, void* d_ws, size_t ws_size,
                              hipStream_t stream)
{
    const float* x       = (const float*)d_in[0];
    const int*   ei      = (const int*)  d_in[1];   // [2, E] int32
    const float* W_in    = (const float*)d_in[2];
    const float* b_in    = (const float*)d_in[3];
    const float* W_nor   = (const float*)d_in[4];
    const float* b_nor   = (const float*)d_in[5];
    const float* W_abnor = (const float*)d_in[6];
    const float* b_abnor = (const float*)d_in[7];
    const float* W_att   = (const float*)d_in[8];
    const float* b_att   = (const float*)d_in[9];
    const float* v_att   = (const float*)d_in[10];
    const float* W_upd   = (const float*)d_in[11];
    const float* b_upd   = (const float*)d_in[12];
    const float* W_cls   = (const float*)d_in[13];
    const float* b_cls   = (const float*)d_in[14];
    float* out = (float*)d_out;

    // ws: cnt[N] | row_start[N+1] | bsum[128] | csr_src[E] | u_bf16[N*64 uints]
    //     | acc[N*HID] f32 | F[20480 uint4].   ticket[E] aliases acc.
    char* base = (char*)d_ws;
    int*  cnt       = (int*)base;
    int*  row_start = cnt + N_NODES;
    int*  bsum      = row_start + (N_NODES + 1);
    int*  csr_src   = bsum + 128;
    size_t off_u    = (((size_t)(2 * N_NODES + 129 + E_EDGES)) * 4 + 63) & ~(size_t)63;
    uint32* u       = (uint32*)(base + off_u);
    size_t off_acc  = (off_u + (size_t)N_NODES * (HID / 2) * 4 + 63) & ~(size_t)63;
    float* acc      = (float*)(base + off_acc);
    int*   ticket   = (int*)acc;
    size_t off_f    = (off_acc + (size_t)N_NODES * HID * 4 + 63) & ~(size_t)63;
    uint4* F        = (uint4*)(base + off_f);

    const int nblk = (N_NODES + NW - 1) / NW;   // 1563

    zero_int_kernel<<<(N_NODES + 255) / 256, 256, 0, stream>>>(cnt, N_NODES);
    deg_ticket_kernel<<<(E_EDGES + 255) / 256, 256, 0, stream>>>(ei + E_EDGES, cnt, ticket);
    scan1_kernel<<<SCAN_NB, SCAN_B, 0, stream>>>(cnt, row_start, bsum);
    scan2_kernel<<<1, 128, 0, stream>>>(bsum, row_start);
    scan3_kernel<<<SCAN_NB, SCAN_B, 0, stream>>>(bsum, row_start);
    fill_kernel<<<(E_EDGES + 255) / 256, 256, 0, stream>>>(ei, row_start, ticket, csr_src);
    prep_w_kernel<<<F_TOTAL / 256, 256, 0, stream>>>(W_in, W_nor, W_abnor, W_att, W_upd, F);
    node_phase_kernel<<<nblk, 128, 0, stream>>>(
        x, b_in, b_nor, b_abnor, b_att, v_att, cnt, F, u);
    gather_kernel<<<(N_NODES + 3) / 4, 256, 0, stream>>>(row_start, csr_src, u, acc);
    final_phase_kernel<<<nblk, 64, 0, stream>>>(
        acc, cnt, b_upd, W_cls, b_cls, F, out);
}

// Round 14
// 170.369 us; speedup vs baseline: 2.8758x; 1.0227x over previous
//
#include <hip/hip_runtime.h>

#define N_NODES 50000
#define E_EDGES 800000
#define IN_DIM  256
#define HID     128
#define HALF    64
#define OUT_DIM 2
#define NW      32               // nodes per block tile
#define SLOPE   0.01f

#define ST      132              // fp32 LDS row stride
#define WSLICE  (NW * ST)        // 4224 floats = 16.9 KB

#define SCAN_B  512
#define SCAN_NB ((N_NODES + SCAN_B - 1) / SCAN_B)   // 98

typedef unsigned int uint32;
typedef __attribute__((ext_vector_type(8)))  __bf16 bf16x8v;
typedef __attribute__((ext_vector_type(16))) float  f32x16;

union BF8 { bf16x8v v; unsigned short s[8]; uint4 q; };

// weight-fragment table offsets (frag = 2 uint4: hi, lo)
#define FI_F 0        // W_in : S=16 -> 4096 frags
#define FN_F 4096     // W_nor: S=4  -> 1024
#define FA_F 5120     // W_abnor: S=4 -> 1024
#define FT_F 6144     // W_att: S=8 -> 2048
#define FU_F 8192     // W_upd: S=8 -> 2048
#define F_TOTAL 10240 // 20480 uint4 = 320 KB

__device__ __forceinline__ uint32 rne16u(uint32 u) {
    return (u + 0x7fffu + ((u >> 16) & 1u)) >> 16;
}

__device__ __forceinline__ void split8(const float* f, BF8& hi, BF8& lo) {
    #pragma unroll
    for (int j = 0; j < 8; j++) {
        uint32 uu = __float_as_uint(f[j]);
        uint32 h  = rne16u(uu);
        float  fh = __uint_as_float(h << 16);
        float  r  = f[j] - fh;
        hi.s[j] = (unsigned short)h;
        lo.s[j] = (unsigned short)rne16u(__float_as_uint(r));
    }
}

__device__ __forceinline__ void mfma3(f32x16& acc, bf16x8v ah, bf16x8v al,
                                      bf16x8v bh, bf16x8v bl) {
    acc = __builtin_amdgcn_mfma_f32_32x32x16_bf16(ah, bh, acc, 0, 0, 0);
    acc = __builtin_amdgcn_mfma_f32_32x32x16_bf16(ah, bl, acc, 0, 0, 0);
    acc = __builtin_amdgcn_mfma_f32_32x32x16_bf16(al, bh, acc, 0, 0, 0);
}

// split a float4 at (row rr, local col k) into fragment-ordered LDS planes:
// A-frag (32x32x16): slot = s*64 + lane, lane = rr + 32*((k>>3)&1), j = k&7
__device__ __forceinline__ void stage_split4(__bf16* __restrict__ Ahi,
                                             __bf16* __restrict__ Alo,
                                             int rr, int k, float4 v) {
    int s_idx = k >> 4, jb = k & 7, lt = rr + 32 * ((k >> 3) & 1);
    int base = (s_idx * 64 + lt) * 8 + jb;
    float f[4] = {v.x, v.y, v.z, v.w};
    uint32 h[4], lo[4];
    #pragma unroll
    for (int j = 0; j < 4; j++) {
        uint32 uu = __float_as_uint(f[j]);
        uint32 hh = rne16u(uu);
        float  fh = __uint_as_float(hh << 16);
        float  r  = f[j] - fh;
        h[j] = hh; lo[j] = rne16u(__float_as_uint(r));
    }
    *(uint2*)(Ahi + base) = make_uint2(h[0] | (h[1] << 16), h[2] | (h[3] << 16));
    *(uint2*)(Alo + base) = make_uint2(lo[0] | (lo[1] << 16), lo[2] | (lo[3] << 16));
}

// 1-tile GEMM from pre-split planes: pure ds_read + F-load + MFMA
__device__ __forceinline__ void mfma_gemm1_pre(f32x16& acc,
        const __bf16* __restrict__ Ahi, const __bf16* __restrict__ Alo,
        int S, int sg0, const uint4* __restrict__ F, int fbase, int l, int t) {
    for (int s = 0; s < S; s++) {
        bf16x8v ah = *(const bf16x8v*)&Ahi[(s * 64 + l) * 8];
        bf16x8v al = *(const bf16x8v*)&Alo[(s * 64 + l) * 8];
        int f = fbase + ((sg0 + s) * 4 + t) * 64 + l;
        BF8 bh, bl; bh.q = F[2 * f]; bl.q = F[2 * f + 1];
        mfma3(acc, ah, al, bh.v, bl.v);
    }
}

// 1-tile GEMM from fp32 LDS tile (split in-loop)
__device__ __forceinline__ void mfma_gemm1(f32x16& acc, const float* B, int aoff,
        int S, int sg0, const uint4* __restrict__ F, int fbase, int l, int t) {
    const int row = l & 31, khi = 8 * (l >> 5);
    for (int s = 0; s < S; s++) {
        int k0 = aoff + 16 * s + khi;
        float a8[8];
        *(float4*)&a8[0] = *(const float4*)&B[row * ST + k0];
        *(float4*)&a8[4] = *(const float4*)&B[row * ST + k0 + 4];
        BF8 ah, al; split8(a8, ah, al);
        int f = fbase + ((sg0 + s) * 4 + t) * 64 + l;
        BF8 bh, bl; bh.q = F[2 * f]; bl.q = F[2 * f + 1];
        mfma3(acc, ah.v, al.v, bh.v, bl.v);
    }
}

// 4-tile GEMM from pre-split planes (final phase, 1 wave)
__device__ __forceinline__ void mfma_gemm_pre(f32x16* acc,
        const __bf16* __restrict__ Ahi, const __bf16* __restrict__ Alo,
        int S, const uint4* __restrict__ F, int fbase, int l) {
    for (int s = 0; s < S; s++) {
        bf16x8v ah = *(const bf16x8v*)&Ahi[(s * 64 + l) * 8];
        bf16x8v al = *(const bf16x8v*)&Alo[(s * 64 + l) * 8];
        #pragma unroll
        for (int t = 0; t < 4; t++) {
            int f = fbase + (s * 4 + t) * 64 + l;
            BF8 bh, bl; bh.q = F[2 * f]; bl.q = F[2 * f + 1];
            mfma3(acc[t], ah, al, bh.v, bl.v);
        }
    }
}

__device__ __forceinline__ void initacc(f32x16* acc, const float* __restrict__ b, int col) {
    #pragma unroll
    for (int t = 0; t < 4; t++) {
        float bv = b[32 * t + col];
        #pragma unroll
        for (int r2 = 0; r2 < 16; r2++) acc[t][r2] = bv;
    }
}

__device__ __forceinline__ uint32 pack_bf2(float x, float y) {
    return rne16u(__float_as_uint(x)) | (rne16u(__float_as_uint(y)) << 16);
}

// ---------------------------------------------------------------- degree ----
__global__ void zero_int_kernel(int* __restrict__ p, int n) {
    int i = blockIdx.x * blockDim.x + threadIdx.x;
    if (i < n) p[i] = 0;
}

__global__ void deg_ticket_kernel(const int* __restrict__ col,
                                  int* __restrict__ cnt, int* __restrict__ ticket) {
    int e = blockIdx.x * blockDim.x + threadIdx.x;
    if (e < E_EDGES) ticket[e] = atomicAdd(&cnt[col[e]], 1);
}

// ------------------------------------------------------- 3-pass fast scan ---
__device__ __forceinline__ int wave_iscan(int v, int l) {
    #pragma unroll
    for (int off = 1; off < 64; off <<= 1) {
        int t = __shfl_up(v, off, 64);
        if (l >= off) v += t;
    }
    return v;
}

__global__ __launch_bounds__(SCAN_B) void scan1_kernel(
    const int* __restrict__ cnt, int* __restrict__ row_start, int* __restrict__ bsum)
{
    __shared__ int wsum[SCAN_B / 64];
    int i = blockIdx.x * SCAN_B + threadIdx.x;
    int v = (i < N_NODES) ? cnt[i] : 0;
    int l = threadIdx.x & 63, w = threadIdx.x >> 6;
    int isc = wave_iscan(v, l);
    if (l == 63) wsum[w] = isc;
    __syncthreads();
    int wo = 0;
    #pragma unroll
    for (int k = 0; k < SCAN_B / 64; k++) wo += (k < w) ? wsum[k] : 0;
    if (i < N_NODES) row_start[i] = wo + isc - v;
    if (threadIdx.x == SCAN_B - 1) bsum[blockIdx.x] = wo + isc;
}

__global__ __launch_bounds__(128) void scan2_kernel(
    int* __restrict__ bsum, int* __restrict__ row_start)
{
    __shared__ int wsum[2];
    int i = threadIdx.x;
    int v = (i < SCAN_NB) ? bsum[i] : 0;
    int l = i & 63, w = i >> 6;
    int isc = wave_iscan(v, l);
    if (l == 63) wsum[w] = isc;
    __syncthreads();
    int wo = (w == 1) ? wsum[0] : 0;
    if (i < SCAN_NB) bsum[i] = wo + isc - v;
    if (i == SCAN_NB - 1) row_start[N_NODES] = wo + isc;
}

__global__ __launch_bounds__(SCAN_B) void scan3_kernel(
    const int* __restrict__ bsum, int* __restrict__ row_start)
{
    int i = blockIdx.x * SCAN_B + threadIdx.x;
    if (i < N_NODES) row_start[i] += bsum[blockIdx.x];
}

__global__ void fill_kernel(const int* __restrict__ ei,
                            const int* __restrict__ row_start,
                            const int* __restrict__ ticket,
                            int* __restrict__ csr_src)
{
    int e = blockIdx.x * blockDim.x + threadIdx.x;
    if (e >= E_EDGES) return;
    int j = ei[e];
    int i = ei[E_EDGES + e];
    csr_src[row_start[i] + ticket[e]] = j;
}

// ---------------------------------------------------- weight prep (split) ---
// B-frag layout (32x32x16): col = lane&31, k = 8*(lane>>5)+j.
__global__ __launch_bounds__(256) void prep_w_kernel(
    const float* __restrict__ W_in, const float* __restrict__ W_nor,
    const float* __restrict__ W_ab, const float* __restrict__ W_att,
    const float* __restrict__ W_upd,
    uint4* __restrict__ F)
{
    int idx = blockIdx.x * 256 + threadIdx.x;
    const float* W; int fbase, fi;
    if (idx < 4096)       { W = W_in;  fbase = FI_F; fi = idx; }
    else if (idx < 5120)  { W = W_nor; fbase = FN_F; fi = idx - 4096; }
    else if (idx < 6144)  { W = W_ab;  fbase = FA_F; fi = idx - 5120; }
    else if (idx < 8192)  { W = W_att; fbase = FT_F; fi = idx - 6144; }
    else if (idx < 10240) { W = W_upd; fbase = FU_F; fi = idx - 8192; }
    else return;
    int l = fi & 63, st = fi >> 6, t = st & 3, s = st >> 2;
    int k0 = 16 * s + 8 * (l >> 5);
    int c  = 32 * t + (l & 31);
    uint32 hi[8], lo[8];
    #pragma unroll
    for (int j = 0; j < 8; j++) {
        float v = W[(size_t)(k0 + j) * HID + c];
        uint32 uu = __float_as_uint(v);
        uint32 h  = rne16u(uu);
        float  fh = __uint_as_float(h << 16);
        float  r  = v - fh;
        hi[j] = h;
        lo[j] = rne16u(__float_as_uint(r));
    }
    uint4 H, L;
    H.x = hi[0] | (hi[1] << 16); H.y = hi[2] | (hi[3] << 16);
    H.z = hi[4] | (hi[5] << 16); H.w = hi[6] | (hi[7] << 16);
    L.x = lo[0] | (lo[1] << 16); L.y = lo[2] | (lo[3] << 16);
    L.z = lo[4] | (lo[5] << 16); L.w = lo[6] | (lo[7] << 16);
    int f = fbase + fi;
    F[2 * f]     = H;
    F[2 * f + 1] = L;
}

// ------------------------------------------------------------- node phase ---
// 256 threads = 4 waves per 32-node tile; wave w owns output cols 32w..32w+31
// (tile t = w). x staged PRE-SPLIT into bf16 fragment planes (FI loop is pure
// ds_read+F+MFMA); h/s tiles stay fp32 with in-loop split.
// D layout: col=l&31, row=(rg&3)+8*(rg>>2)+4*(l>>5).
__global__ __launch_bounds__(256, 4) void node_phase_kernel(
    const float* __restrict__ x,
    const float* __restrict__ b_in,  const float* __restrict__ b_nor,
    const float* __restrict__ b_abnor, const float* __restrict__ b_att,
    const float* __restrict__ v_att,
    const int* __restrict__ cnt,
    const uint4* __restrict__ F,
    uint32* __restrict__ u)            // [N][HID/2] packed bf16 pairs
{
    __shared__ __align__(16) float smem[WSLICE];   // 16.9 KB overlaid
    __shared__ float dinvs[NW];
    __shared__ float gpart[4][NW];
    __bf16* Ahi = (__bf16*)smem;          // 8 KB plane (512 slots x 8)
    __bf16* Alo = (__bf16*)smem + 4096;   // 8 KB plane

    const int tid    = threadIdx.x;
    const int w      = tid >> 6;          // tile t = w
    const int l      = tid & 63;
    const int col    = l & 31;
    const int hi     = l >> 5;
    const int wnode0 = blockIdx.x * NW;

    if (tid < NW) {
        int nd = wnode0 + tid;
        float c = (nd < N_NODES) ? (float)cnt[nd] : 0.f;
        dinvs[tid] = rsqrtf(c + 1.0f);
    }

    // ---- h = leaky_relu(x @ W_in + b_in), K=256 in two 128-halves ----
    f32x16 hacc;
    {
        float bv = b_in[32 * w + col];
        #pragma unroll
        for (int r2 = 0; r2 < 16; r2++) hacc[r2] = bv;
    }
    for (int half = 0; half < 2; half++) {
        #pragma unroll
        for (int it = 0; it < 4; it++) {           // 1024 float4 over 256 thr
            int i = it * 256 + tid;
            int rr = i >> 5, kq = i & 31, k = 4 * kq;
            int nd = wnode0 + rr; if (nd >= N_NODES) nd = N_NODES - 1;
            float4 v = *(const float4*)(x + (size_t)nd * IN_DIM + half * 128 + k);
            stage_split4(Ahi, Alo, rr, k, v);
        }
        __syncthreads();
        mfma_gemm1_pre(hacc, Ahi, Alo, 8, half * 8, F, FI_F, l, w);
        __syncthreads();   // planes consumed; safe to overwrite
    }

    // ---- lrelu(h) -> fp32 tile cols [32w, 32w+32) ----
    float* B = smem;
    #pragma unroll
    for (int rg = 0; rg < 16; rg++) {
        int rrow = (rg & 3) + 8 * (rg >> 2) + 4 * hi;
        float v = hacc[rg];
        B[rrow * ST + 32 * w + col] = v > 0.f ? v : SLOPE * v;
    }
    __syncthreads();

    // ---- xn = h[:, :64] @ W_nor ; xa = h[:, 64:] @ W_abnor ----
    f32x16 xn, xa;
    {
        float bv = b_nor[32 * w + col];
        #pragma unroll
        for (int r2 = 0; r2 < 16; r2++) xn[r2] = bv;
    }
    mfma_gemm1(xn, B, 0, 4, 0, F, FN_F, l, w);
    {
        float bv = b_abnor[32 * w + col];
        #pragma unroll
        for (int r2 = 0; r2 < 16; r2++) xa[r2] = bv;
    }
    mfma_gemm1(xa, B, HALF, 4, 0, F, FA_F, l, w);
    __syncthreads();   // h consumed

    // ---- s = xn+xa -> B; d = xn-xa in regs ----
    f32x16 d;
    #pragma unroll
    for (int rg = 0; rg < 16; rg++) {
        int rrow = (rg & 3) + 8 * (rg >> 2) + 4 * hi;
        float sv = xn[rg] + xa[rg];
        d[rg] = xn[rg] - xa[rg];
        B[rrow * ST + 32 * w + col] = sv;
    }
    __syncthreads();

    // ---- t = s @ W_att + b_att ----
    f32x16 tac;
    {
        float bv = b_att[32 * w + col];
        #pragma unroll
        for (int r2 = 0; r2 < 16; r2++) tac[r2] = bv;
    }
    mfma_gemm1(tac, B, 0, 8, 0, F, FT_F, l, w);

    // ---- alpha: per-wave partial (32 cols), cross-wave via gpart ----
    float g[16];
    {
        float vv = v_att[32 * w + col];
        #pragma unroll
        for (int rg = 0; rg < 16; rg++) g[rg] = tanhf(tac[rg]) * vv;
    }
    #pragma unroll
    for (int msk = 16; msk >= 1; msk >>= 1) {
        #pragma unroll
        for (int rg = 0; rg < 16; rg++) g[rg] += __shfl_xor(g[rg], msk, 64);
    }
    if (col == 0) {
        #pragma unroll
        for (int rg = 0; rg < 16; rg++) {
            int rrow = (rg & 3) + 8 * (rg >> 2) + 4 * hi;
            gpart[w][rrow] = g[rg];
        }
    }
    __syncthreads();

    float am[16];
    #pragma unroll
    for (int rg = 0; rg < 16; rg++) {
        int rrow = (rg & 3) + 8 * (rg >> 2) + 4 * hi;
        float gt = gpart[0][rrow] + gpart[1][rrow] + gpart[2][rrow] + gpart[3][rrow];
        am[rg] = 1.f / (1.f + expf(-gt)) - 0.5f;
    }

    // ---- u = dinv * (0.5*s + (alpha-0.5)*d), packed bf16 pairs ----
    #pragma unroll
    for (int rg = 0; rg < 16; rg++) {
        int rrow = (rg & 3) + 8 * (rg >> 2) + 4 * hi;
        int n    = wnode0 + rrow;
        float sv = B[rrow * ST + 32 * w + col];
        float uv = dinvs[rrow] * (0.5f * sv + am[rg] * d[rg]);
        float pv = __shfl_xor(uv, 1, 64);
        if (((l & 1) == 0) && n < N_NODES) {
            u[(size_t)n * (HID / 2) + 16 * w + (col >> 1)] = pack_bf2(uv, pv);
        }
    }
}

// ------------------------------------------------------------- edge phase ---
__global__ __launch_bounds__(256) void gather_kernel(
    const int* __restrict__ row_start, const int* __restrict__ csr_src,
    const uint32* __restrict__ u, float* __restrict__ acc)
{
    int node = blockIdx.x * 4 + (threadIdx.x >> 6);
    int lane = threadIdx.x & 63;
    if (node >= N_NODES) return;

    const size_t RW = HID / 2;
    uint32 v = u[(size_t)node * RW + lane];
    float sx = __uint_as_float(v << 16);
    float sy = __uint_as_float(v & 0xffff0000u);

    int b = row_start[node], e = row_start[node + 1];
    int p = b;
    for (; p + 8 <= e; p += 8) {
        int j0 = csr_src[p + 0], j1 = csr_src[p + 1];
        int j2 = csr_src[p + 2], j3 = csr_src[p + 3];
        int j4 = csr_src[p + 4], j5 = csr_src[p + 5];
        int j6 = csr_src[p + 6], j7 = csr_src[p + 7];
        uint32 v0 = u[(size_t)j0 * RW + lane];
        uint32 v1 = u[(size_t)j1 * RW + lane];
        uint32 v2 = u[(size_t)j2 * RW + lane];
        uint32 v3 = u[(size_t)j3 * RW + lane];
        uint32 v4 = u[(size_t)j4 * RW + lane];
        uint32 v5 = u[(size_t)j5 * RW + lane];
        uint32 v6 = u[(size_t)j6 * RW + lane];
        uint32 v7 = u[(size_t)j7 * RW + lane];
        sx += __uint_as_float(v0 << 16) + __uint_as_float(v1 << 16)
            + __uint_as_float(v2 << 16) + __uint_as_float(v3 << 16)
            + __uint_as_float(v4 << 16) + __uint_as_float(v5 << 16)
            + __uint_as_float(v6 << 16) + __uint_as_float(v7 << 16);
        sy += __uint_as_float(v0 & 0xffff0000u) + __uint_as_float(v1 & 0xffff0000u)
            + __uint_as_float(v2 & 0xffff0000u) + __uint_as_float(v3 & 0xffff0000u)
            + __uint_as_float(v4 & 0xffff0000u) + __uint_as_float(v5 & 0xffff0000u)
            + __uint_as_float(v6 & 0xffff0000u) + __uint_as_float(v7 & 0xffff0000u);
    }
    for (; p < e; p++) {
        int j = csr_src[p];
        uint32 w = u[(size_t)j * RW + lane];
        sx += __uint_as_float(w << 16);
        sy += __uint_as_float(w & 0xffff0000u);
    }
    float2 s = make_float2(sx, sy);
    *(float2*)(acc + (size_t)node * HID + lane * 2) = s;
}

// ------------------------------------------------------------ final phase ---
// One wave per 32 nodes; acc staged PRE-SPLIT (prescaled by dinv) into planes;
// upd GEMM is pure ds_read+F+MFMA.
__global__ __launch_bounds__(64, 2) void final_phase_kernel(
    const float* __restrict__ acc, const int* __restrict__ cnt,
    const float* __restrict__ b_upd,
    const float* __restrict__ W_cls, const float* __restrict__ b_cls,
    const uint4* __restrict__ F,
    float* __restrict__ out)
{
    __shared__ __align__(16) float smem[WSLICE];
    __bf16* Ahi = (__bf16*)smem;
    __bf16* Alo = (__bf16*)smem + 4096;

    const int l      = threadIdx.x;
    const int col    = l & 31;
    const int wnode0 = blockIdx.x * NW;

    // stage 32 acc rows, prescaled by dinv, pre-split into planes
    #pragma unroll
    for (int it = 0; it < 16; it++) {
        int i = it * 64 + l;
        int rr = i >> 5, kq = i & 31, k = 4 * kq;
        int nd = wnode0 + rr; if (nd >= N_NODES) nd = N_NODES - 1;
        float dv = rsqrtf((float)cnt[nd] + 1.0f);
        float4 v = *(const float4*)(acc + (size_t)nd * HID + k);
        v.x *= dv; v.y *= dv; v.z *= dv; v.w *= dv;
        stage_split4(Ahi, Alo, rr, k, v);
    }
    // single wave: LDS ordering via lgkmcnt, no barrier needed

    f32x16 up[4];
    initacc(up, b_upd, col);
    mfma_gemm_pre(up, Ahi, Alo, 8, F, FU_F, l);

    // lrelu -> fp32 tile (planes dead)
    float* B = smem;
    #pragma unroll
    for (int t = 0; t < 4; t++) {
        #pragma unroll
        for (int rg = 0; rg < 16; rg++) {
            int rrow = (rg & 3) + 8 * (rg >> 2) + 4 * (l >> 5);
            float v = up[t][rg];
            B[rrow * ST + 32 * t + col] = v > 0.f ? v : SLOPE * v;
        }
    }

    // classifier: 64 lanes handle 32 nodes x 2 outputs
    {
        int n = l >> 1, o = l & 1;
        if (wnode0 + n < N_NODES) {
            float s = b_cls[o];
            for (int k = 0; k < HID; k++)
                s = fmaf(B[n * ST + k], W_cls[k * OUT_DIM + o], s);
            out[(size_t)(wnode0 + n) * OUT_DIM + o] = s;
        }
    }
}

// ------------------------------------------------------------------ launch --
extern "C" void kernel_launch(void* const* d_in, const int* in_sizes, int n_in,
                              void* d_out, int out_size, void* d_ws, size_t ws_size,
                              hipStream_t stream)
{
    const float* x       = (const float*)d_in[0];
    const int*   ei      = (const int*)  d_in[1];   // [2, E] int32
    const float* W_in    = (const float*)d_in[2];
    const float* b_in    = (const float*)d_in[3];
    const float* W_nor   = (const float*)d_in[4];
    const float* b_nor   = (const float*)d_in[5];
    const float* W_abnor = (const float*)d_in[6];
    const float* b_abnor = (const float*)d_in[7];
    const float* W_att   = (const float*)d_in[8];
    const float* b_att   = (const float*)d_in[9];
    const float* v_att   = (const float*)d_in[10];
    const float* W_upd   = (const float*)d_in[11];
    const float* b_upd   = (const float*)d_in[12];
    const float* W_cls   = (const float*)d_in[13];
    const float* b_cls   = (const float*)d_in[14];
    float* out = (float*)d_out;

    // ws: cnt[N] | row_start[N+1] | bsum[128] | csr_src[E] | u_bf16[N*64 uints]
    //     | acc[N*HID] f32 | F[20480 uint4].   ticket[E] aliases acc.
    char* base = (char*)d_ws;
    int*  cnt       = (int*)base;
    int*  row_start = cnt + N_NODES;
    int*  bsum      = row_start + (N_NODES + 1);
    int*  csr_src   = bsum + 128;
    size_t off_u    = (((size_t)(2 * N_NODES + 129 + E_EDGES)) * 4 + 63) & ~(size_t)63;
    uint32* u       = (uint32*)(base + off_u);
    size_t off_acc  = (off_u + (size_t)N_NODES * (HID / 2) * 4 + 63) & ~(size_t)63;
    float* acc      = (float*)(base + off_acc);
    int*   ticket   = (int*)acc;
    size_t off_f    = (off_acc + (size_t)N_NODES * HID * 4 + 63) & ~(size_t)63;
    uint4* F        = (uint4*)(base + off_f);

    const int nblk = (N_NODES + NW - 1) / NW;   // 1563

    zero_int_kernel<<<(N_NODES + 255) / 256, 256, 0, stream>>>(cnt, N_NODES);
    deg_ticket_kernel<<<(E_EDGES + 255) / 256, 256, 0, stream>>>(ei + E_EDGES, cnt, ticket);
    scan1_kernel<<<SCAN_NB, SCAN_B, 0, stream>>>(cnt, row_start, bsum);
    scan2_kernel<<<1, 128, 0, stream>>>(bsum, row_start);
    scan3_kernel<<<SCAN_NB, SCAN_B, 0, stream>>>(bsum, row_start);
    fill_kernel<<<(E_EDGES + 255) / 256, 256, 0, stream>>>(ei, row_start, ticket, csr_src);
    prep_w_kernel<<<F_TOTAL / 256, 256, 0, stream>>>(W_in, W_nor, W_abnor, W_att, W_upd, F);
    node_phase_kernel<<<nblk, 256, 0, stream>>>(
        x, b_in, b_nor, b_abnor, b_att, v_att, cnt, F, u);
    gather_kernel<<<(N_NODES + 3) / 4, 256, 0, stream>>>(row_start, csr_src, u, acc);
    final_phase_kernel<<<nblk, 64, 0, stream>>>(
        acc, cnt, b_upd, W_cls, b_cls, F, out);
}

// Round 15
// 164.967 us; speedup vs baseline: 2.9700x; 1.0327x over previous
//
#include <hip/hip_runtime.h>

#define N_NODES 50000
#define E_EDGES 800000
#define IN_DIM  256
#define HID     128
#define HALF    64
#define OUT_DIM 2
#define NW      32               // nodes per block tile
#define SLOPE   0.01f

#define ST      132              // tile row stride (fp32/uint32 units)
#define WSLICE  (NW * ST)        // 4224 words = 16.9 KB

#define SSTRIDE 520              // bf16 units per s-step in A planes (512+8 pad)
#define PLANE   (8 * SSTRIDE)    // 4160 bf16 per plane

#define SCAN_B  512
#define SCAN_NB ((N_NODES + SCAN_B - 1) / SCAN_B)   // 98

typedef unsigned int uint32;
typedef __attribute__((ext_vector_type(8)))  __bf16 bf16x8v;
typedef __attribute__((ext_vector_type(16))) float  f32x16;

union BF8 { bf16x8v v; unsigned short s[8]; uint4 q; };

// weight-fragment table offsets (frag = 2 uint4: hi, lo)
#define FI_F 0        // W_in : S=16 -> 4096 frags
#define FN_F 4096     // W_nor: S=4  -> 1024
#define FA_F 5120     // W_abnor: S=4 -> 1024
#define FT_F 6144     // W_att: S=8 -> 2048
#define FU_F 8192     // W_upd: S=8 -> 2048
#define F_TOTAL 10240 // 20480 uint4 = 320 KB

__device__ __forceinline__ uint32 rne16u(uint32 u) {
    return (u + 0x7fffu + ((u >> 16) & 1u)) >> 16;
}

// pack one fp32 into (hi_bf16 << 16) | lo_bf16  (error-compensated split)
__device__ __forceinline__ uint32 pack_hl(float v) {
    uint32 uu = __float_as_uint(v);
    uint32 hh = rne16u(uu);
    float  fh = __uint_as_float(hh << 16);
    float  r  = v - fh;
    uint32 ll = rne16u(__float_as_uint(r));
    return (hh << 16) | ll;
}

__device__ __forceinline__ void mfma3(f32x16& acc, bf16x8v ah, bf16x8v al,
                                      bf16x8v bh, bf16x8v bl) {
    acc = __builtin_amdgcn_mfma_f32_32x32x16_bf16(ah, bh, acc, 0, 0, 0);
    acc = __builtin_amdgcn_mfma_f32_32x32x16_bf16(ah, bl, acc, 0, 0, 0);
    acc = __builtin_amdgcn_mfma_f32_32x32x16_bf16(al, bh, acc, 0, 0, 0);
}

// split a float4 at (row rr, local col k) into fragment-ordered LDS planes.
// A-frag (32x32x16): slot = s*SSTRIDE + lane*8 + j, lane = rr + 32*((k>>3)&1).
// SSTRIDE=520 pad -> staging-write banks (4s + jb/2)%32: 2-way max (free).
__device__ __forceinline__ void stage_split4(__bf16* __restrict__ Ahi,
                                             __bf16* __restrict__ Alo,
                                             int rr, int k, float4 v) {
    int s_idx = k >> 4, jb = k & 7, lt = rr + 32 * ((k >> 3) & 1);
    int base = s_idx * SSTRIDE + lt * 8 + jb;
    float f[4] = {v.x, v.y, v.z, v.w};
    uint32 h[4], lo[4];
    #pragma unroll
    for (int j = 0; j < 4; j++) {
        uint32 uu = __float_as_uint(f[j]);
        uint32 hh = rne16u(uu);
        float  fh = __uint_as_float(hh << 16);
        float  r  = f[j] - fh;
        h[j] = hh; lo[j] = rne16u(__float_as_uint(r));
    }
    *(uint2*)(Ahi + base) = make_uint2(h[0] | (h[1] << 16), h[2] | (h[3] << 16));
    *(uint2*)(Alo + base) = make_uint2(lo[0] | (lo[1] << 16), lo[2] | (lo[3] << 16));
}

// 1-tile GEMM from pre-split planes: pure ds_read + F-load + MFMA
__device__ __forceinline__ void mfma_gemm1_pre(f32x16& acc,
        const __bf16* __restrict__ Ahi, const __bf16* __restrict__ Alo,
        int S, int sg0, const uint4* __restrict__ F, int fbase, int l, int t) {
    for (int s = 0; s < S; s++) {
        bf16x8v ah = *(const bf16x8v*)&Ahi[s * SSTRIDE + l * 8];
        bf16x8v al = *(const bf16x8v*)&Alo[s * SSTRIDE + l * 8];
        int f = fbase + ((sg0 + s) * 4 + t) * 64 + l;
        BF8 bh, bl; bh.q = F[2 * f]; bl.q = F[2 * f + 1];
        mfma3(acc, ah, al, bh.v, bl.v);
    }
}

// 1-tile GEMM from packed (hi|lo) uint32 tile: 2 b128 + 8 shift/mask unpacks
__device__ __forceinline__ void mfma_gemm1_pk(f32x16& acc, const uint32* T,
        int aoff, int S, const uint4* __restrict__ F, int fbase, int l, int t) {
    const int row = l & 31, khi = 8 * (l >> 5);
    for (int s = 0; s < S; s++) {
        int k0 = aoff + 16 * s + khi;
        uint4 qa = *(const uint4*)&T[row * ST + k0];
        uint4 qb = *(const uint4*)&T[row * ST + k0 + 4];
        BF8 ah, al;
        ah.q.x = (qa.x >> 16) | (qa.y & 0xffff0000u);
        ah.q.y = (qa.z >> 16) | (qa.w & 0xffff0000u);
        ah.q.z = (qb.x >> 16) | (qb.y & 0xffff0000u);
        ah.q.w = (qb.z >> 16) | (qb.w & 0xffff0000u);
        al.q.x = (qa.x & 0xffffu) | (qa.y << 16);
        al.q.y = (qa.z & 0xffffu) | (qa.w << 16);
        al.q.z = (qb.x & 0xffffu) | (qb.y << 16);
        al.q.w = (qb.z & 0xffffu) | (qb.w << 16);
        int f = fbase + (s * 4 + t) * 64 + l;
        BF8 bh, bl; bh.q = F[2 * f]; bl.q = F[2 * f + 1];
        mfma3(acc, ah.v, al.v, bh.v, bl.v);
    }
}

// 4-tile GEMM from pre-split planes (final phase, 1 wave)
__device__ __forceinline__ void mfma_gemm_pre(f32x16* acc,
        const __bf16* __restrict__ Ahi, const __bf16* __restrict__ Alo,
        int S, const uint4* __restrict__ F, int fbase, int l) {
    for (int s = 0; s < S; s++) {
        bf16x8v ah = *(const bf16x8v*)&Ahi[s * SSTRIDE + l * 8];
        bf16x8v al = *(const bf16x8v*)&Alo[s * SSTRIDE + l * 8];
        #pragma unroll
        for (int t = 0; t < 4; t++) {
            int f = fbase + (s * 4 + t) * 64 + l;
            BF8 bh, bl; bh.q = F[2 * f]; bl.q = F[2 * f + 1];
            mfma3(acc[t], ah, al, bh.v, bl.v);
        }
    }
}

__device__ __forceinline__ void initacc(f32x16* acc, const float* __restrict__ b, int col) {
    #pragma unroll
    for (int t = 0; t < 4; t++) {
        float bv = b[32 * t + col];
        #pragma unroll
        for (int r2 = 0; r2 < 16; r2++) acc[t][r2] = bv;
    }
}

__device__ __forceinline__ uint32 pack_bf2(float x, float y) {
    return rne16u(__float_as_uint(x)) | (rne16u(__float_as_uint(y)) << 16);
}

// ---------------------------------------------------------------- degree ----
__global__ void zero_int_kernel(int* __restrict__ p, int n) {
    int i = blockIdx.x * blockDim.x + threadIdx.x;
    if (i < n) p[i] = 0;
}

__global__ void deg_ticket_kernel(const int* __restrict__ col,
                                  int* __restrict__ cnt, int* __restrict__ ticket) {
    int e = blockIdx.x * blockDim.x + threadIdx.x;
    if (e < E_EDGES) ticket[e] = atomicAdd(&cnt[col[e]], 1);
}

// ------------------------------------------------------- 3-pass fast scan ---
__device__ __forceinline__ int wave_iscan(int v, int l) {
    #pragma unroll
    for (int off = 1; off < 64; off <<= 1) {
        int t = __shfl_up(v, off, 64);
        if (l >= off) v += t;
    }
    return v;
}

__global__ __launch_bounds__(SCAN_B) void scan1_kernel(
    const int* __restrict__ cnt, int* __restrict__ row_start, int* __restrict__ bsum)
{
    __shared__ int wsum[SCAN_B / 64];
    int i = blockIdx.x * SCAN_B + threadIdx.x;
    int v = (i < N_NODES) ? cnt[i] : 0;
    int l = threadIdx.x & 63, w = threadIdx.x >> 6;
    int isc = wave_iscan(v, l);
    if (l == 63) wsum[w] = isc;
    __syncthreads();
    int wo = 0;
    #pragma unroll
    for (int k = 0; k < SCAN_B / 64; k++) wo += (k < w) ? wsum[k] : 0;
    if (i < N_NODES) row_start[i] = wo + isc - v;
    if (threadIdx.x == SCAN_B - 1) bsum[blockIdx.x] = wo + isc;
}

__global__ __launch_bounds__(128) void scan2_kernel(
    int* __restrict__ bsum, int* __restrict__ row_start)
{
    __shared__ int wsum[2];
    int i = threadIdx.x;
    int v = (i < SCAN_NB) ? bsum[i] : 0;
    int l = i & 63, w = i >> 6;
    int isc = wave_iscan(v, l);
    if (l == 63) wsum[w] = isc;
    __syncthreads();
    int wo = (w == 1) ? wsum[0] : 0;
    if (i < SCAN_NB) bsum[i] = wo + isc - v;
    if (i == SCAN_NB - 1) row_start[N_NODES] = wo + isc;
}

__global__ __launch_bounds__(SCAN_B) void scan3_kernel(
    const int* __restrict__ bsum, int* __restrict__ row_start)
{
    int i = blockIdx.x * SCAN_B + threadIdx.x;
    if (i < N_NODES) row_start[i] += bsum[blockIdx.x];
}

__global__ void fill_kernel(const int* __restrict__ ei,
                            const int* __restrict__ row_start,
                            const int* __restrict__ ticket,
                            int* __restrict__ csr_src)
{
    int e = blockIdx.x * blockDim.x + threadIdx.x;
    if (e >= E_EDGES) return;
    int j = ei[e];
    int i = ei[E_EDGES + e];
    csr_src[row_start[i] + ticket[e]] = j;
}

// ---------------------------------------------------- weight prep (split) ---
// B-frag layout (32x32x16): col = lane&31, k = 8*(lane>>5)+j.
__global__ __launch_bounds__(256) void prep_w_kernel(
    const float* __restrict__ W_in, const float* __restrict__ W_nor,
    const float* __restrict__ W_ab, const float* __restrict__ W_att,
    const float* __restrict__ W_upd,
    uint4* __restrict__ F)
{
    int idx = blockIdx.x * 256 + threadIdx.x;
    const float* W; int fbase, fi;
    if (idx < 4096)       { W = W_in;  fbase = FI_F; fi = idx; }
    else if (idx < 5120)  { W = W_nor; fbase = FN_F; fi = idx - 4096; }
    else if (idx < 6144)  { W = W_ab;  fbase = FA_F; fi = idx - 5120; }
    else if (idx < 8192)  { W = W_att; fbase = FT_F; fi = idx - 6144; }
    else if (idx < 10240) { W = W_upd; fbase = FU_F; fi = idx - 8192; }
    else return;
    int l = fi & 63, st = fi >> 6, t = st & 3, s = st >> 2;
    int k0 = 16 * s + 8 * (l >> 5);
    int c  = 32 * t + (l & 31);
    uint32 hi[8], lo[8];
    #pragma unroll
    for (int j = 0; j < 8; j++) {
        float v = W[(size_t)(k0 + j) * HID + c];
        uint32 uu = __float_as_uint(v);
        uint32 h  = rne16u(uu);
        float  fh = __uint_as_float(h << 16);
        float  r  = v - fh;
        hi[j] = h;
        lo[j] = rne16u(__float_as_uint(r));
    }
    uint4 H, L;
    H.x = hi[0] | (hi[1] << 16); H.y = hi[2] | (hi[3] << 16);
    H.z = hi[4] | (hi[5] << 16); H.w = hi[6] | (hi[7] << 16);
    L.x = lo[0] | (lo[1] << 16); L.y = lo[2] | (lo[3] << 16);
    L.z = lo[4] | (lo[5] << 16); L.w = lo[6] | (lo[7] << 16);
    int f = fbase + fi;
    F[2 * f]     = H;
    F[2 * f + 1] = L;
}

// ------------------------------------------------------------- node phase ---
// 256 threads = 4 waves per 32-node tile; wave w owns output cols 32w..32w+31.
// x staged PRE-SPLIT into padded bf16 planes (pure ds+F+MFMA loop); h and s
// stored as packed (hi|lo) uint32 tiles, packed ONCE by the owner wave and
// unpacked with shift/mask (v_perm) on read. s and d stay in registers.
__global__ __launch_bounds__(256, 4) void node_phase_kernel(
    const float* __restrict__ x,
    const float* __restrict__ b_in,  const float* __restrict__ b_nor,
    const float* __restrict__ b_abnor, const float* __restrict__ b_att,
    const float* __restrict__ v_att,
    const int* __restrict__ cnt,
    const uint4* __restrict__ F,
    uint32* __restrict__ u)            // [N][HID/2] packed bf16 pairs
{
    __shared__ __align__(16) float smem[WSLICE];   // 16.9 KB overlaid
    __shared__ float dinvs[NW];
    __shared__ float gpart[4][NW];
    __bf16* Ahi = (__bf16*)smem;              // padded plane (4160 bf16)
    __bf16* Alo = (__bf16*)smem + PLANE;      // second plane
    uint32* T   = (uint32*)smem;              // packed h/s tile [32][ST]

    const int tid    = threadIdx.x;
    const int w      = tid >> 6;          // tile t = w
    const int l      = tid & 63;
    const int col    = l & 31;
    const int hi     = l >> 5;
    const int wnode0 = blockIdx.x * NW;

    if (tid < NW) {
        int nd = wnode0 + tid;
        float c = (nd < N_NODES) ? (float)cnt[nd] : 0.f;
        dinvs[tid] = rsqrtf(c + 1.0f);
    }

    // ---- h = leaky_relu(x @ W_in + b_in), K=256 in two 128-halves ----
    f32x16 hacc;
    {
        float bv = b_in[32 * w + col];
        #pragma unroll
        for (int r2 = 0; r2 < 16; r2++) hacc[r2] = bv;
    }
    for (int half = 0; half < 2; half++) {
        #pragma unroll
        for (int it = 0; it < 4; it++) {           // 1024 float4 over 256 thr
            int i = it * 256 + tid;
            int rr = i >> 5, kq = i & 31, k = 4 * kq;
            int nd = wnode0 + rr; if (nd >= N_NODES) nd = N_NODES - 1;
            float4 v = *(const float4*)(x + (size_t)nd * IN_DIM + half * 128 + k);
            stage_split4(Ahi, Alo, rr, k, v);
        }
        __syncthreads();
        mfma_gemm1_pre(hacc, Ahi, Alo, 8, half * 8, F, FI_F, l, w);
        __syncthreads();   // planes consumed; safe to overwrite
    }

    // ---- lrelu(h) -> packed tile cols [32w, 32w+32) ----
    #pragma unroll
    for (int rg = 0; rg < 16; rg++) {
        int rrow = (rg & 3) + 8 * (rg >> 2) + 4 * hi;
        float v = hacc[rg];
        v = v > 0.f ? v : SLOPE * v;
        T[rrow * ST + 32 * w + col] = pack_hl(v);
    }
    __syncthreads();

    // ---- xn = h[:, :64] @ W_nor ; xa = h[:, 64:] @ W_abnor ----
    f32x16 xn, xa;
    {
        float bv = b_nor[32 * w + col];
        #pragma unroll
        for (int r2 = 0; r2 < 16; r2++) xn[r2] = bv;
    }
    mfma_gemm1_pk(xn, T, 0, 4, F, FN_F, l, w);
    {
        float bv = b_abnor[32 * w + col];
        #pragma unroll
        for (int r2 = 0; r2 < 16; r2++) xa[r2] = bv;
    }
    mfma_gemm1_pk(xa, T, HALF, 4, F, FA_F, l, w);
    __syncthreads();   // h consumed

    // ---- s = xn+xa (regs + packed tile); d = xn-xa (regs) ----
    f32x16 sv, d;
    #pragma unroll
    for (int rg = 0; rg < 16; rg++) {
        int rrow = (rg & 3) + 8 * (rg >> 2) + 4 * hi;
        sv[rg] = xn[rg] + xa[rg];
        d[rg]  = xn[rg] - xa[rg];
        T[rrow * ST + 32 * w + col] = pack_hl(sv[rg]);
    }
    __syncthreads();

    // ---- t = s @ W_att + b_att ----
    f32x16 tac;
    {
        float bv = b_att[32 * w + col];
        #pragma unroll
        for (int r2 = 0; r2 < 16; r2++) tac[r2] = bv;
    }
    mfma_gemm1_pk(tac, T, 0, 8, F, FT_F, l, w);

    // ---- alpha: per-wave partial (32 cols), cross-wave via gpart ----
    float g[16];
    {
        float vv = v_att[32 * w + col];
        #pragma unroll
        for (int rg = 0; rg < 16; rg++) g[rg] = tanhf(tac[rg]) * vv;
    }
    #pragma unroll
    for (int msk = 16; msk >= 1; msk >>= 1) {
        #pragma unroll
        for (int rg = 0; rg < 16; rg++) g[rg] += __shfl_xor(g[rg], msk, 64);
    }
    if (col == 0) {
        #pragma unroll
        for (int rg = 0; rg < 16; rg++) {
            int rrow = (rg & 3) + 8 * (rg >> 2) + 4 * hi;
            gpart[w][rrow] = g[rg];
        }
    }
    __syncthreads();

    float am[16];
    #pragma unroll
    for (int rg = 0; rg < 16; rg++) {
        int rrow = (rg & 3) + 8 * (rg >> 2) + 4 * hi;
        float gt = gpart[0][rrow] + gpart[1][rrow] + gpart[2][rrow] + gpart[3][rrow];
        am[rg] = 1.f / (1.f + expf(-gt)) - 0.5f;
    }

    // ---- u = dinv * (0.5*s + (alpha-0.5)*d), packed bf16 pairs ----
    #pragma unroll
    for (int rg = 0; rg < 16; rg++) {
        int rrow = (rg & 3) + 8 * (rg >> 2) + 4 * hi;
        int n    = wnode0 + rrow;
        float uv = dinvs[rrow] * (0.5f * sv[rg] + am[rg] * d[rg]);
        float pv = __shfl_xor(uv, 1, 64);
        if (((l & 1) == 0) && n < N_NODES) {
            u[(size_t)n * (HID / 2) + 16 * w + (col >> 1)] = pack_bf2(uv, pv);
        }
    }
}

// ------------------------------------------------------------- edge phase ---
__global__ __launch_bounds__(256) void gather_kernel(
    const int* __restrict__ row_start, const int* __restrict__ csr_src,
    const uint32* __restrict__ u, float* __restrict__ acc)
{
    int node = blockIdx.x * 4 + (threadIdx.x >> 6);
    int lane = threadIdx.x & 63;
    if (node >= N_NODES) return;

    const size_t RW = HID / 2;
    uint32 v = u[(size_t)node * RW + lane];
    float sx = __uint_as_float(v << 16);
    float sy = __uint_as_float(v & 0xffff0000u);

    int b = row_start[node], e = row_start[node + 1];
    int p = b;
    for (; p + 8 <= e; p += 8) {
        int j0 = csr_src[p + 0], j1 = csr_src[p + 1];
        int j2 = csr_src[p + 2], j3 = csr_src[p + 3];
        int j4 = csr_src[p + 4], j5 = csr_src[p + 5];
        int j6 = csr_src[p + 6], j7 = csr_src[p + 7];
        uint32 v0 = u[(size_t)j0 * RW + lane];
        uint32 v1 = u[(size_t)j1 * RW + lane];
        uint32 v2 = u[(size_t)j2 * RW + lane];
        uint32 v3 = u[(size_t)j3 * RW + lane];
        uint32 v4 = u[(size_t)j4 * RW + lane];
        uint32 v5 = u[(size_t)j5 * RW + lane];
        uint32 v6 = u[(size_t)j6 * RW + lane];
        uint32 v7 = u[(size_t)j7 * RW + lane];
        sx += __uint_as_float(v0 << 16) + __uint_as_float(v1 << 16)
            + __uint_as_float(v2 << 16) + __uint_as_float(v3 << 16)
            + __uint_as_float(v4 << 16) + __uint_as_float(v5 << 16)
            + __uint_as_float(v6 << 16) + __uint_as_float(v7 << 16);
        sy += __uint_as_float(v0 & 0xffff0000u) + __uint_as_float(v1 & 0xffff0000u)
            + __uint_as_float(v2 & 0xffff0000u) + __uint_as_float(v3 & 0xffff0000u)
            + __uint_as_float(v4 & 0xffff0000u) + __uint_as_float(v5 & 0xffff0000u)
            + __uint_as_float(v6 & 0xffff0000u) + __uint_as_float(v7 & 0xffff0000u);
    }
    for (; p < e; p++) {
        int j = csr_src[p];
        uint32 w = u[(size_t)j * RW + lane];
        sx += __uint_as_float(w << 16);
        sy += __uint_as_float(w & 0xffff0000u);
    }
    float2 s = make_float2(sx, sy);
    *(float2*)(acc + (size_t)node * HID + lane * 2) = s;
}

// ------------------------------------------------------------ final phase ---
// One wave per 32 nodes; acc staged PRE-SPLIT (prescaled by dinv) into padded
// planes; upd GEMM is pure ds_read+F+MFMA.
__global__ __launch_bounds__(64, 2) void final_phase_kernel(
    const float* __restrict__ acc, const int* __restrict__ cnt,
    const float* __restrict__ b_upd,
    const float* __restrict__ W_cls, const float* __restrict__ b_cls,
    const uint4* __restrict__ F,
    float* __restrict__ out)
{
    __shared__ __align__(16) float smem[WSLICE];
    __bf16* Ahi = (__bf16*)smem;
    __bf16* Alo = (__bf16*)smem + PLANE;

    const int l      = threadIdx.x;
    const int col    = l & 31;
    const int wnode0 = blockIdx.x * NW;

    // stage 32 acc rows, prescaled by dinv, pre-split into planes
    #pragma unroll
    for (int it = 0; it < 16; it++) {
        int i = it * 64 + l;
        int rr = i >> 5, kq = i & 31, k = 4 * kq;
        int nd = wnode0 + rr; if (nd >= N_NODES) nd = N_NODES - 1;
        float dv = rsqrtf((float)cnt[nd] + 1.0f);
        float4 v = *(const float4*)(acc + (size_t)nd * HID + k);
        v.x *= dv; v.y *= dv; v.z *= dv; v.w *= dv;
        stage_split4(Ahi, Alo, rr, k, v);
    }
    // single wave: LDS ordering via lgkmcnt, no barrier needed

    f32x16 up[4];
    initacc(up, b_upd, col);
    mfma_gemm_pre(up, Ahi, Alo, 8, F, FU_F, l);

    // lrelu -> fp32 tile (planes dead)
    float* B = smem;
    #pragma unroll
    for (int t = 0; t < 4; t++) {
        #pragma unroll
        for (int rg = 0; rg < 16; rg++) {
            int rrow = (rg & 3) + 8 * (rg >> 2) + 4 * (l >> 5);
            float v = up[t][rg];
            B[rrow * ST + 32 * t + col] = v > 0.f ? v : SLOPE * v;
        }
    }

    // classifier: 64 lanes handle 32 nodes x 2 outputs
    {
        int n = l >> 1, o = l & 1;
        if (wnode0 + n < N_NODES) {
            float s = b_cls[o];
            for (int k = 0; k < HID; k++)
                s = fmaf(B[n * ST + k], W_cls[k * OUT_DIM + o], s);
            out[(size_t)(wnode0 + n) * OUT_DIM + o] = s;
        }
    }
}

// ------------------------------------------------------------------ launch --
extern "C" void kernel_launch(void* const* d_in, const int* in_sizes, int n_in,
                              void* d_out, int out_size, void* d_ws, size_t ws_size,
                              hipStream_t stream)
{
    const float* x       = (const float*)d_in[0];
    const int*   ei      = (const int*)  d_in[1];   // [2, E] int32
    const float* W_in    = (const float*)d_in[2];
    const float* b_in    = (const float*)d_in[3];
    const float* W_nor   = (const float*)d_in[4];
    const float* b_nor   = (const float*)d_in[5];
    const float* W_abnor = (const float*)d_in[6];
    const float* b_abnor = (const float*)d_in[7];
    const float* W_att   = (const float*)d_in[8];
    const float* b_att   = (const float*)d_in[9];
    const float* v_att   = (const float*)d_in[10];
    const float* W_upd   = (const float*)d_in[11];
    const float* b_upd   = (const float*)d_in[12];
    const float* W_cls   = (const float*)d_in[13];
    const float* b_cls   = (const float*)d_in[14];
    float* out = (float*)d_out;

    // ws: cnt[N] | row_start[N+1] | bsum[128] | csr_src[E] | u_bf16[N*64 uints]
    //     | acc[N*HID] f32 | F[20480 uint4].   ticket[E] aliases acc.
    char* base = (char*)d_ws;
    int*  cnt       = (int*)base;
    int*  row_start = cnt + N_NODES;
    int*  bsum      = row_start + (N_NODES + 1);
    int*  csr_src   = bsum + 128;
    size_t off_u    = (((size_t)(2 * N_NODES + 129 + E_EDGES)) * 4 + 63) & ~(size_t)63;
    uint32* u       = (uint32*)(base + off_u);
    size_t off_acc  = (off_u + (size_t)N_NODES * (HID / 2) * 4 + 63) & ~(size_t)63;
    float* acc      = (float*)(base + off_acc);
    int*   ticket   = (int*)acc;
    size_t off_f    = (off_acc + (size_t)N_NODES * HID * 4 + 63) & ~(size_t)63;
    uint4* F        = (uint4*)(base + off_f);

    const int nblk = (N_NODES + NW - 1) / NW;   // 1563

    zero_int_kernel<<<(N_NODES + 255) / 256, 256, 0, stream>>>(cnt, N_NODES);
    deg_ticket_kernel<<<(E_EDGES + 255) / 256, 256, 0, stream>>>(ei + E_EDGES, cnt, ticket);
    scan1_kernel<<<SCAN_NB, SCAN_B, 0, stream>>>(cnt, row_start, bsum);
    scan2_kernel<<<1, 128, 0, stream>>>(bsum, row_start);
    scan3_kernel<<<SCAN_NB, SCAN_B, 0, stream>>>(bsum, row_start);
    fill_kernel<<<(E_EDGES + 255) / 256, 256, 0, stream>>>(ei, row_start, ticket, csr_src);
    prep_w_kernel<<<F_TOTAL / 256, 256, 0, stream>>>(W_in, W_nor, W_abnor, W_att, W_upd, F);
    node_phase_kernel<<<nblk, 256, 0, stream>>>(
        x, b_in, b_nor, b_abnor, b_att, v_att, cnt, F, u);
    gather_kernel<<<(N_NODES + 3) / 4, 256, 0, stream>>>(row_start, csr_src, u, acc);
    final_phase_kernel<<<nblk, 64, 0, stream>>>(
        acc, cnt, b_upd, W_cls, b_cls, F, out);
}

// Round 16
// 161.961 us; speedup vs baseline: 3.0251x; 1.0186x over previous
//
#include <hip/hip_runtime.h>

#define N_NODES 50000
#define E_EDGES 800000
#define IN_DIM  256
#define HID     128
#define HALF    64
#define OUT_DIM 2
#define NW      32               // nodes per block tile
#define SLOPE   0.01f

#define ST      132              // tile row stride (fp32/uint32 units)
#define WSLICE  (NW * ST)        // 4224 words = 16.9 KB

#define SSTRIDE 520              // bf16 units per s-step in A planes (512+8 pad)
#define PLANE   (8 * SSTRIDE)    // 4160 bf16 per plane

#define SCAN_B  512
#define SCAN_NB ((N_NODES + SCAN_B - 1) / SCAN_B)   // 98

typedef unsigned int uint32;
typedef __attribute__((ext_vector_type(8)))  __bf16 bf16x8v;
typedef __attribute__((ext_vector_type(16))) float  f32x16;

union BF8 { bf16x8v v; unsigned short s[8]; uint4 q; };

// weight-fragment table offsets (frag = 2 uint4: hi, lo)
#define FI_F 0        // W_in : S=16 -> 4096 frags
#define FN_F 4096     // W_nor: S=4  -> 1024
#define FA_F 5120     // W_abnor: S=4 -> 1024
#define FT_F 6144     // W_att: S=8 -> 2048
#define FU_F 8192     // W_upd: S=8 -> 2048
#define F_TOTAL 10240 // 20480 uint4 = 320 KB

__device__ __forceinline__ uint32 rne16u(uint32 u) {
    return (u + 0x7fffu + ((u >> 16) & 1u)) >> 16;
}

// pack one fp32 into (hi_bf16 << 16) | lo_bf16  (error-compensated split)
__device__ __forceinline__ uint32 pack_hl(float v) {
    uint32 uu = __float_as_uint(v);
    uint32 hh = rne16u(uu);
    float  fh = __uint_as_float(hh << 16);
    float  r  = v - fh;
    uint32 ll = rne16u(__float_as_uint(r));
    return (hh << 16) | ll;
}

// fast tanh / sigmoid via v_exp + v_rcp (~1e-7 rel err)
__device__ __forceinline__ float fast_tanh(float x) {
    float ex = __expf(2.f * x);
    return 1.f - 2.f * __builtin_amdgcn_rcpf(ex + 1.f);
}
__device__ __forceinline__ float fast_sig(float x) {
    return __builtin_amdgcn_rcpf(1.f + __expf(-x));
}

__device__ __forceinline__ void mfma3(f32x16& acc, bf16x8v ah, bf16x8v al,
                                      bf16x8v bh, bf16x8v bl) {
    acc = __builtin_amdgcn_mfma_f32_32x32x16_bf16(ah, bh, acc, 0, 0, 0);
    acc = __builtin_amdgcn_mfma_f32_32x32x16_bf16(ah, bl, acc, 0, 0, 0);
    acc = __builtin_amdgcn_mfma_f32_32x32x16_bf16(al, bh, acc, 0, 0, 0);
}

// split a float4 at (row rr, local col k) into fragment-ordered LDS planes.
// A-frag (32x32x16): slot = s*SSTRIDE + lane*8 + j, lane = rr + 32*((k>>3)&1).
__device__ __forceinline__ void stage_split4(__bf16* __restrict__ Ahi,
                                             __bf16* __restrict__ Alo,
                                             int rr, int k, float4 v) {
    int s_idx = k >> 4, jb = k & 7, lt = rr + 32 * ((k >> 3) & 1);
    int base = s_idx * SSTRIDE + lt * 8 + jb;
    float f[4] = {v.x, v.y, v.z, v.w};
    uint32 h[4], lo[4];
    #pragma unroll
    for (int j = 0; j < 4; j++) {
        uint32 uu = __float_as_uint(f[j]);
        uint32 hh = rne16u(uu);
        float  fh = __uint_as_float(hh << 16);
        float  r  = f[j] - fh;
        h[j] = hh; lo[j] = rne16u(__float_as_uint(r));
    }
    *(uint2*)(Ahi + base) = make_uint2(h[0] | (h[1] << 16), h[2] | (h[3] << 16));
    *(uint2*)(Alo + base) = make_uint2(lo[0] | (lo[1] << 16), lo[2] | (lo[3] << 16));
}

// 1-tile GEMM from pre-split planes: pure ds_read + F-load + MFMA
__device__ __forceinline__ void mfma_gemm1_pre(f32x16& acc,
        const __bf16* __restrict__ Ahi, const __bf16* __restrict__ Alo,
        int S, int sg0, const uint4* __restrict__ F, int fbase, int l, int t) {
    for (int s = 0; s < S; s++) {
        bf16x8v ah = *(const bf16x8v*)&Ahi[s * SSTRIDE + l * 8];
        bf16x8v al = *(const bf16x8v*)&Alo[s * SSTRIDE + l * 8];
        int f = fbase + ((sg0 + s) * 4 + t) * 64 + l;
        BF8 bh, bl; bh.q = F[2 * f]; bl.q = F[2 * f + 1];
        mfma3(acc, ah, al, bh.v, bl.v);
    }
}

// 1-tile GEMM from packed (hi|lo) uint32 tile: 2 b128 + 8 shift/mask unpacks
__device__ __forceinline__ void mfma_gemm1_pk(f32x16& acc, const uint32* T,
        int aoff, int S, const uint4* __restrict__ F, int fbase, int l, int t) {
    const int row = l & 31, khi = 8 * (l >> 5);
    for (int s = 0; s < S; s++) {
        int k0 = aoff + 16 * s + khi;
        uint4 qa = *(const uint4*)&T[row * ST + k0];
        uint4 qb = *(const uint4*)&T[row * ST + k0 + 4];
        BF8 ah, al;
        ah.q.x = (qa.x >> 16) | (qa.y & 0xffff0000u);
        ah.q.y = (qa.z >> 16) | (qa.w & 0xffff0000u);
        ah.q.z = (qb.x >> 16) | (qb.y & 0xffff0000u);
        ah.q.w = (qb.z >> 16) | (qb.w & 0xffff0000u);
        al.q.x = (qa.x & 0xffffu) | (qa.y << 16);
        al.q.y = (qa.z & 0xffffu) | (qa.w << 16);
        al.q.z = (qb.x & 0xffffu) | (qb.y << 16);
        al.q.w = (qb.z & 0xffffu) | (qb.w << 16);
        int f = fbase + (s * 4 + t) * 64 + l;
        BF8 bh, bl; bh.q = F[2 * f]; bl.q = F[2 * f + 1];
        mfma3(acc, ah.v, al.v, bh.v, bl.v);
    }
}

__device__ __forceinline__ uint32 pack_bf2(float x, float y) {
    return rne16u(__float_as_uint(x)) | (rne16u(__float_as_uint(y)) << 16);
}

// ---------------------------------------------------------------- degree ----
__global__ void zero_int_kernel(int* __restrict__ p, int n) {
    int i = blockIdx.x * blockDim.x + threadIdx.x;
    if (i < n) p[i] = 0;
}

__global__ void deg_ticket_kernel(const int* __restrict__ col,
                                  int* __restrict__ cnt, int* __restrict__ ticket) {
    int e = blockIdx.x * blockDim.x + threadIdx.x;
    if (e < E_EDGES) ticket[e] = atomicAdd(&cnt[col[e]], 1);
}

// ------------------------------------------------------- 3-pass fast scan ---
__device__ __forceinline__ int wave_iscan(int v, int l) {
    #pragma unroll
    for (int off = 1; off < 64; off <<= 1) {
        int t = __shfl_up(v, off, 64);
        if (l >= off) v += t;
    }
    return v;
}

__global__ __launch_bounds__(SCAN_B) void scan1_kernel(
    const int* __restrict__ cnt, int* __restrict__ row_start, int* __restrict__ bsum)
{
    __shared__ int wsum[SCAN_B / 64];
    int i = blockIdx.x * SCAN_B + threadIdx.x;
    int v = (i < N_NODES) ? cnt[i] : 0;
    int l = threadIdx.x & 63, w = threadIdx.x >> 6;
    int isc = wave_iscan(v, l);
    if (l == 63) wsum[w] = isc;
    __syncthreads();
    int wo = 0;
    #pragma unroll
    for (int k = 0; k < SCAN_B / 64; k++) wo += (k < w) ? wsum[k] : 0;
    if (i < N_NODES) row_start[i] = wo + isc - v;
    if (threadIdx.x == SCAN_B - 1) bsum[blockIdx.x] = wo + isc;
}

__global__ __launch_bounds__(128) void scan2_kernel(
    int* __restrict__ bsum, int* __restrict__ row_start)
{
    __shared__ int wsum[2];
    int i = threadIdx.x;
    int v = (i < SCAN_NB) ? bsum[i] : 0;
    int l = i & 63, w = i >> 6;
    int isc = wave_iscan(v, l);
    if (l == 63) wsum[w] = isc;
    __syncthreads();
    int wo = (w == 1) ? wsum[0] : 0;
    if (i < SCAN_NB) bsum[i] = wo + isc - v;
    if (i == SCAN_NB - 1) row_start[N_NODES] = wo + isc;
}

__global__ __launch_bounds__(SCAN_B) void scan3_kernel(
    const int* __restrict__ bsum, int* __restrict__ row_start)
{
    int i = blockIdx.x * SCAN_B + threadIdx.x;
    if (i < N_NODES) row_start[i] += bsum[blockIdx.x];
}

__global__ void fill_kernel(const int* __restrict__ ei,
                            const int* __restrict__ row_start,
                            const int* __restrict__ ticket,
                            int* __restrict__ csr_src)
{
    int e = blockIdx.x * blockDim.x + threadIdx.x;
    if (e >= E_EDGES) return;
    int j = ei[e];
    int i = ei[E_EDGES + e];
    csr_src[row_start[i] + ticket[e]] = j;
}

// ---------------------------------------------------- weight prep (split) ---
// B-frag layout (32x32x16): col = lane&31, k = 8*(lane>>5)+j.
__global__ __launch_bounds__(256) void prep_w_kernel(
    const float* __restrict__ W_in, const float* __restrict__ W_nor,
    const float* __restrict__ W_ab, const float* __restrict__ W_att,
    const float* __restrict__ W_upd,
    uint4* __restrict__ F)
{
    int idx = blockIdx.x * 256 + threadIdx.x;
    const float* W; int fbase, fi;
    if (idx < 4096)       { W = W_in;  fbase = FI_F; fi = idx; }
    else if (idx < 5120)  { W = W_nor; fbase = FN_F; fi = idx - 4096; }
    else if (idx < 6144)  { W = W_ab;  fbase = FA_F; fi = idx - 5120; }
    else if (idx < 8192)  { W = W_att; fbase = FT_F; fi = idx - 6144; }
    else if (idx < 10240) { W = W_upd; fbase = FU_F; fi = idx - 8192; }
    else return;
    int l = fi & 63, st = fi >> 6, t = st & 3, s = st >> 2;
    int k0 = 16 * s + 8 * (l >> 5);
    int c  = 32 * t + (l & 31);
    uint32 hi[8], lo[8];
    #pragma unroll
    for (int j = 0; j < 8; j++) {
        float v = W[(size_t)(k0 + j) * HID + c];
        uint32 uu = __float_as_uint(v);
        uint32 h  = rne16u(uu);
        float  fh = __uint_as_float(h << 16);
        float  r  = v - fh;
        hi[j] = h;
        lo[j] = rne16u(__float_as_uint(r));
    }
    uint4 H, L;
    H.x = hi[0] | (hi[1] << 16); H.y = hi[2] | (hi[3] << 16);
    H.z = hi[4] | (hi[5] << 16); H.w = hi[6] | (hi[7] << 16);
    L.x = lo[0] | (lo[1] << 16); L.y = lo[2] | (lo[3] << 16);
    L.z = lo[4] | (lo[5] << 16); L.w = lo[6] | (lo[7] << 16);
    int f = fbase + fi;
    F[2 * f]     = H;
    F[2 * f + 1] = L;
}

// ------------------------------------------------------------- node phase ---
// 256 threads = 4 waves per 32-node tile; wave w owns output cols 32w..32w+31.
__global__ __launch_bounds__(256, 4) void node_phase_kernel(
    const float* __restrict__ x,
    const float* __restrict__ b_in,  const float* __restrict__ b_nor,
    const float* __restrict__ b_abnor, const float* __restrict__ b_att,
    const float* __restrict__ v_att,
    const int* __restrict__ cnt,
    const uint4* __restrict__ F,
    uint32* __restrict__ u)            // [N][HID/2] packed bf16 pairs
{
    __shared__ __align__(16) float smem[WSLICE];   // 16.9 KB overlaid
    __shared__ float dinvs[NW];
    __shared__ float gpart[4][NW];
    __bf16* Ahi = (__bf16*)smem;              // padded plane (4160 bf16)
    __bf16* Alo = (__bf16*)smem + PLANE;      // second plane
    uint32* T   = (uint32*)smem;              // packed h/s tile [32][ST]

    const int tid    = threadIdx.x;
    const int w      = tid >> 6;          // tile t = w
    const int l      = tid & 63;
    const int col    = l & 31;
    const int hi     = l >> 5;
    const int wnode0 = blockIdx.x * NW;

    if (tid < NW) {
        int nd = wnode0 + tid;
        float c = (nd < N_NODES) ? (float)cnt[nd] : 0.f;
        dinvs[tid] = rsqrtf(c + 1.0f);
    }

    // ---- h = leaky_relu(x @ W_in + b_in), K=256 in two 128-halves ----
    f32x16 hacc;
    {
        float bv = b_in[32 * w + col];
        #pragma unroll
        for (int r2 = 0; r2 < 16; r2++) hacc[r2] = bv;
    }
    for (int half = 0; half < 2; half++) {
        #pragma unroll
        for (int it = 0; it < 4; it++) {           // 1024 float4 over 256 thr
            int i = it * 256 + tid;
            int rr = i >> 5, kq = i & 31, k = 4 * kq;
            int nd = wnode0 + rr; if (nd >= N_NODES) nd = N_NODES - 1;
            float4 v = *(const float4*)(x + (size_t)nd * IN_DIM + half * 128 + k);
            stage_split4(Ahi, Alo, rr, k, v);
        }
        __syncthreads();
        mfma_gemm1_pre(hacc, Ahi, Alo, 8, half * 8, F, FI_F, l, w);
        __syncthreads();   // planes consumed; safe to overwrite
    }

    // ---- lrelu(h) -> packed tile cols [32w, 32w+32) ----
    #pragma unroll
    for (int rg = 0; rg < 16; rg++) {
        int rrow = (rg & 3) + 8 * (rg >> 2) + 4 * hi;
        float v = hacc[rg];
        v = v > 0.f ? v : SLOPE * v;
        T[rrow * ST + 32 * w + col] = pack_hl(v);
    }
    __syncthreads();

    // ---- xn = h[:, :64] @ W_nor ; xa = h[:, 64:] @ W_abnor ----
    f32x16 xn, xa;
    {
        float bv = b_nor[32 * w + col];
        #pragma unroll
        for (int r2 = 0; r2 < 16; r2++) xn[r2] = bv;
    }
    mfma_gemm1_pk(xn, T, 0, 4, F, FN_F, l, w);
    {
        float bv = b_abnor[32 * w + col];
        #pragma unroll
        for (int r2 = 0; r2 < 16; r2++) xa[r2] = bv;
    }
    mfma_gemm1_pk(xa, T, HALF, 4, F, FA_F, l, w);
    __syncthreads();   // h consumed

    // ---- s = xn+xa (regs + packed tile); d = xn-xa (regs) ----
    f32x16 sv, d;
    #pragma unroll
    for (int rg = 0; rg < 16; rg++) {
        int rrow = (rg & 3) + 8 * (rg >> 2) + 4 * hi;
        sv[rg] = xn[rg] + xa[rg];
        d[rg]  = xn[rg] - xa[rg];
        T[rrow * ST + 32 * w + col] = pack_hl(sv[rg]);
    }
    __syncthreads();

    // ---- t = s @ W_att + b_att ----
    f32x16 tac;
    {
        float bv = b_att[32 * w + col];
        #pragma unroll
        for (int r2 = 0; r2 < 16; r2++) tac[r2] = bv;
    }
    mfma_gemm1_pk(tac, T, 0, 8, F, FT_F, l, w);

    // ---- alpha: per-wave partial (32 cols), cross-wave via gpart ----
    float g[16];
    {
        float vv = v_att[32 * w + col];
        #pragma unroll
        for (int rg = 0; rg < 16; rg++) g[rg] = fast_tanh(tac[rg]) * vv;
    }
    #pragma unroll
    for (int msk = 16; msk >= 1; msk >>= 1) {
        #pragma unroll
        for (int rg = 0; rg < 16; rg++) g[rg] += __shfl_xor(g[rg], msk, 64);
    }
    if (col == 0) {
        #pragma unroll
        for (int rg = 0; rg < 16; rg++) {
            int rrow = (rg & 3) + 8 * (rg >> 2) + 4 * hi;
            gpart[w][rrow] = g[rg];
        }
    }
    __syncthreads();

    float am[16];
    #pragma unroll
    for (int rg = 0; rg < 16; rg++) {
        int rrow = (rg & 3) + 8 * (rg >> 2) + 4 * hi;
        float gt = gpart[0][rrow] + gpart[1][rrow] + gpart[2][rrow] + gpart[3][rrow];
        am[rg] = fast_sig(gt) - 0.5f;
    }

    // ---- u = dinv * (0.5*s + (alpha-0.5)*d), packed bf16 pairs ----
    #pragma unroll
    for (int rg = 0; rg < 16; rg++) {
        int rrow = (rg & 3) + 8 * (rg >> 2) + 4 * hi;
        int n    = wnode0 + rrow;
        float uv = dinvs[rrow] * (0.5f * sv[rg] + am[rg] * d[rg]);
        float pv = __shfl_xor(uv, 1, 64);
        if (((l & 1) == 0) && n < N_NODES) {
            u[(size_t)n * (HID / 2) + 16 * w + (col >> 1)] = pack_bf2(uv, pv);
        }
    }
}

// ------------------------------------------------------------- edge phase ---
// One wave per node; fully predicated 8-batches (no serial dependent tail).
__global__ __launch_bounds__(256) void gather_kernel(
    const int* __restrict__ row_start, const int* __restrict__ csr_src,
    const uint32* __restrict__ u, float* __restrict__ acc)
{
    int node = blockIdx.x * 4 + (threadIdx.x >> 6);
    int lane = threadIdx.x & 63;
    if (node >= N_NODES) return;

    const size_t RW = HID / 2;
    uint32 v = u[(size_t)node * RW + lane];
    float sx = __uint_as_float(v << 16);
    float sy = __uint_as_float(v & 0xffff0000u);

    int b = row_start[node], e = row_start[node + 1];
    for (int p = b; p < e; p += 8) {
        int idx[8];
        #pragma unroll
        for (int q = 0; q < 8; q++) {
            int a = p + q; if (a > e - 1) a = e - 1;   // clamp: loads stay in-bounds
            idx[q] = csr_src[a];
        }
        uint32 vv[8];
        #pragma unroll
        for (int q = 0; q < 8; q++) vv[q] = u[(size_t)idx[q] * RW + lane];
        #pragma unroll
        for (int q = 0; q < 8; q++) {
            if (p + q < e) {
                sx += __uint_as_float(vv[q] << 16);
                sy += __uint_as_float(vv[q] & 0xffff0000u);
            }
        }
    }
    float2 s = make_float2(sx, sy);
    *(float2*)(acc + (size_t)node * HID + lane * 2) = s;
}

// ------------------------------------------------------------ final phase ---
// 256 threads = 4 waves per 32-node tile; shared pre-split staging; wave w
// computes FU tile t=w; classifier parallel over all 256 threads.
__global__ __launch_bounds__(256, 4) void final_phase_kernel(
    const float* __restrict__ acc, const int* __restrict__ cnt,
    const float* __restrict__ b_upd,
    const float* __restrict__ W_cls, const float* __restrict__ b_cls,
    const uint4* __restrict__ F,
    float* __restrict__ out)
{
    __shared__ __align__(16) float smem[WSLICE];
    __bf16* Ahi = (__bf16*)smem;
    __bf16* Alo = (__bf16*)smem + PLANE;

    const int tid    = threadIdx.x;
    const int w      = tid >> 6;
    const int l      = tid & 63;
    const int col    = l & 31;
    const int hi     = l >> 5;
    const int wnode0 = blockIdx.x * NW;

    // stage 32 acc rows, prescaled by dinv, pre-split into planes
    #pragma unroll
    for (int it = 0; it < 4; it++) {
        int i = it * 256 + tid;
        int rr = i >> 5, kq = i & 31, k = 4 * kq;
        int nd = wnode0 + rr; if (nd >= N_NODES) nd = N_NODES - 1;
        float dv = rsqrtf((float)cnt[nd] + 1.0f);
        float4 v = *(const float4*)(acc + (size_t)nd * HID + k);
        v.x *= dv; v.y *= dv; v.z *= dv; v.w *= dv;
        stage_split4(Ahi, Alo, rr, k, v);
    }
    __syncthreads();

    f32x16 up;
    {
        float bv = b_upd[32 * w + col];
        #pragma unroll
        for (int r2 = 0; r2 < 16; r2++) up[r2] = bv;
    }
    mfma_gemm1_pre(up, Ahi, Alo, 8, 0, F, FU_F, l, w);
    __syncthreads();   // planes consumed before overwrite

    // lrelu -> fp32 tile cols [32w, 32w+32)
    float* B = smem;
    #pragma unroll
    for (int rg = 0; rg < 16; rg++) {
        int rrow = (rg & 3) + 8 * (rg >> 2) + 4 * hi;
        float v = up[rg];
        B[rrow * ST + 32 * w + col] = v > 0.f ? v : SLOPE * v;
    }
    __syncthreads();

    // classifier: tid = n*8 + o*4 + c ; 4 lanes per (node,out), shfl-reduce
    {
        int n = tid >> 3, o = (tid >> 2) & 1, c = tid & 3;
        float s = 0.f;
        int k0 = c * 32;
        for (int k = k0; k < k0 + 32; k++)
            s = fmaf(B[n * ST + k], W_cls[k * OUT_DIM + o], s);
        s += __shfl_xor(s, 1, 64);
        s += __shfl_xor(s, 2, 64);
        if (c == 0 && wnode0 + n < N_NODES) {
            out[(size_t)(wnode0 + n) * OUT_DIM + o] = s + b_cls[o];
        }
    }
}

// ------------------------------------------------------------------ launch --
extern "C" void kernel_launch(void* const* d_in, const int* in_sizes, int n_in,
                              void* d_out, int out_size, void* d_ws, size_t ws_size,
                              hipStream_t stream)
{
    const float* x       = (const float*)d_in[0];
    const int*   ei      = (const int*)  d_in[1];   // [2, E] int32
    const float* W_in    = (const float*)d_in[2];
    const float* b_in    = (const float*)d_in[3];
    const float* W_nor   = (const float*)d_in[4];
    const float* b_nor   = (const float*)d_in[5];
    const float* W_abnor = (const float*)d_in[6];
    const float* b_abnor = (const float*)d_in[7];
    const float* W_att   = (const float*)d_in[8];
    const float* b_att   = (const float*)d_in[9];
    const float* v_att   = (const float*)d_in[10];
    const float* W_upd   = (const float*)d_in[11];
    const float* b_upd   = (const float*)d_in[12];
    const float* W_cls   = (const float*)d_in[13];
    const float* b_cls   = (const float*)d_in[14];
    float* out = (float*)d_out;

    // ws: cnt[N] | row_start[N+1] | bsum[128] | csr_src[E] | u_bf16[N*64 uints]
    //     | acc[N*HID] f32 | F[20480 uint4].   ticket[E] aliases acc.
    char* base = (char*)d_ws;
    int*  cnt       = (int*)base;
    int*  row_start = cnt + N_NODES;
    int*  bsum      = row_start + (N_NODES + 1);
    int*  csr_src   = bsum + 128;
    size_t off_u    = (((size_t)(2 * N_NODES + 129 + E_EDGES)) * 4 + 63) & ~(size_t)63;
    uint32* u       = (uint32*)(base + off_u);
    size_t off_acc  = (off_u + (size_t)N_NODES * (HID / 2) * 4 + 63) & ~(size_t)63;
    float* acc      = (float*)(base + off_acc);
    int*   ticket   = (int*)acc;
    size_t off_f    = (off_acc + (size_t)N_NODES * HID * 4 + 63) & ~(size_t)63;
    uint4* F        = (uint4*)(base + off_f);

    const int nblk = (N_NODES + NW - 1) / NW;   // 1563

    zero_int_kernel<<<(N_NODES + 255) / 256, 256, 0, stream>>>(cnt, N_NODES);
    deg_ticket_kernel<<<(E_EDGES + 255) / 256, 256, 0, stream>>>(ei + E_EDGES, cnt, ticket);
    scan1_kernel<<<SCAN_NB, SCAN_B, 0, stream>>>(cnt, row_start, bsum);
    scan2_kernel<<<1, 128, 0, stream>>>(bsum, row_start);
    scan3_kernel<<<SCAN_NB, SCAN_B, 0, stream>>>(bsum, row_start);
    fill_kernel<<<(E_EDGES + 255) / 256, 256, 0, stream>>>(ei, row_start, ticket, csr_src);
    prep_w_kernel<<<F_TOTAL / 256, 256, 0, stream>>>(W_in, W_nor, W_abnor, W_att, W_upd, F);
    node_phase_kernel<<<nblk, 256, 0, stream>>>(
        x, b_in, b_nor, b_abnor, b_att, v_att, cnt, F, u);
    gather_kernel<<<(N_NODES + 3) / 4, 256, 0, stream>>>(row_start, csr_src, u, acc);
    final_phase_kernel<<<nblk, 256, 0, stream>>>(
        acc, cnt, b_upd, W_cls, b_cls, F, out);
}

// Round 17
// 159.891 us; speedup vs baseline: 3.0643x; 1.0129x over previous
//
#include <hip/hip_runtime.h>

#define N_NODES 50000
#define E_EDGES 800000
#define IN_DIM  256
#define HID     128
#define HALF    64
#define OUT_DIM 2
#define NW      32               // nodes per block tile
#define SLOPE   0.01f

#define ST      132              // tile row stride (fp32/uint32 units)
#define WSLICE  (NW * ST)        // 4224 words = 16.9 KB

#define SSTRIDE 520              // bf16 units per s-step in A planes (512+8 pad)
#define PLANE   (8 * SSTRIDE)    // 4160 bf16 per plane

#define SCAN_B  512
#define SCAN_NB ((N_NODES + SCAN_B - 1) / SCAN_B)   // 98

typedef unsigned int uint32;
typedef __attribute__((ext_vector_type(8)))  __bf16 bf16x8v;
typedef __attribute__((ext_vector_type(16))) float  f32x16;

union BF8 { bf16x8v v; unsigned short s[8]; uint4 q; };

// weight-fragment table offsets (frag = 2 uint4: hi, lo)
#define FI_F 0        // W_in : S=16 -> 4096 frags
#define FN_F 4096     // W_nor: S=4  -> 1024
#define FA_F 5120     // W_abnor: S=4 -> 1024
#define FT_F 6144     // W_att: S=8 -> 2048
#define FU_F 8192     // W_upd: S=8 -> 2048
#define F_TOTAL 10240 // 20480 uint4 = 320 KB

__device__ __forceinline__ uint32 rne16u(uint32 u) {
    return (u + 0x7fffu + ((u >> 16) & 1u)) >> 16;
}

// pack one fp32 into (hi_bf16 << 16) | lo_bf16  (error-compensated split)
__device__ __forceinline__ uint32 pack_hl(float v) {
    uint32 uu = __float_as_uint(v);
    uint32 hh = rne16u(uu);
    float  fh = __uint_as_float(hh << 16);
    float  r  = v - fh;
    uint32 ll = rne16u(__float_as_uint(r));
    return (hh << 16) | ll;
}

// fast tanh / sigmoid via v_exp + v_rcp (~1e-7 rel err)
__device__ __forceinline__ float fast_tanh(float x) {
    float ex = __expf(2.f * x);
    return 1.f - 2.f * __builtin_amdgcn_rcpf(ex + 1.f);
}
__device__ __forceinline__ float fast_sig(float x) {
    return __builtin_amdgcn_rcpf(1.f + __expf(-x));
}

__device__ __forceinline__ void mfma3(f32x16& acc, bf16x8v ah, bf16x8v al,
                                      bf16x8v bh, bf16x8v bl) {
    acc = __builtin_amdgcn_mfma_f32_32x32x16_bf16(ah, bh, acc, 0, 0, 0);
    acc = __builtin_amdgcn_mfma_f32_32x32x16_bf16(ah, bl, acc, 0, 0, 0);
    acc = __builtin_amdgcn_mfma_f32_32x32x16_bf16(al, bh, acc, 0, 0, 0);
}

// split a float4 at (row rr, local col k) into fragment-ordered LDS planes.
// A-frag (32x32x16): slot = s*SSTRIDE + lane*8 + j, lane = rr + 32*((k>>3)&1).
__device__ __forceinline__ void stage_split4(__bf16* __restrict__ Ahi,
                                             __bf16* __restrict__ Alo,
                                             int rr, int k, float4 v) {
    int s_idx = k >> 4, jb = k & 7, lt = rr + 32 * ((k >> 3) & 1);
    int base = s_idx * SSTRIDE + lt * 8 + jb;
    float f[4] = {v.x, v.y, v.z, v.w};
    uint32 h[4], lo[4];
    #pragma unroll
    for (int j = 0; j < 4; j++) {
        uint32 uu = __float_as_uint(f[j]);
        uint32 hh = rne16u(uu);
        float  fh = __uint_as_float(hh << 16);
        float  r  = f[j] - fh;
        h[j] = hh; lo[j] = rne16u(__float_as_uint(r));
    }
    *(uint2*)(Ahi + base) = make_uint2(h[0] | (h[1] << 16), h[2] | (h[3] << 16));
    *(uint2*)(Alo + base) = make_uint2(lo[0] | (lo[1] << 16), lo[2] | (lo[3] << 16));
}

// 1-tile GEMM from pre-split planes: pure ds_read + F-load + MFMA
__device__ __forceinline__ void mfma_gemm1_pre(f32x16& acc,
        const __bf16* __restrict__ Ahi, const __bf16* __restrict__ Alo,
        int S, int sg0, const uint4* __restrict__ F, int fbase, int l, int t) {
    for (int s = 0; s < S; s++) {
        bf16x8v ah = *(const bf16x8v*)&Ahi[s * SSTRIDE + l * 8];
        bf16x8v al = *(const bf16x8v*)&Alo[s * SSTRIDE + l * 8];
        int f = fbase + ((sg0 + s) * 4 + t) * 64 + l;
        BF8 bh, bl; bh.q = F[2 * f]; bl.q = F[2 * f + 1];
        mfma3(acc, ah, al, bh.v, bl.v);
    }
}

// 1-tile GEMM from packed (hi|lo) uint32 tile: 2 b128 + 8 shift/mask unpacks
__device__ __forceinline__ void mfma_gemm1_pk(f32x16& acc, const uint32* T,
        int aoff, int S, const uint4* __restrict__ F, int fbase, int l, int t) {
    const int row = l & 31, khi = 8 * (l >> 5);
    for (int s = 0; s < S; s++) {
        int k0 = aoff + 16 * s + khi;
        uint4 qa = *(const uint4*)&T[row * ST + k0];
        uint4 qb = *(const uint4*)&T[row * ST + k0 + 4];
        BF8 ah, al;
        ah.q.x = (qa.x >> 16) | (qa.y & 0xffff0000u);
        ah.q.y = (qa.z >> 16) | (qa.w & 0xffff0000u);
        ah.q.z = (qb.x >> 16) | (qb.y & 0xffff0000u);
        ah.q.w = (qb.z >> 16) | (qb.w & 0xffff0000u);
        al.q.x = (qa.x & 0xffffu) | (qa.y << 16);
        al.q.y = (qa.z & 0xffffu) | (qa.w << 16);
        al.q.z = (qb.x & 0xffffu) | (qb.y << 16);
        al.q.w = (qb.z & 0xffffu) | (qb.w << 16);
        int f = fbase + (s * 4 + t) * 64 + l;
        BF8 bh, bl; bh.q = F[2 * f]; bl.q = F[2 * f + 1];
        mfma3(acc, ah.v, al.v, bh.v, bl.v);
    }
}

__device__ __forceinline__ uint32 pack_bf2(float x, float y) {
    return rne16u(__float_as_uint(x)) | (rne16u(__float_as_uint(y)) << 16);
}

// ---------------------------------------------------------------- degree ----
__global__ void zero_int_kernel(int* __restrict__ p, int n) {
    int i = blockIdx.x * blockDim.x + threadIdx.x;
    if (i < n) p[i] = 0;
}

__global__ void deg_ticket_kernel(const int* __restrict__ col,
                                  int* __restrict__ cnt, int* __restrict__ ticket) {
    int e = blockIdx.x * blockDim.x + threadIdx.x;
    if (e < E_EDGES) ticket[e] = atomicAdd(&cnt[col[e]], 1);
}

// ------------------------------------------------------- 3-pass fast scan ---
__device__ __forceinline__ int wave_iscan(int v, int l) {
    #pragma unroll
    for (int off = 1; off < 64; off <<= 1) {
        int t = __shfl_up(v, off, 64);
        if (l >= off) v += t;
    }
    return v;
}

__global__ __launch_bounds__(SCAN_B) void scan1_kernel(
    const int* __restrict__ cnt, int* __restrict__ row_start, int* __restrict__ bsum)
{
    __shared__ int wsum[SCAN_B / 64];
    int i = blockIdx.x * SCAN_B + threadIdx.x;
    int v = (i < N_NODES) ? cnt[i] : 0;
    int l = threadIdx.x & 63, w = threadIdx.x >> 6;
    int isc = wave_iscan(v, l);
    if (l == 63) wsum[w] = isc;
    __syncthreads();
    int wo = 0;
    #pragma unroll
    for (int k = 0; k < SCAN_B / 64; k++) wo += (k < w) ? wsum[k] : 0;
    if (i < N_NODES) row_start[i] = wo + isc - v;
    if (threadIdx.x == SCAN_B - 1) bsum[blockIdx.x] = wo + isc;
}

__global__ __launch_bounds__(128) void scan2_kernel(
    int* __restrict__ bsum, int* __restrict__ row_start)
{
    __shared__ int wsum[2];
    int i = threadIdx.x;
    int v = (i < SCAN_NB) ? bsum[i] : 0;
    int l = i & 63, w = i >> 6;
    int isc = wave_iscan(v, l);
    if (l == 63) wsum[w] = isc;
    __syncthreads();
    int wo = (w == 1) ? wsum[0] : 0;
    if (i < SCAN_NB) bsum[i] = wo + isc - v;
    if (i == SCAN_NB - 1) row_start[N_NODES] = wo + isc;
}

__global__ __launch_bounds__(SCAN_B) void scan3_kernel(
    const int* __restrict__ bsum, int* __restrict__ row_start)
{
    int i = blockIdx.x * SCAN_B + threadIdx.x;
    if (i < N_NODES) row_start[i] += bsum[blockIdx.x];
}

__global__ void fill_kernel(const int* __restrict__ ei,
                            const int* __restrict__ row_start,
                            const int* __restrict__ ticket,
                            int* __restrict__ csr_src)
{
    int e = blockIdx.x * blockDim.x + threadIdx.x;
    if (e >= E_EDGES) return;
    int j = ei[e];
    int i = ei[E_EDGES + e];
    csr_src[row_start[i] + ticket[e]] = j;
}

// ---------------------------------------------------- weight prep (split) ---
// B-frag layout (32x32x16): col = lane&31, k = 8*(lane>>5)+j.
__global__ __launch_bounds__(256) void prep_w_kernel(
    const float* __restrict__ W_in, const float* __restrict__ W_nor,
    const float* __restrict__ W_ab, const float* __restrict__ W_att,
    const float* __restrict__ W_upd,
    uint4* __restrict__ F)
{
    int idx = blockIdx.x * 256 + threadIdx.x;
    const float* W; int fbase, fi;
    if (idx < 4096)       { W = W_in;  fbase = FI_F; fi = idx; }
    else if (idx < 5120)  { W = W_nor; fbase = FN_F; fi = idx - 4096; }
    else if (idx < 6144)  { W = W_ab;  fbase = FA_F; fi = idx - 5120; }
    else if (idx < 8192)  { W = W_att; fbase = FT_F; fi = idx - 6144; }
    else if (idx < 10240) { W = W_upd; fbase = FU_F; fi = idx - 8192; }
    else return;
    int l = fi & 63, st = fi >> 6, t = st & 3, s = st >> 2;
    int k0 = 16 * s + 8 * (l >> 5);
    int c  = 32 * t + (l & 31);
    uint32 hi[8], lo[8];
    #pragma unroll
    for (int j = 0; j < 8; j++) {
        float v = W[(size_t)(k0 + j) * HID + c];
        uint32 uu = __float_as_uint(v);
        uint32 h  = rne16u(uu);
        float  fh = __uint_as_float(h << 16);
        float  r  = v - fh;
        hi[j] = h;
        lo[j] = rne16u(__float_as_uint(r));
    }
    uint4 H, L;
    H.x = hi[0] | (hi[1] << 16); H.y = hi[2] | (hi[3] << 16);
    H.z = hi[4] | (hi[5] << 16); H.w = hi[6] | (hi[7] << 16);
    L.x = lo[0] | (lo[1] << 16); L.y = lo[2] | (lo[3] << 16);
    L.z = lo[4] | (lo[5] << 16); L.w = lo[6] | (lo[7] << 16);
    int f = fbase + fi;
    F[2 * f]     = H;
    F[2 * f + 1] = L;
}

// ------------------------------------------------------------- node phase ---
// 256 threads = 4 waves per 32-node tile; wave w owns output cols 32w..32w+31.
__global__ __launch_bounds__(256, 4) void node_phase_kernel(
    const float* __restrict__ x,
    const float* __restrict__ b_in,  const float* __restrict__ b_nor,
    const float* __restrict__ b_abnor, const float* __restrict__ b_att,
    const float* __restrict__ v_att,
    const int* __restrict__ cnt,
    const uint4* __restrict__ F,
    uint32* __restrict__ u)            // [N][HID/2] packed bf16 pairs
{
    __shared__ __align__(16) float smem[WSLICE];   // 16.9 KB overlaid
    __shared__ float dinvs[NW];
    __shared__ float gpart[4][NW];
    __bf16* Ahi = (__bf16*)smem;              // padded plane (4160 bf16)
    __bf16* Alo = (__bf16*)smem + PLANE;      // second plane
    uint32* T   = (uint32*)smem;              // packed h/s tile [32][ST]

    const int tid    = threadIdx.x;
    const int w      = tid >> 6;          // tile t = w
    const int l      = tid & 63;
    const int col    = l & 31;
    const int hi     = l >> 5;
    const int wnode0 = blockIdx.x * NW;

    if (tid < NW) {
        int nd = wnode0 + tid;
        float c = (nd < N_NODES) ? (float)cnt[nd] : 0.f;
        dinvs[tid] = rsqrtf(c + 1.0f);
    }

    // ---- h = leaky_relu(x @ W_in + b_in), K=256 in two 128-halves ----
    f32x16 hacc;
    {
        float bv = b_in[32 * w + col];
        #pragma unroll
        for (int r2 = 0; r2 < 16; r2++) hacc[r2] = bv;
    }
    for (int half = 0; half < 2; half++) {
        #pragma unroll
        for (int it = 0; it < 4; it++) {           // 1024 float4 over 256 thr
            int i = it * 256 + tid;
            int rr = i >> 5, kq = i & 31, k = 4 * kq;
            int nd = wnode0 + rr; if (nd >= N_NODES) nd = N_NODES - 1;
            float4 v = *(const float4*)(x + (size_t)nd * IN_DIM + half * 128 + k);
            stage_split4(Ahi, Alo, rr, k, v);
        }
        __syncthreads();
        mfma_gemm1_pre(hacc, Ahi, Alo, 8, half * 8, F, FI_F, l, w);
        __syncthreads();   // planes consumed; safe to overwrite
    }

    // ---- lrelu(h) -> packed tile cols [32w, 32w+32) ----
    #pragma unroll
    for (int rg = 0; rg < 16; rg++) {
        int rrow = (rg & 3) + 8 * (rg >> 2) + 4 * hi;
        float v = hacc[rg];
        v = v > 0.f ? v : SLOPE * v;
        T[rrow * ST + 32 * w + col] = pack_hl(v);
    }
    __syncthreads();

    // ---- xn = h[:, :64] @ W_nor ; xa = h[:, 64:] @ W_abnor ----
    f32x16 xn, xa;
    {
        float bv = b_nor[32 * w + col];
        #pragma unroll
        for (int r2 = 0; r2 < 16; r2++) xn[r2] = bv;
    }
    mfma_gemm1_pk(xn, T, 0, 4, F, FN_F, l, w);
    {
        float bv = b_abnor[32 * w + col];
        #pragma unroll
        for (int r2 = 0; r2 < 16; r2++) xa[r2] = bv;
    }
    mfma_gemm1_pk(xa, T, HALF, 4, F, FA_F, l, w);
    __syncthreads();   // h consumed

    // ---- s = xn+xa (regs + packed tile); d = xn-xa (regs) ----
    f32x16 sv, d;
    #pragma unroll
    for (int rg = 0; rg < 16; rg++) {
        int rrow = (rg & 3) + 8 * (rg >> 2) + 4 * hi;
        sv[rg] = xn[rg] + xa[rg];
        d[rg]  = xn[rg] - xa[rg];
        T[rrow * ST + 32 * w + col] = pack_hl(sv[rg]);
    }
    __syncthreads();

    // ---- t = s @ W_att + b_att ----
    f32x16 tac;
    {
        float bv = b_att[32 * w + col];
        #pragma unroll
        for (int r2 = 0; r2 < 16; r2++) tac[r2] = bv;
    }
    mfma_gemm1_pk(tac, T, 0, 8, F, FT_F, l, w);

    // ---- alpha: per-wave partial (32 cols), cross-wave via gpart ----
    float g[16];
    {
        float vv = v_att[32 * w + col];
        #pragma unroll
        for (int rg = 0; rg < 16; rg++) g[rg] = fast_tanh(tac[rg]) * vv;
    }
    #pragma unroll
    for (int msk = 16; msk >= 1; msk >>= 1) {
        #pragma unroll
        for (int rg = 0; rg < 16; rg++) g[rg] += __shfl_xor(g[rg], msk, 64);
    }
    if (col == 0) {
        #pragma unroll
        for (int rg = 0; rg < 16; rg++) {
            int rrow = (rg & 3) + 8 * (rg >> 2) + 4 * hi;
            gpart[w][rrow] = g[rg];
        }
    }
    __syncthreads();

    float am[16];
    #pragma unroll
    for (int rg = 0; rg < 16; rg++) {
        int rrow = (rg & 3) + 8 * (rg >> 2) + 4 * hi;
        float gt = gpart[0][rrow] + gpart[1][rrow] + gpart[2][rrow] + gpart[3][rrow];
        am[rg] = fast_sig(gt) - 0.5f;
    }

    // ---- u = dinv * (0.5*s + (alpha-0.5)*d), packed bf16 pairs ----
    #pragma unroll
    for (int rg = 0; rg < 16; rg++) {
        int rrow = (rg & 3) + 8 * (rg >> 2) + 4 * hi;
        int n    = wnode0 + rrow;
        float uv = dinvs[rrow] * (0.5f * sv[rg] + am[rg] * d[rg]);
        float pv = __shfl_xor(uv, 1, 64);
        if (((l & 1) == 0) && n < N_NODES) {
            u[(size_t)n * (HID / 2) + 16 * w + (col >> 1)] = pack_bf2(uv, pv);
        }
    }
}

// ----------------------------------------------- fused gather + final phase ---
// 256 threads = 4 waves per 32-node tile. Wave w gathers nodes 8w..8w+7 from
// u via CSR (predicated 8-batches), applies dinv, and stages the aggregated
// rows DIRECTLY into the MFMA A-planes (lane l holds cols 2l, 2l+1 -> one
// aligned 4B store per plane per node). Then FU MFMA (tile t=w) + classifier.
__global__ __launch_bounds__(256, 4) void final_fused_kernel(
    const int* __restrict__ row_start, const int* __restrict__ csr_src,
    const uint32* __restrict__ u, const int* __restrict__ cnt,
    const float* __restrict__ b_upd,
    const float* __restrict__ W_cls, const float* __restrict__ b_cls,
    const uint4* __restrict__ F,
    float* __restrict__ out)
{
    __shared__ __align__(16) float smem[WSLICE];
    __bf16* Ahi = (__bf16*)smem;
    __bf16* Alo = (__bf16*)smem + PLANE;

    const int tid    = threadIdx.x;
    const int w      = tid >> 6;
    const int l      = tid & 63;
    const int col    = l & 31;
    const int hi     = l >> 5;
    const int wnode0 = blockIdx.x * NW;

    const size_t RW = HID / 2;
    // plane slot for this lane's pair (cols k=2l, 2l+1); same slot for all 8 rows
    const int kk   = 2 * l;
    const int sidx = kk >> 4, jj = kk & 7, ltb = 32 * ((kk >> 3) & 1);

    for (int q = 0; q < 8; q++) {
        int rr = 8 * w + q;
        int nd = wnode0 + rr; if (nd >= N_NODES) nd = N_NODES - 1;

        uint32 v = u[(size_t)nd * RW + l];
        float sx = __uint_as_float(v << 16);
        float sy = __uint_as_float(v & 0xffff0000u);

        int b = row_start[nd], e = row_start[nd + 1];
        for (int p = b; p < e; p += 8) {
            int idx[8];
            #pragma unroll
            for (int qq = 0; qq < 8; qq++) {
                int a = p + qq; if (a > e - 1) a = e - 1;
                idx[qq] = csr_src[a];
            }
            uint32 vv[8];
            #pragma unroll
            for (int qq = 0; qq < 8; qq++) vv[qq] = u[(size_t)idx[qq] * RW + l];
            #pragma unroll
            for (int qq = 0; qq < 8; qq++) {
                if (p + qq < e) {
                    sx += __uint_as_float(vv[qq] << 16);
                    sy += __uint_as_float(vv[qq] & 0xffff0000u);
                }
            }
        }
        float dv = rsqrtf((float)cnt[nd] + 1.0f);
        sx *= dv; sy *= dv;

        // split-stage this pair into the A-planes
        uint32 px = pack_hl(sx), py = pack_hl(sy);
        int base = sidx * SSTRIDE + (rr + ltb) * 8 + jj;
        *(uint32*)&Ahi[base] = (px >> 16) | (py & 0xffff0000u);
        *(uint32*)&Alo[base] = (px & 0xffffu) | (py << 16);
    }
    __syncthreads();

    f32x16 up;
    {
        float bv = b_upd[32 * w + col];
        #pragma unroll
        for (int r2 = 0; r2 < 16; r2++) up[r2] = bv;
    }
    mfma_gemm1_pre(up, Ahi, Alo, 8, 0, F, FU_F, l, w);
    __syncthreads();   // planes consumed before overwrite

    // lrelu -> fp32 tile cols [32w, 32w+32)
    float* B = smem;
    #pragma unroll
    for (int rg = 0; rg < 16; rg++) {
        int rrow = (rg & 3) + 8 * (rg >> 2) + 4 * hi;
        float v = up[rg];
        B[rrow * ST + 32 * w + col] = v > 0.f ? v : SLOPE * v;
    }
    __syncthreads();

    // classifier: tid = n*8 + o*4 + c ; 4 lanes per (node,out), shfl-reduce
    {
        int n = tid >> 3, o = (tid >> 2) & 1, c = tid & 3;
        float s = 0.f;
        int k0 = c * 32;
        for (int k = k0; k < k0 + 32; k++)
            s = fmaf(B[n * ST + k], W_cls[k * OUT_DIM + o], s);
        s += __shfl_xor(s, 1, 64);
        s += __shfl_xor(s, 2, 64);
        if (c == 0 && wnode0 + n < N_NODES) {
            out[(size_t)(wnode0 + n) * OUT_DIM + o] = s + b_cls[o];
        }
    }
}

// ------------------------------------------------------------------ launch --
extern "C" void kernel_launch(void* const* d_in, const int* in_sizes, int n_in,
                              void* d_out, int out_size, void* d_ws, size_t ws_size,
                              hipStream_t stream)
{
    const float* x       = (const float*)d_in[0];
    const int*   ei      = (const int*)  d_in[1];   // [2, E] int32
    const float* W_in    = (const float*)d_in[2];
    const float* b_in    = (const float*)d_in[3];
    const float* W_nor   = (const float*)d_in[4];
    const float* b_nor   = (const float*)d_in[5];
    const float* W_abnor = (const float*)d_in[6];
    const float* b_abnor = (const float*)d_in[7];
    const float* W_att   = (const float*)d_in[8];
    const float* b_att   = (const float*)d_in[9];
    const float* v_att   = (const float*)d_in[10];
    const float* W_upd   = (const float*)d_in[11];
    const float* b_upd   = (const float*)d_in[12];
    const float* W_cls   = (const float*)d_in[13];
    const float* b_cls   = (const float*)d_in[14];
    float* out = (float*)d_out;

    // ws: cnt[N] | row_start[N+1] | bsum[128] | csr_src[E] | ticket[E]
    //     | u_bf16[N*64 uints] | F[20480 uint4]   (~20 MB)
    char* base = (char*)d_ws;
    int*  cnt       = (int*)base;
    int*  row_start = cnt + N_NODES;
    int*  bsum      = row_start + (N_NODES + 1);
    int*  csr_src   = bsum + 128;
    int*  ticket    = csr_src + E_EDGES;
    size_t off_u    = (((size_t)(2 * N_NODES + 129 + 2 * E_EDGES)) * 4 + 63) & ~(size_t)63;
    uint32* u       = (uint32*)(base + off_u);
    size_t off_f    = (off_u + (size_t)N_NODES * (HID / 2) * 4 + 63) & ~(size_t)63;
    uint4* F        = (uint4*)(base + off_f);

    const int nblk = (N_NODES + NW - 1) / NW;   // 1563

    zero_int_kernel<<<(N_NODES + 255) / 256, 256, 0, stream>>>(cnt, N_NODES);
    deg_ticket_kernel<<<(E_EDGES + 255) / 256, 256, 0, stream>>>(ei + E_EDGES, cnt, ticket);
    scan1_kernel<<<SCAN_NB, SCAN_B, 0, stream>>>(cnt, row_start, bsum);
    scan2_kernel<<<1, 128, 0, stream>>>(bsum, row_start);
    scan3_kernel<<<SCAN_NB, SCAN_B, 0, stream>>>(bsum, row_start);
    fill_kernel<<<(E_EDGES + 255) / 256, 256, 0, stream>>>(ei, row_start, ticket, csr_src);
    prep_w_kernel<<<F_TOTAL / 256, 256, 0, stream>>>(W_in, W_nor, W_abnor, W_att, W_upd, F);
    node_phase_kernel<<<nblk, 256, 0, stream>>>(
        x, b_in, b_nor, b_abnor, b_att, v_att, cnt, F, u);
    final_fused_kernel<<<nblk, 256, 0, stream>>>(
        row_start, csr_src, u, cnt, b_upd, W_cls, b_cls, F, out);
}